// Round 2
// baseline (2297.675 us; speedup 1.0000x reference)
//
#include <hip/hip_runtime.h>
#include <hip/hip_bf16.h>

#define LL 3136
#define HH 56
#define WWD 56
#define DMODEL 384
#define DINNER 768
#define NH 12
#define HD 64
#define DSTATE 64
#define CDIM 896
#define DPROJ 1676
#define LNEPS 1e-5f
#define GRP 8

__device__ __forceinline__ float b2f(unsigned short u) {
    return __uint_as_float(((unsigned int)u) << 16);
}
__device__ __forceinline__ unsigned short f2b(float f) {
    __hip_bfloat16 h = __float2bfloat16(f);   // RNE
    return *reinterpret_cast<unsigned short*>(&h);
}

// C[m,n] = sum_k A[m*lda+k] * B[n*ldb+k]  ("TN": both K-contiguous)
// A is fp32 or bf16 (A_BF16), C is fp32 or bf16 (C_BF16). B always fp32.
template<int A_BF16, int C_BF16>
__global__ __launch_bounds__(256) void gemm_tn(
    const void* __restrict__ Ap, const float* __restrict__ B, void* __restrict__ Cp,
    int M, int N, int K, int lda, int ldb, int ldc)
{
    __shared__ float As[32][68];
    __shared__ float Bs[32][68];
    const int t  = threadIdx.x;
    const int bm = blockIdx.x * 64;
    const int bn = blockIdx.y * 64;
    const int tx = t & 15, ty = t >> 4;
    const int lk = (t & 7) * 4;   // k offset (4 elems)
    const int lr = t >> 3;        // row 0..31 (+32 second pass)
    float acc[4][4] = {};

    for (int k0 = 0; k0 < K; k0 += 32) {
#pragma unroll
        for (int rr = 0; rr < 64; rr += 32) {
            int m = bm + lr + rr;
            if (A_BF16) {
                const unsigned short* A = (const unsigned short*)Ap;
                ushort4 v = *(const ushort4*)&A[(size_t)m * lda + k0 + lk];
                As[lk+0][lr+rr] = b2f(v.x); As[lk+1][lr+rr] = b2f(v.y);
                As[lk+2][lr+rr] = b2f(v.z); As[lk+3][lr+rr] = b2f(v.w);
            } else {
                const float* A = (const float*)Ap;
                float4 v = *(const float4*)&A[(size_t)m * lda + k0 + lk];
                As[lk+0][lr+rr] = v.x; As[lk+1][lr+rr] = v.y;
                As[lk+2][lr+rr] = v.z; As[lk+3][lr+rr] = v.w;
            }
            int n = bn + lr + rr;
            float4 w = make_float4(0.f, 0.f, 0.f, 0.f);
            if (n < N) w = *(const float4*)&B[(size_t)n * ldb + k0 + lk];
            Bs[lk+0][lr+rr] = w.x; Bs[lk+1][lr+rr] = w.y;
            Bs[lk+2][lr+rr] = w.z; Bs[lk+3][lr+rr] = w.w;
        }
        __syncthreads();
#pragma unroll
        for (int k = 0; k < 32; ++k) {
            float4 a = *(const float4*)&As[k][ty*4];
            float4 b = *(const float4*)&Bs[k][tx*4];
            acc[0][0] += a.x*b.x; acc[0][1] += a.x*b.y; acc[0][2] += a.x*b.z; acc[0][3] += a.x*b.w;
            acc[1][0] += a.y*b.x; acc[1][1] += a.y*b.y; acc[1][2] += a.y*b.z; acc[1][3] += a.y*b.w;
            acc[2][0] += a.z*b.x; acc[2][1] += a.z*b.y; acc[2][2] += a.z*b.z; acc[2][3] += a.z*b.w;
            acc[3][0] += a.w*b.x; acc[3][1] += a.w*b.y; acc[3][2] += a.w*b.z; acc[3][3] += a.w*b.w;
        }
        __syncthreads();
    }

    if (bn + 64 <= N) {
#pragma unroll
        for (int i = 0; i < 4; ++i) {
            if (C_BF16) {
                unsigned short* C = (unsigned short*)Cp;
                ushort4 o;
                o.x = f2b(acc[i][0]); o.y = f2b(acc[i][1]);
                o.z = f2b(acc[i][2]); o.w = f2b(acc[i][3]);
                *(ushort4*)&C[(size_t)(bm + ty*4 + i) * ldc + bn + tx*4] = o;
            } else {
                float* C = (float*)Cp;
                float4 v = make_float4(acc[i][0], acc[i][1], acc[i][2], acc[i][3]);
                *(float4*)&C[(size_t)(bm + ty*4 + i) * ldc + bn + tx*4] = v;
            }
        }
    } else {
        for (int i = 0; i < 4; ++i)
            for (int j = 0; j < 4; ++j) {
                int n = bn + tx*4 + j;
                if (n < N) {
                    if (C_BF16) {
                        unsigned short* C = (unsigned short*)Cp;
                        C[(size_t)(bm + ty*4 + i) * ldc + n] = f2b(acc[i][j]);
                    } else {
                        float* C = (float*)Cp;
                        C[(size_t)(bm + ty*4 + i) * ldc + n] = acc[i][j];
                    }
                }
            }
    }
}

// depthwise 3x3 conv (pad 1) on bf16 xBC slice of zx, + bias + SiLU -> bf16 xconv (group-local)
__global__ __launch_bounds__(256) void conv_silu(
    const unsigned short* __restrict__ zx, const float* __restrict__ cw,
    const float* __restrict__ cb, unsigned short* __restrict__ xconv, int b0)
{
    int c = blockIdx.x * 256 + threadIdx.x;
    if (c >= CDIM) return;
    int l = blockIdx.y;
    int bz = blockIdx.z;
    int h = l / WWD, w = l % WWD;
    float acc = cb[c];
    const unsigned short* base = zx + (size_t)(b0 + bz) * LL * DPROJ + DINNER + c;
#pragma unroll
    for (int kh = -1; kh <= 1; ++kh) {
        int h2 = h + kh;
        if (h2 < 0 || h2 >= HH) continue;
#pragma unroll
        for (int kw = -1; kw <= 1; ++kw) {
            int w2 = w + kw;
            if (w2 < 0 || w2 >= WWD) continue;
            acc += cw[c * 9 + (kh + 1) * 3 + (kw + 1)] * b2f(base[(size_t)(h2 * WWD + w2) * DPROJ]);
        }
    }
    float s = acc / (1.f + __expf(-acc));   // SiLU
    xconv[((size_t)bz * LL + l) * CDIM + c] = f2b(s);
}

// coef[b][h][l] = softplus(dt_raw + dt_bias[h]) * (-exp(A_log[h]))
__global__ __launch_bounds__(256) void coef_kernel(
    const unsigned short* __restrict__ zx, const float* __restrict__ dt_bias,
    const float* __restrict__ A_log, float* __restrict__ coef, int Bt)
{
    int idx = blockIdx.x * 256 + threadIdx.x;
    int total = Bt * NH * LL;
    if (idx >= total) return;
    int l = idx % LL;
    int h = (idx / LL) % NH;
    int b = idx / (LL * NH);
    float x = b2f(zx[((size_t)b * LL + l) * DPROJ + DINNER + CDIM + h]) + dt_bias[h];
    float sp = (x > 20.f) ? x : log1pf(__expf(x));
    coef[idx] = -__expf(A_log[h]) * sp;
}

// KV[b,h,s,p] += sum_{l in chunk} Bmat[b,l,s] * x[b,l,h*64+p] * coef[b,h,l]
__global__ __launch_bounds__(256) void kv_kernel(
    const unsigned short* __restrict__ xconv, const float* __restrict__ coef,
    float* __restrict__ KV, int b0)
{
    int h  = blockIdx.x;
    int bl = blockIdx.y;
    int b  = b0 + bl;
    int lbase = blockIdx.z * 448;
    __shared__ float Bsh[32][DSTATE];
    __shared__ float Xsh[32][HD];
    __shared__ float cf[32];
    const int t = threadIdx.x;
    const int p = t & 63;
    const int s0 = t >> 6;          // wave id 0..3, owns s = s0*16 .. s0*16+15
    const int lq = t >> 4;          // 0..15
    const int sq = (t & 15) * 4;
    float acc[16] = {};
    const unsigned short* xbase = xconv + (size_t)bl * LL * CDIM;
    const float* crow = coef + ((size_t)b * NH + h) * LL + lbase;

    for (int l0 = 0; l0 < 448; l0 += 32) {
#pragma unroll
        for (int rr = 0; rr < 32; rr += 16) {
            const unsigned short* r = xbase + (size_t)(lbase + l0 + lq + rr) * CDIM;
            ushort4 bv = *(const ushort4*)&r[DINNER + sq];
            Bsh[lq + rr][sq + 0] = b2f(bv.x); Bsh[lq + rr][sq + 1] = b2f(bv.y);
            Bsh[lq + rr][sq + 2] = b2f(bv.z); Bsh[lq + rr][sq + 3] = b2f(bv.w);
            ushort4 xv = *(const ushort4*)&r[h * HD + sq];
            Xsh[lq + rr][sq + 0] = b2f(xv.x); Xsh[lq + rr][sq + 1] = b2f(xv.y);
            Xsh[lq + rr][sq + 2] = b2f(xv.z); Xsh[lq + rr][sq + 3] = b2f(xv.w);
        }
        if (t < 32) cf[t] = crow[l0 + t];
        __syncthreads();
#pragma unroll
        for (int li = 0; li < 32; ++li) {
            float xv = Xsh[li][p] * cf[li];
            float4 b0v = *(const float4*)&Bsh[li][s0 * 16 + 0];
            float4 b1v = *(const float4*)&Bsh[li][s0 * 16 + 4];
            float4 b2v = *(const float4*)&Bsh[li][s0 * 16 + 8];
            float4 b3v = *(const float4*)&Bsh[li][s0 * 16 + 12];
            acc[0]  += b0v.x * xv; acc[1]  += b0v.y * xv; acc[2]  += b0v.z * xv; acc[3]  += b0v.w * xv;
            acc[4]  += b1v.x * xv; acc[5]  += b1v.y * xv; acc[6]  += b1v.z * xv; acc[7]  += b1v.w * xv;
            acc[8]  += b2v.x * xv; acc[9]  += b2v.y * xv; acc[10] += b2v.z * xv; acc[11] += b2v.w * xv;
            acc[12] += b3v.x * xv; acc[13] += b3v.y * xv; acc[14] += b3v.w == b3v.w ? b3v.z * xv : 0.f; acc[15] += b3v.w * xv;
        }
        __syncthreads();
    }
    float* out = KV + ((size_t)b * NH + h) * DSTATE * HD;
#pragma unroll
    for (int j = 0; j < 16; ++j)
        atomicAdd(&out[(size_t)(s0 * 16 + j) * HD + p], acc[j]);
}

// y = Cmat @ KV + x*D ; gate silu(z) ; LayerNorm(768) ; write y (bf16) over z region of zx
__global__ __launch_bounds__(256) void yln_kernel(
    unsigned short* __restrict__ zx, const unsigned short* __restrict__ xc,
    const float* __restrict__ KVg, const float* __restrict__ Dp,
    const float* __restrict__ ln_g, const float* __restrict__ ln_b, int b0)
{
    int lrow0 = blockIdx.x * 4;          // group-local row
    int bl = lrow0 / LL;
    int b  = b0 + bl;
    size_t grow0 = (size_t)b * LL + (lrow0 % LL);
    const int t = threadIdx.x;
    __shared__ float Cs[4][64];
    __shared__ float rs1[4][4], rs2[4][4];
    {
        int r = t >> 6, s = t & 63;
        Cs[r][s] = b2f(xc[(size_t)(lrow0 + r) * CDIM + DINNER + DSTATE + s]);
    }
    __syncthreads();

    float yv[3][4];
#pragma unroll
    for (int i = 0; i < 3; ++i) {
        int d = t + 256 * i;
        int h = d >> 6, p = d & 63;
        const float* kv = KVg + ((size_t)b * NH + h) * DSTATE * HD + p;
        float dcoef = Dp[h];
        float acc[4];
#pragma unroll
        for (int r = 0; r < 4; ++r)
            acc[r] = b2f(xc[(size_t)(lrow0 + r) * CDIM + d]) * dcoef;
        for (int s = 0; s < 64; ++s) {
            float kvv = kv[(size_t)s * HD];
#pragma unroll
            for (int r = 0; r < 4; ++r) acc[r] += Cs[r][s] * kvv;
        }
#pragma unroll
        for (int r = 0; r < 4; ++r) {
            float z = b2f(zx[(grow0 + r) * DPROJ + d]);
            float sz = z / (1.f + __expf(-z));
            yv[i][r] = acc[r] * sz;
        }
    }

#pragma unroll
    for (int r = 0; r < 4; ++r) {
        float s1 = yv[0][r] + yv[1][r] + yv[2][r];
        float s2 = yv[0][r]*yv[0][r] + yv[1][r]*yv[1][r] + yv[2][r]*yv[2][r];
        for (int off = 32; off; off >>= 1) {
            s1 += __shfl_down(s1, off);
            s2 += __shfl_down(s2, off);
        }
        if ((t & 63) == 0) { rs1[r][t >> 6] = s1; rs2[r][t >> 6] = s2; }
    }
    __syncthreads();

    float mu[4], rstd[4];
#pragma unroll
    for (int r = 0; r < 4; ++r) {
        float S1 = rs1[r][0] + rs1[r][1] + rs1[r][2] + rs1[r][3];
        float S2 = rs2[r][0] + rs2[r][1] + rs2[r][2] + rs2[r][3];
        mu[r] = S1 * (1.f / 768.f);
        float var = S2 * (1.f / 768.f) - mu[r] * mu[r];
        rstd[r] = rsqrtf(var + LNEPS);
    }

#pragma unroll
    for (int i = 0; i < 3; ++i) {
        int d = t + 256 * i;
        float g = ln_g[d], bb = ln_b[d];
#pragma unroll
        for (int r = 0; r < 4; ++r)
            zx[(grow0 + r) * DPROJ + d] = f2b((yv[i][r] - mu[r]) * rstd[r] * g + bb);
    }
}

extern "C" void kernel_launch(void* const* d_in, const int* in_sizes, int n_in,
                              void* d_out, int out_size, void* d_ws, size_t ws_size,
                              hipStream_t stream)
{
    const float* u       = (const float*)d_in[0];
    const float* W_in    = (const float*)d_in[1];
    const float* conv_w  = (const float*)d_in[2];
    const float* conv_b  = (const float*)d_in[3];
    const float* dt_bias = (const float*)d_in[4];
    const float* A_log   = (const float*)d_in[5];
    const float* Dp      = (const float*)d_in[6];
    const float* ln_g    = (const float*)d_in[7];
    const float* ln_b    = (const float*)d_in[8];
    const float* W_out   = (const float*)d_in[9];
    float* out = (float*)d_out;
    (void)ws_size;

    const int B = in_sizes[0] / (LL * DMODEL);   // 16
    const int M = B * LL;                        // 50176

    // workspace layout (~209 MiB total)
    unsigned short* zx    = (unsigned short*)d_ws;                 // M*1676 bf16 (z|xBC|dt; y overwrites z)
    unsigned short* xconv = zx + (size_t)M * DPROJ;                // GRP*LL*896 bf16
    float* coef = (float*)(xconv + (size_t)GRP * LL * CDIM);       // B*NH*LL fp32
    float* KV   = coef + (size_t)B * NH * LL;                      // B*NH*64*64 fp32

    hipMemsetAsync(KV, 0, (size_t)B * NH * DSTATE * HD * sizeof(float), stream);

    // 1) zxbcdt = u @ W_in^T  (fp32 compute, bf16 store)
    gemm_tn<0, 1><<<dim3(M / 64, (DPROJ + 63) / 64), 256, 0, stream>>>(
        u, W_in, zx, M, DPROJ, DMODEL, DMODEL, DMODEL, DPROJ);

    // 2) dt coefficients (all batches)
    {
        int total = B * NH * LL;
        coef_kernel<<<(total + 255) / 256, 256, 0, stream>>>(
            zx, dt_bias, A_log, coef, B);
    }

    // per-group: conv -> KV -> y/LN
    for (int b0 = 0; b0 < B; b0 += GRP) {
        conv_silu<<<dim3((CDIM + 255) / 256, LL, GRP), 256, 0, stream>>>(
            zx, conv_w, conv_b, xconv, b0);
        kv_kernel<<<dim3(NH, GRP, 7), 256, 0, stream>>>(
            xconv, coef, KV, b0);
        yln_kernel<<<dim3(GRP * LL / 4), 256, 0, stream>>>(
            zx, xconv, KV, Dp, ln_g, ln_b, b0);
    }

    // 3) out = y @ W_out^T  (A bf16 in zx with ld=DPROJ, fp32 out)
    gemm_tn<1, 0><<<dim3(M / 64, DMODEL / 64), 256, 0, stream>>>(
        zx, W_out, out, M, DMODEL, DINNER, DPROJ, DINNER, DMODEL);
}

// Round 4
// 1369.836 us; speedup vs baseline: 1.6773x; 1.6773x over previous
//
#include <hip/hip_runtime.h>
#include <hip/hip_bf16.h>

#define LL 3136
#define HH 56
#define WWD 56
#define DMODEL 384
#define DINNER 768
#define NH 12
#define HD 64
#define DSTATE 64
#define CDIM 896
#define DPROJ 1676
#define LNEPS 1e-5f
#define GRP 4
#define GM (GRP * LL)          // 12544 rows per group
#define LDT 72                 // padded LDS row stride (bf16 elems)

typedef __attribute__((ext_vector_type(8))) short short8;
typedef __attribute__((ext_vector_type(4))) float f32x4;

__device__ __forceinline__ float b2f(unsigned short u) {
    return __uint_as_float(((unsigned int)u) << 16);
}
__device__ __forceinline__ unsigned short f2b(float f) {
    __hip_bfloat16 h = __float2bfloat16(f);   // RNE
    return *reinterpret_cast<unsigned short*>(&h);
}

// RNE split: a = hi + lo + r, |r| <= 2^-16 |a|
__device__ __forceinline__ void split8(const float* __restrict__ f, short8& hv, short8& lv) {
#pragma unroll
    for (int i = 0; i < 8; ++i) {
        float a = f[i];
        unsigned short h = f2b(a);
        hv[i] = (short)h;
        float r = a - b2f(h);
        lv[i] = (short)f2b(r);
    }
}

__device__ __forceinline__ f32x4 mfma16(short8 a, short8 b, f32x4 c) {
    return __builtin_amdgcn_mfma_f32_16x16x32_bf16(a, b, c, 0, 0, 0);
}

// C[m,n] = sum_k A[m*lda+k] * B[n*ldb+k], fp32 in/out, RNE 3-term bf16-split MFMA.
// M = GM (full 128-tiles), N guarded, K multiple of 64.
__global__ __launch_bounds__(256, 2) void gemm_split(
    const float* __restrict__ A, int lda, const float* __restrict__ Bw, int ldb,
    float* __restrict__ C, int ldc, int N, int K)
{
    __shared__ __align__(16) unsigned short Ah[128 * LDT], Al[128 * LDT];
    __shared__ __align__(16) unsigned short Bh[128 * LDT], Bl[128 * LDT];
    const int t = threadIdx.x;
    const int bn = blockIdx.x * 128;
    const int bm = blockIdx.y * 128;
    const int lane = t & 63;
    const int w = t >> 6;
    const int wr = (w >> 1) * 64, wc = (w & 1) * 64;
    const int srow = t >> 3, sch = t & 7;

    f32x4 acc[4][4];
#pragma unroll
    for (int m = 0; m < 4; ++m)
#pragma unroll
        for (int n = 0; n < 4; ++n) acc[m][n] = (f32x4){0.f, 0.f, 0.f, 0.f};

    for (int k0 = 0; k0 < K; k0 += 64) {
        __syncthreads();
#pragma unroll
        for (int j = 0; j < 4; ++j) {
            int row = srow + 32 * j;
            float tmp[8];
            {   // A tile
                const float* src = A + (size_t)(bm + row) * lda + k0 + sch * 8;
                *(float4*)&tmp[0] = *(const float4*)src;
                *(float4*)&tmp[4] = *(const float4*)(src + 4);
                short8 hv, lv; split8(tmp, hv, lv);
                int dst = row * LDT + sch * 8;
                *(short8*)&Ah[dst] = hv;
                *(short8*)&Al[dst] = lv;
            }
            {   // B tile (row-guarded)
                int n = bn + row;
                if (n < N) {
                    const float* src = Bw + (size_t)n * ldb + k0 + sch * 8;
                    *(float4*)&tmp[0] = *(const float4*)src;
                    *(float4*)&tmp[4] = *(const float4*)(src + 4);
                } else {
#pragma unroll
                    for (int i = 0; i < 8; ++i) tmp[i] = 0.f;
                }
                short8 hv, lv; split8(tmp, hv, lv);
                int dst = row * LDT + sch * 8;
                *(short8*)&Bh[dst] = hv;
                *(short8*)&Bl[dst] = lv;
            }
        }
        __syncthreads();
#pragma unroll
        for (int ks = 0; ks < 2; ++ks) {
            const int koff = ks * 32 + (lane >> 4) * 8;
            const int arow = wr + (lane & 15);
            const int brow = wc + (lane & 15);
            short8 ah[4], al[4], bh[4], bl[4];
#pragma unroll
            for (int m = 0; m < 4; ++m) {
                ah[m] = *(const short8*)&Ah[(arow + m * 16) * LDT + koff];
                al[m] = *(const short8*)&Al[(arow + m * 16) * LDT + koff];
            }
#pragma unroll
            for (int n = 0; n < 4; ++n) {
                bh[n] = *(const short8*)&Bh[(brow + n * 16) * LDT + koff];
                bl[n] = *(const short8*)&Bl[(brow + n * 16) * LDT + koff];
            }
#pragma unroll
            for (int m = 0; m < 4; ++m)
#pragma unroll
                for (int n = 0; n < 4; ++n) {
                    acc[m][n] = mfma16(ah[m], bh[n], acc[m][n]);
                    acc[m][n] = mfma16(ah[m], bl[n], acc[m][n]);
                    acc[m][n] = mfma16(al[m], bh[n], acc[m][n]);
                }
        }
    }

    const int col0 = bn + wc + (lane & 15);
    const int row0 = bm + wr + ((lane >> 4) << 2);
#pragma unroll
    for (int n = 0; n < 4; ++n) {
        int col = col0 + n * 16;
        if (col < N) {
#pragma unroll
            for (int m = 0; m < 4; ++m)
#pragma unroll
                for (int ri = 0; ri < 4; ++ri)
                    C[(size_t)(row0 + m * 16 + ri) * ldc + col] = acc[m][n][ri];
        }
    }
}

// depthwise 3x3 conv (pad 1) on fp32 xBC cols of P, + bias + SiLU -> fp32 XC (group-local)
__global__ __launch_bounds__(256) void conv_silu(
    const float* __restrict__ P, const float* __restrict__ cw,
    const float* __restrict__ cb, float* __restrict__ XC)
{
    int c4 = threadIdx.x * 4;
    if (c4 >= CDIM) return;
    int l = blockIdx.x, bl = blockIdx.y;
    int h = l / WWD, w = l % WWD;
    float acc[4] = {cb[c4], cb[c4 + 1], cb[c4 + 2], cb[c4 + 3]};
    float wv[9][4];
#pragma unroll
    for (int tap = 0; tap < 9; ++tap)
#pragma unroll
        for (int j = 0; j < 4; ++j) wv[tap][j] = cw[(c4 + j) * 9 + tap];
    const float* base = P + (size_t)bl * LL * DPROJ + DINNER + c4;
#pragma unroll
    for (int kh = -1; kh <= 1; ++kh) {
        int h2 = h + kh;
        if ((unsigned)h2 >= HH) continue;
#pragma unroll
        for (int kw = -1; kw <= 1; ++kw) {
            int w2 = w + kw;
            if ((unsigned)w2 >= WWD) continue;
            float4 v = *(const float4*)&base[(size_t)(h2 * WWD + w2) * DPROJ];
            int tap = (kh + 1) * 3 + (kw + 1);
            acc[0] += wv[tap][0] * v.x;
            acc[1] += wv[tap][1] * v.y;
            acc[2] += wv[tap][2] * v.z;
            acc[3] += wv[tap][3] * v.w;
        }
    }
    float4 o;
    o.x = acc[0] / (1.f + __expf(-acc[0]));
    o.y = acc[1] / (1.f + __expf(-acc[1]));
    o.z = acc[2] / (1.f + __expf(-acc[2]));
    o.w = acc[3] / (1.f + __expf(-acc[3]));
    *(float4*)&XC[((size_t)bl * LL + l) * CDIM + c4] = o;
}

// coefg[bl][h][l] = softplus(dt_raw + dt_bias[h]) * (-exp(A_log[h]))   (group-local)
__global__ __launch_bounds__(256) void coef_kernel(
    const float* __restrict__ P, const float* __restrict__ dt_bias,
    const float* __restrict__ A_log, float* __restrict__ coefg)
{
    int idx = blockIdx.x * 256 + threadIdx.x;   // GRP*NH*LL total, exact
    int l = idx % LL;
    int h = (idx / LL) % NH;
    int bl = idx / (LL * NH);
    float x = P[((size_t)bl * LL + l) * DPROJ + DINNER + CDIM + h] + dt_bias[h];
    float sp = (x > 20.f) ? x : log1pf(__expf(x));
    coefg[idx] = -__expf(A_log[h]) * sp;
}

// KVg[bl,h,s,p] += sum_{l in chunk} B[l,s] * x[l,h*64+p] * coefg[bl,h,l]
__global__ __launch_bounds__(256) void kv_kernel(
    const float* __restrict__ XC, const float* __restrict__ coefg,
    float* __restrict__ KVg)
{
    int h  = blockIdx.x;
    int bl = blockIdx.y;
    int lbase = blockIdx.z * 448;
    __shared__ float Bsh[32][DSTATE];
    __shared__ float Xsh[32][HD];
    __shared__ float cf[32];
    const int t = threadIdx.x;
    const int p = t & 63;
    const int s0 = t >> 6;
    const int lq = t >> 4;
    const int sq = (t & 15) * 4;
    float acc[16] = {};
    const float* xbase = XC + (size_t)bl * LL * CDIM;
    const float* crow = coefg + ((size_t)bl * NH + h) * LL + lbase;

    for (int l0 = 0; l0 < 448; l0 += 32) {
#pragma unroll
        for (int rr = 0; rr < 32; rr += 16) {
            const float* r = xbase + (size_t)(lbase + l0 + lq + rr) * CDIM;
            *(float4*)&Bsh[lq + rr][sq] = *(const float4*)&r[DINNER + sq];
            *(float4*)&Xsh[lq + rr][sq] = *(const float4*)&r[h * HD + sq];
        }
        if (t < 32) cf[t] = crow[l0 + t];
        __syncthreads();
#pragma unroll
        for (int li = 0; li < 32; ++li) {
            float xv = Xsh[li][p] * cf[li];
            float4 b0v = *(const float4*)&Bsh[li][s0 * 16 + 0];
            float4 b1v = *(const float4*)&Bsh[li][s0 * 16 + 4];
            float4 b2v = *(const float4*)&Bsh[li][s0 * 16 + 8];
            float4 b3v = *(const float4*)&Bsh[li][s0 * 16 + 12];
            acc[0]  += b0v.x * xv; acc[1]  += b0v.y * xv; acc[2]  += b0v.z * xv; acc[3]  += b0v.w * xv;
            acc[4]  += b1v.x * xv; acc[5]  += b1v.y * xv; acc[6]  += b1v.z * xv; acc[7]  += b1v.w * xv;
            acc[8]  += b2v.x * xv; acc[9]  += b2v.y * xv; acc[10] += b2v.z * xv; acc[11] += b2v.w * xv;
            acc[12] += b3v.x * xv; acc[13] += b3v.y * xv; acc[14] += b3v.z * xv; acc[15] += b3v.w * xv;
        }
        __syncthreads();
    }
    float* out = KVg + ((size_t)bl * NH + h) * DSTATE * HD;
#pragma unroll
    for (int j = 0; j < 16; ++j)
        atomicAdd(&out[(size_t)(s0 * 16 + j) * HD + p], acc[j]);
}

// y = C@KV + x*D ; gate silu(z) ; LayerNorm(768) ; write y fp32 over z cols of P
__global__ __launch_bounds__(256) void yln_kernel(
    float* __restrict__ P, const float* __restrict__ XC,
    const float* __restrict__ KVg, const float* __restrict__ Dp,
    const float* __restrict__ ln_g, const float* __restrict__ ln_b)
{
    int lrow0 = blockIdx.x * 4;          // group-local row
    int bl = lrow0 / LL;
    const int t = threadIdx.x;
    __shared__ float Cs[4][64];
    __shared__ float rs1[4][4], rs2[4][4];
    {
        int r = t >> 6, s = t & 63;
        Cs[r][s] = XC[(size_t)(lrow0 + r) * CDIM + DINNER + DSTATE + s];
    }
    __syncthreads();

    float yv[3][4];
#pragma unroll
    for (int i = 0; i < 3; ++i) {
        int d = t + 256 * i;
        int h = d >> 6, p = d & 63;
        const float* kv = KVg + ((size_t)bl * NH + h) * DSTATE * HD + p;
        float dcoef = Dp[h];
        float acc[4];
#pragma unroll
        for (int r = 0; r < 4; ++r)
            acc[r] = XC[(size_t)(lrow0 + r) * CDIM + d] * dcoef;
        for (int s = 0; s < 64; ++s) {
            float kvv = kv[(size_t)s * HD];
#pragma unroll
            for (int r = 0; r < 4; ++r) acc[r] += Cs[r][s] * kvv;
        }
#pragma unroll
        for (int r = 0; r < 4; ++r) {
            float z = P[(size_t)(lrow0 + r) * DPROJ + d];
            float sz = z / (1.f + __expf(-z));
            yv[i][r] = acc[r] * sz;
        }
    }

#pragma unroll
    for (int r = 0; r < 4; ++r) {
        float s1 = yv[0][r] + yv[1][r] + yv[2][r];
        float s2 = yv[0][r]*yv[0][r] + yv[1][r]*yv[1][r] + yv[2][r]*yv[2][r];
        for (int off = 32; off; off >>= 1) {
            s1 += __shfl_down(s1, off);
            s2 += __shfl_down(s2, off);
        }
        if ((t & 63) == 0) { rs1[r][t >> 6] = s1; rs2[r][t >> 6] = s2; }
    }
    __syncthreads();

    float mu[4], rstd[4];
#pragma unroll
    for (int r = 0; r < 4; ++r) {
        float S1 = rs1[r][0] + rs1[r][1] + rs1[r][2] + rs1[r][3];
        float S2 = rs2[r][0] + rs2[r][1] + rs2[r][2] + rs2[r][3];
        mu[r] = S1 * (1.f / 768.f);
        float var = S2 * (1.f / 768.f) - mu[r] * mu[r];
        rstd[r] = rsqrtf(var + LNEPS);
    }

#pragma unroll
    for (int i = 0; i < 3; ++i) {
        int d = t + 256 * i;
        float g = ln_g[d], bb = ln_b[d];
#pragma unroll
        for (int r = 0; r < 4; ++r)
            P[(size_t)(lrow0 + r) * DPROJ + d] = (yv[i][r] - mu[r]) * rstd[r] * g + bb;
    }
}

extern "C" void kernel_launch(void* const* d_in, const int* in_sizes, int n_in,
                              void* d_out, int out_size, void* d_ws, size_t ws_size,
                              hipStream_t stream)
{
    const float* u       = (const float*)d_in[0];
    const float* W_in    = (const float*)d_in[1];
    const float* conv_w  = (const float*)d_in[2];
    const float* conv_b  = (const float*)d_in[3];
    const float* dt_bias = (const float*)d_in[4];
    const float* A_log   = (const float*)d_in[5];
    const float* Dp      = (const float*)d_in[6];
    const float* ln_g    = (const float*)d_in[7];
    const float* ln_b    = (const float*)d_in[8];
    const float* W_out   = (const float*)d_in[9];
    float* out = (float*)d_out;
    (void)ws_size;

    const int B = in_sizes[0] / (LL * DMODEL);   // 16

    // workspace (all fp32, ~130 MiB): per-group proj/conv buffers
    float* P     = (float*)d_ws;                    // GM*1676
    float* XC    = P + (size_t)GM * DPROJ;          // GM*896
    float* coefg = XC + (size_t)GM * CDIM;          // GRP*NH*LL
    float* KVg   = coefg + (size_t)GRP * NH * LL;   // GRP*NH*64*64

    for (int b0 = 0; b0 < B; b0 += GRP) {
        // 1) P = u_grp @ W_in^T  (fp32 via 3-term bf16-split MFMA)
        gemm_split<<<dim3(14, GM / 128), 256, 0, stream>>>(
            u + (size_t)b0 * LL * DMODEL, DMODEL, W_in, DMODEL, P, DPROJ, DPROJ, DMODEL);

        // 2) dt coefficients
        coef_kernel<<<(GRP * NH * LL) / 256, 256, 0, stream>>>(P, dt_bias, A_log, coefg);

        // 3) depthwise conv + SiLU
        conv_silu<<<dim3(LL, GRP), 256, 0, stream>>>(P, conv_w, conv_b, XC);

        // 4) KV einsum
        hipMemsetAsync(KVg, 0, (size_t)GRP * NH * DSTATE * HD * sizeof(float), stream);
        kv_kernel<<<dim3(NH, GRP, 7), 256, 0, stream>>>(XC, coefg, KVg);

        // 5) y = C@KV + x*D, gate, LayerNorm -> y fp32 into P cols 0..767
        yln_kernel<<<GM / 4, 256, 0, stream>>>(P, XC, KVg, Dp, ln_g, ln_b);

        // 6) out_grp = y @ W_out^T
        gemm_split<<<dim3(DMODEL / 128, GM / 128), 256, 0, stream>>>(
            P, DPROJ, W_out, DINNER, out + (size_t)b0 * LL * DMODEL, DMODEL, DMODEL, DINNER);
    }
}

// Round 5
// 1276.509 us; speedup vs baseline: 1.8000x; 1.0731x over previous
//
#include <hip/hip_runtime.h>
#include <hip/hip_bf16.h>

#define LL 3136
#define HH 56
#define WWD 56
#define DMODEL 384
#define DINNER 768
#define NH 12
#define HD 64
#define DSTATE 64
#define CDIM 896
#define DPROJ 1676
#define LNEPS 1e-5f
#define GRP 4
#define GM (GRP * LL)          // 12544 rows per group
#define LDT 72                 // padded LDS row stride (bf16 elems)

typedef __attribute__((ext_vector_type(8))) short short8;
typedef __attribute__((ext_vector_type(4))) float f32x4;

__device__ __forceinline__ float b2f(unsigned short u) {
    return __uint_as_float(((unsigned int)u) << 16);
}
__device__ __forceinline__ unsigned short f2b(float f) {
    __hip_bfloat16 h = __float2bfloat16(f);   // RNE
    return *reinterpret_cast<unsigned short*>(&h);
}

__device__ __forceinline__ f32x4 mfma16(short8 a, short8 b, f32x4 c) {
    return __builtin_amdgcn_mfma_f32_16x16x32_bf16(a, b, c, 0, 0, 0);
}

// elementwise RNE split: in -> hi bf16, lo bf16 (residual)
__global__ __launch_bounds__(256) void split_f32(
    const float* __restrict__ in, unsigned short* __restrict__ hi,
    unsigned short* __restrict__ lo, int n4)
{
    int i = blockIdx.x * 256 + threadIdx.x;
    if (i >= n4) return;
    float4 v = ((const float4*)in)[i];
    ushort4 h, l;
    h.x = f2b(v.x); l.x = f2b(v.x - b2f(h.x));
    h.y = f2b(v.y); l.y = f2b(v.y - b2f(h.y));
    h.z = f2b(v.z); l.z = f2b(v.z - b2f(h.z));
    h.w = f2b(v.w); l.w = f2b(v.w - b2f(h.w));
    ((ushort4*)hi)[i] = h;
    ((ushort4*)lo)[i] = l;
}

// C[m,n] = sum_k (Ah+Al)[m,k] * (Bh+Bl)[n,k] (3-term), pre-split bf16 operands, fp32 out.
// M full 128-tiles, N guarded, K multiple of 64.
__global__ __launch_bounds__(256, 2) void gemm_ps(
    const unsigned short* __restrict__ Ah, const unsigned short* __restrict__ Al, int lda,
    const unsigned short* __restrict__ Bh, const unsigned short* __restrict__ Bl, int ldb,
    float* __restrict__ C, int ldc, int N, int K)
{
    __shared__ __align__(16) unsigned short Ahs[128 * LDT], Als[128 * LDT];
    __shared__ __align__(16) unsigned short Bhs[128 * LDT], Bls[128 * LDT];
    const int t = threadIdx.x;
    const int bn = blockIdx.x * 128;
    const int bm = blockIdx.y * 128;
    const int lane = t & 63;
    const int w = t >> 6;
    const int wr = (w >> 1) * 64, wc = (w & 1) * 64;
    const int srow = t >> 3, sch = t & 7;

    f32x4 acc[4][4];
#pragma unroll
    for (int m = 0; m < 4; ++m)
#pragma unroll
        for (int n = 0; n < 4; ++n) acc[m][n] = (f32x4){0.f, 0.f, 0.f, 0.f};

    for (int k0 = 0; k0 < K; k0 += 64) {
        __syncthreads();
#pragma unroll
        for (int j = 0; j < 4; ++j) {
            int row = srow + 32 * j;
            int dst = row * LDT + sch * 8;
            {
                size_t off = (size_t)(bm + row) * lda + k0 + sch * 8;
                *(short8*)&Ahs[dst] = *(const short8*)&Ah[off];
                *(short8*)&Als[dst] = *(const short8*)&Al[off];
            }
            {
                int n = bn + row;
                if (n < N) {
                    size_t off = (size_t)n * ldb + k0 + sch * 8;
                    *(short8*)&Bhs[dst] = *(const short8*)&Bh[off];
                    *(short8*)&Bls[dst] = *(const short8*)&Bl[off];
                } else {
                    short8 z = (short8){0,0,0,0,0,0,0,0};
                    *(short8*)&Bhs[dst] = z;
                    *(short8*)&Bls[dst] = z;
                }
            }
        }
        __syncthreads();
#pragma unroll
        for (int ks = 0; ks < 2; ++ks) {
            const int koff = ks * 32 + (lane >> 4) * 8;
            const int arow = wr + (lane & 15);
            const int brow = wc + (lane & 15);
            short8 ah[4], al[4], bh[4], bl[4];
#pragma unroll
            for (int m = 0; m < 4; ++m) {
                ah[m] = *(const short8*)&Ahs[(arow + m * 16) * LDT + koff];
                al[m] = *(const short8*)&Als[(arow + m * 16) * LDT + koff];
            }
#pragma unroll
            for (int n = 0; n < 4; ++n) {
                bh[n] = *(const short8*)&Bhs[(brow + n * 16) * LDT + koff];
                bl[n] = *(const short8*)&Bls[(brow + n * 16) * LDT + koff];
            }
#pragma unroll
            for (int m = 0; m < 4; ++m)
#pragma unroll
                for (int n = 0; n < 4; ++n) {
                    acc[m][n] = mfma16(ah[m], bh[n], acc[m][n]);
                    acc[m][n] = mfma16(ah[m], bl[n], acc[m][n]);
                    acc[m][n] = mfma16(al[m], bh[n], acc[m][n]);
                }
        }
    }

    const int col0 = bn + wc + (lane & 15);
    const int row0 = bm + wr + ((lane >> 4) << 2);
#pragma unroll
    for (int n = 0; n < 4; ++n) {
        int col = col0 + n * 16;
        if (col < N) {
#pragma unroll
            for (int m = 0; m < 4; ++m)
#pragma unroll
                for (int ri = 0; ri < 4; ++ri)
                    C[(size_t)(row0 + m * 16 + ri) * ldc + col] = acc[m][n][ri];
        }
    }
}

// depthwise 3x3 conv (pad 1) on fp32 xBC cols of P, + bias + SiLU -> fp32 XC (group-local)
__global__ __launch_bounds__(256) void conv_silu(
    const float* __restrict__ P, const float* __restrict__ cw,
    const float* __restrict__ cb, float* __restrict__ XC)
{
    int c4 = threadIdx.x * 4;
    if (c4 >= CDIM) return;
    int l = blockIdx.x, bl = blockIdx.y;
    int h = l / WWD, w = l % WWD;
    float acc[4] = {cb[c4], cb[c4 + 1], cb[c4 + 2], cb[c4 + 3]};
    float wv[9][4];
#pragma unroll
    for (int tap = 0; tap < 9; ++tap)
#pragma unroll
        for (int j = 0; j < 4; ++j) wv[tap][j] = cw[(c4 + j) * 9 + tap];
    const float* base = P + (size_t)bl * LL * DPROJ + DINNER + c4;
#pragma unroll
    for (int kh = -1; kh <= 1; ++kh) {
        int h2 = h + kh;
        if ((unsigned)h2 >= HH) continue;
#pragma unroll
        for (int kw = -1; kw <= 1; ++kw) {
            int w2 = w + kw;
            if ((unsigned)w2 >= WWD) continue;
            float4 v = *(const float4*)&base[(size_t)(h2 * WWD + w2) * DPROJ];
            int tap = (kh + 1) * 3 + (kw + 1);
            acc[0] += wv[tap][0] * v.x;
            acc[1] += wv[tap][1] * v.y;
            acc[2] += wv[tap][2] * v.z;
            acc[3] += wv[tap][3] * v.w;
        }
    }
    float4 o;
    o.x = acc[0] / (1.f + __expf(-acc[0]));
    o.y = acc[1] / (1.f + __expf(-acc[1]));
    o.z = acc[2] / (1.f + __expf(-acc[2]));
    o.w = acc[3] / (1.f + __expf(-acc[3]));
    *(float4*)&XC[((size_t)bl * LL + l) * CDIM + c4] = o;
}

// coefg[bl][h][l] = softplus(dt_raw + dt_bias[h]) * (-exp(A_log[h]))   (group-local)
__global__ __launch_bounds__(256) void coef_kernel(
    const float* __restrict__ P, const float* __restrict__ dt_bias,
    const float* __restrict__ A_log, float* __restrict__ coefg)
{
    int idx = blockIdx.x * 256 + threadIdx.x;
    int l = idx % LL;
    int h = (idx / LL) % NH;
    int bl = idx / (LL * NH);
    float x = P[((size_t)bl * LL + l) * DPROJ + DINNER + CDIM + h] + dt_bias[h];
    float sp = (x > 20.f) ? x : log1pf(__expf(x));
    coefg[idx] = -__expf(A_log[h]) * sp;
}

// KVT[bl,h,p,s] += sum_{l in chunk} B[l,s] * x[l,h*64+p] * coefg[bl,h,l]  (TRANSPOSED layout)
__global__ __launch_bounds__(256) void kv_kernel(
    const float* __restrict__ XC, const float* __restrict__ coefg,
    float* __restrict__ KVT)
{
    int h  = blockIdx.x;
    int bl = blockIdx.y;
    int lbase = blockIdx.z * 448;
    __shared__ float Bsh[32][DSTATE];
    __shared__ float Xsh[32][HD];
    __shared__ float cf[32];
    const int t = threadIdx.x;
    const int ss = t & 63;          // lane owns state index s
    const int p0 = (t >> 6) * 16;   // wave owns p block
    const int lq = t >> 4;
    const int sq = (t & 15) * 4;
    float acc[16] = {};
    const float* xbase = XC + (size_t)bl * LL * CDIM;
    const float* crow = coefg + ((size_t)bl * NH + h) * LL + lbase;

    for (int l0 = 0; l0 < 448; l0 += 32) {
#pragma unroll
        for (int rr = 0; rr < 32; rr += 16) {
            const float* r = xbase + (size_t)(lbase + l0 + lq + rr) * CDIM;
            *(float4*)&Bsh[lq + rr][sq] = *(const float4*)&r[DINNER + sq];
            *(float4*)&Xsh[lq + rr][sq] = *(const float4*)&r[h * HD + sq];
        }
        if (t < 32) cf[t] = crow[l0 + t];
        __syncthreads();
#pragma unroll
        for (int li = 0; li < 32; ++li) {
            float bb = Bsh[li][ss] * cf[li];
            float4 x0 = *(const float4*)&Xsh[li][p0 + 0];
            float4 x1 = *(const float4*)&Xsh[li][p0 + 4];
            float4 x2 = *(const float4*)&Xsh[li][p0 + 8];
            float4 x3 = *(const float4*)&Xsh[li][p0 + 12];
            acc[0]  += x0.x * bb; acc[1]  += x0.y * bb; acc[2]  += x0.z * bb; acc[3]  += x0.w * bb;
            acc[4]  += x1.x * bb; acc[5]  += x1.y * bb; acc[6]  += x1.z * bb; acc[7]  += x1.w * bb;
            acc[8]  += x2.x * bb; acc[9]  += x2.y * bb; acc[10] += x2.z * bb; acc[11] += x2.w * bb;
            acc[12] += x3.x * bb; acc[13] += x3.y * bb; acc[14] += x3.z * bb; acc[15] += x3.w * bb;
        }
        __syncthreads();
    }
    float* outp = KVT + ((size_t)bl * NH + h) * HD * DSTATE;
#pragma unroll
    for (int j = 0; j < 16; ++j)
        atomicAdd(&outp[(size_t)(p0 + j) * DSTATE + ss], acc[j]);
}

// y = C@KV + x*D ; gate silu(z) ; LayerNorm(768) ; write y as bf16 hi|lo pair over z cols of P
__global__ __launch_bounds__(256, 4) void yln_kernel(
    float* __restrict__ P, const float* __restrict__ XC,
    const float* __restrict__ KVT, const float* __restrict__ Dp,
    const float* __restrict__ ln_g, const float* __restrict__ ln_b)
{
    int lrow0 = blockIdx.x * 4;          // group-local row
    int bl = lrow0 / LL;
    const int t = threadIdx.x;
    __shared__ float Cs[4][64];
    __shared__ float rs1[4][4], rs2[4][4];
    {
        int r = t >> 6, s = t & 63;
        Cs[r][s] = XC[(size_t)(lrow0 + r) * CDIM + DINNER + DSTATE + s];
    }
    __syncthreads();

    float yv[3][4];
#pragma unroll
    for (int i = 0; i < 3; ++i) {
        int d = t + 256 * i;
        int h = d >> 6, p = d & 63;
        const float* kvp = KVT + (((size_t)bl * NH + h) * HD + p) * DSTATE;
        float dcoef = Dp[h];
        float acc[4];
#pragma unroll
        for (int r = 0; r < 4; ++r)
            acc[r] = XC[(size_t)(lrow0 + r) * CDIM + d] * dcoef;
#pragma unroll 4
        for (int s4 = 0; s4 < 16; ++s4) {
            float4 kv4 = *(const float4*)&kvp[s4 * 4];
#pragma unroll
            for (int r = 0; r < 4; ++r) {
                float4 cs4 = *(const float4*)&Cs[r][s4 * 4];
                acc[r] += cs4.x * kv4.x + cs4.y * kv4.y + cs4.z * kv4.z + cs4.w * kv4.w;
            }
        }
#pragma unroll
        for (int r = 0; r < 4; ++r) {
            float z = P[(size_t)(lrow0 + r) * DPROJ + d];
            float sz = z / (1.f + __expf(-z));
            yv[i][r] = acc[r] * sz;
        }
    }

#pragma unroll
    for (int r = 0; r < 4; ++r) {
        float s1 = yv[0][r] + yv[1][r] + yv[2][r];
        float s2 = yv[0][r]*yv[0][r] + yv[1][r]*yv[1][r] + yv[2][r]*yv[2][r];
        for (int off = 32; off; off >>= 1) {
            s1 += __shfl_down(s1, off);
            s2 += __shfl_down(s2, off);
        }
        if ((t & 63) == 0) { rs1[r][t >> 6] = s1; rs2[r][t >> 6] = s2; }
    }
    __syncthreads();

    float mu[4], rstd[4];
#pragma unroll
    for (int r = 0; r < 4; ++r) {
        float S1 = rs1[r][0] + rs1[r][1] + rs1[r][2] + rs1[r][3];
        float S2 = rs2[r][0] + rs2[r][1] + rs2[r][2] + rs2[r][3];
        mu[r] = S1 * (1.f / 768.f);
        float var = S2 * (1.f / 768.f) - mu[r] * mu[r];
        rstd[r] = rsqrtf(var + LNEPS);
    }

#pragma unroll
    for (int i = 0; i < 3; ++i) {
        int d = t + 256 * i;
        float g = ln_g[d], bb = ln_b[d];
#pragma unroll
        for (int r = 0; r < 4; ++r) {
            float y = (yv[i][r] - mu[r]) * rstd[r] * g + bb;
            unsigned short hi = f2b(y);
            unsigned short lo = f2b(y - b2f(hi));
            unsigned short* prow = (unsigned short*)(P + (size_t)(lrow0 + r) * DPROJ);
            prow[d] = hi;
            prow[DINNER + d] = lo;
        }
    }
}

extern "C" void kernel_launch(void* const* d_in, const int* in_sizes, int n_in,
                              void* d_out, int out_size, void* d_ws, size_t ws_size,
                              hipStream_t stream)
{
    const float* u       = (const float*)d_in[0];
    const float* W_in    = (const float*)d_in[1];
    const float* conv_w  = (const float*)d_in[2];
    const float* conv_b  = (const float*)d_in[3];
    const float* dt_bias = (const float*)d_in[4];
    const float* A_log   = (const float*)d_in[5];
    const float* Dp      = (const float*)d_in[6];
    const float* ln_g    = (const float*)d_in[7];
    const float* ln_b    = (const float*)d_in[8];
    const float* W_out   = (const float*)d_in[9];
    float* out = (float*)d_out;
    (void)ws_size;

    const int B = in_sizes[0] / (LL * DMODEL);   // 16

    // workspace (~152 MiB)
    float* P     = (float*)d_ws;                        // GM*1676 f32
    float* XC    = P + (size_t)GM * DPROJ;              // GM*896 f32
    float* coefg = XC + (size_t)GM * CDIM;              // GRP*NH*LL f32
    float* KVT   = coefg + (size_t)GRP * NH * LL;       // GRP*NH*64*64 f32
    unsigned short* uh  = (unsigned short*)(KVT + (size_t)GRP * NH * HD * DSTATE);
    unsigned short* ul  = uh + (size_t)GM * DMODEL;     // GM*384 each
    unsigned short* Wih = ul + (size_t)GM * DMODEL;     // 1676*384
    unsigned short* Wil = Wih + (size_t)DPROJ * DMODEL;
    unsigned short* Woh = Wil + (size_t)DPROJ * DMODEL; // 384*768
    unsigned short* Wol = Woh + (size_t)DMODEL * DINNER;

    // one-time weight pre-splits
    {
        int n4 = DPROJ * DMODEL / 4;
        split_f32<<<(n4 + 255) / 256, 256, 0, stream>>>(W_in, Wih, Wil, n4);
        n4 = DMODEL * DINNER / 4;
        split_f32<<<(n4 + 255) / 256, 256, 0, stream>>>(W_out, Woh, Wol, n4);
    }

    for (int b0 = 0; b0 < B; b0 += GRP) {
        // 0) pre-split u group
        {
            int n4 = GM * DMODEL / 4;
            split_f32<<<(n4 + 255) / 256, 256, 0, stream>>>(
                u + (size_t)b0 * LL * DMODEL, uh, ul, n4);
        }

        // 1) P = u_grp @ W_in^T
        gemm_ps<<<dim3(14, GM / 128), 256, 0, stream>>>(
            uh, ul, DMODEL, Wih, Wil, DMODEL, P, DPROJ, DPROJ, DMODEL);

        // 2) dt coefficients
        coef_kernel<<<(GRP * NH * LL) / 256, 256, 0, stream>>>(P, dt_bias, A_log, coefg);

        // 3) depthwise conv + SiLU
        conv_silu<<<dim3(LL, GRP), 256, 0, stream>>>(P, conv_w, conv_b, XC);

        // 4) KV einsum (transposed KVT[p][s])
        hipMemsetAsync(KVT, 0, (size_t)GRP * NH * DSTATE * HD * sizeof(float), stream);
        kv_kernel<<<dim3(NH, GRP, 7), 256, 0, stream>>>(XC, coefg, KVT);

        // 5) y = C@KV + x*D, gate, LayerNorm -> y bf16 hi|lo into P z cols
        yln_kernel<<<GM / 4, 256, 0, stream>>>(P, XC, KVT, Dp, ln_g, ln_b);

        // 6) out_grp = y @ W_out^T  (A = packed hi/lo in P, lda = 3352 ushorts)
        gemm_ps<<<dim3(DMODEL / 128, GM / 128), 256, 0, stream>>>(
            (const unsigned short*)P, (const unsigned short*)P + DINNER, DPROJ * 2,
            Woh, Wol, DINNER,
            out + (size_t)b0 * LL * DMODEL, DMODEL, DMODEL, DINNER);
    }
}

// Round 6
// 1079.403 us; speedup vs baseline: 2.1287x; 1.1826x over previous
//
#include <hip/hip_runtime.h>
#include <hip/hip_bf16.h>

#define LL 3136
#define HH 56
#define WWD 56
#define DMODEL 384
#define DINNER 768
#define NH 12
#define HD 64
#define DSTATE 64
#define CDIM 896
#define DPROJ 1676
#define LNEPS 1e-5f
#define GRP 4
#define GM (GRP * LL)          // 12544 rows per group
#define LDT 72                 // padded LDS row stride (bf16 elems)

typedef __attribute__((ext_vector_type(8))) short short8;
typedef __attribute__((ext_vector_type(4))) float f32x4;

__device__ __forceinline__ float b2f(unsigned short u) {
    return __uint_as_float(((unsigned int)u) << 16);
}
__device__ __forceinline__ unsigned short f2b(float f) {
    __hip_bfloat16 h = __float2bfloat16(f);   // RNE
    return *reinterpret_cast<unsigned short*>(&h);
}

// RNE split: a = hi + lo + r, |r| <= 2^-16 |a|
__device__ __forceinline__ void split8(const float* __restrict__ f, short8& hv, short8& lv) {
#pragma unroll
    for (int i = 0; i < 8; ++i) {
        float a = f[i];
        unsigned short h = f2b(a);
        hv[i] = (short)h;
        float r = a - b2f(h);
        lv[i] = (short)f2b(r);
    }
}

__device__ __forceinline__ f32x4 mfma16(short8 a, short8 b, f32x4 c) {
    return __builtin_amdgcn_mfma_f32_16x16x32_bf16(a, b, c, 0, 0, 0);
}

// elementwise RNE split: in -> hi bf16, lo bf16 (residual)
__global__ __launch_bounds__(256) void split_f32(
    const float* __restrict__ in, unsigned short* __restrict__ hi,
    unsigned short* __restrict__ lo, int n4)
{
    int i = blockIdx.x * 256 + threadIdx.x;
    if (i >= n4) return;
    float4 v = ((const float4*)in)[i];
    ushort4 h, l;
    h.x = f2b(v.x); l.x = f2b(v.x - b2f(h.x));
    h.y = f2b(v.y); l.y = f2b(v.y - b2f(h.y));
    h.z = f2b(v.z); l.z = f2b(v.z - b2f(h.z));
    h.w = f2b(v.w); l.w = f2b(v.w - b2f(h.w));
    ((ushort4*)hi)[i] = h;
    ((ushort4*)lo)[i] = l;
}

// C[m,n] = sum_k (Ah+Al)[m,k] * (Bh+Bl)[n,k] (3-term), pre-split bf16 operands, fp32 out.
__global__ __launch_bounds__(256, 2) void gemm_ps(
    const unsigned short* __restrict__ Ah, const unsigned short* __restrict__ Al, int lda,
    const unsigned short* __restrict__ Bh, const unsigned short* __restrict__ Bl, int ldb,
    float* __restrict__ C, int ldc, int N, int K)
{
    __shared__ __align__(16) unsigned short Ahs[128 * LDT], Als[128 * LDT];
    __shared__ __align__(16) unsigned short Bhs[128 * LDT], Bls[128 * LDT];
    const int t = threadIdx.x;
    const int bn = blockIdx.x * 128;
    const int bm = blockIdx.y * 128;
    const int lane = t & 63;
    const int w = t >> 6;
    const int wr = (w >> 1) * 64, wc = (w & 1) * 64;
    const int srow = t >> 3, sch = t & 7;

    f32x4 acc[4][4];
#pragma unroll
    for (int m = 0; m < 4; ++m)
#pragma unroll
        for (int n = 0; n < 4; ++n) acc[m][n] = (f32x4){0.f, 0.f, 0.f, 0.f};

    for (int k0 = 0; k0 < K; k0 += 64) {
        __syncthreads();
#pragma unroll
        for (int j = 0; j < 4; ++j) {
            int row = srow + 32 * j;
            int dst = row * LDT + sch * 8;
            {
                size_t off = (size_t)(bm + row) * lda + k0 + sch * 8;
                *(short8*)&Ahs[dst] = *(const short8*)&Ah[off];
                *(short8*)&Als[dst] = *(const short8*)&Al[off];
            }
            {
                int n = bn + row;
                if (n < N) {
                    size_t off = (size_t)n * ldb + k0 + sch * 8;
                    *(short8*)&Bhs[dst] = *(const short8*)&Bh[off];
                    *(short8*)&Bls[dst] = *(const short8*)&Bl[off];
                } else {
                    short8 z = (short8){0,0,0,0,0,0,0,0};
                    *(short8*)&Bhs[dst] = z;
                    *(short8*)&Bls[dst] = z;
                }
            }
        }
        __syncthreads();
#pragma unroll
        for (int ks = 0; ks < 2; ++ks) {
            const int koff = ks * 32 + (lane >> 4) * 8;
            const int arow = wr + (lane & 15);
            const int brow = wc + (lane & 15);
            short8 ah[4], al[4], bh[4], bl[4];
#pragma unroll
            for (int m = 0; m < 4; ++m) {
                ah[m] = *(const short8*)&Ahs[(arow + m * 16) * LDT + koff];
                al[m] = *(const short8*)&Als[(arow + m * 16) * LDT + koff];
            }
#pragma unroll
            for (int n = 0; n < 4; ++n) {
                bh[n] = *(const short8*)&Bhs[(brow + n * 16) * LDT + koff];
                bl[n] = *(const short8*)&Bls[(brow + n * 16) * LDT + koff];
            }
#pragma unroll
            for (int m = 0; m < 4; ++m)
#pragma unroll
                for (int n = 0; n < 4; ++n) {
                    acc[m][n] = mfma16(ah[m], bh[n], acc[m][n]);
                    acc[m][n] = mfma16(ah[m], bl[n], acc[m][n]);
                    acc[m][n] = mfma16(al[m], bh[n], acc[m][n]);
                }
        }
    }

    const int col0 = bn + wc + (lane & 15);
    const int row0 = bm + wr + ((lane >> 4) << 2);
#pragma unroll
    for (int n = 0; n < 4; ++n) {
        int col = col0 + n * 16;
        if (col < N) {
#pragma unroll
            for (int m = 0; m < 4; ++m)
#pragma unroll
                for (int ri = 0; ri < 4; ++ri)
                    C[(size_t)(row0 + m * 16 + ri) * ldc + col] = acc[m][n][ri];
        }
    }
}

// depthwise 3x3 conv (pad 1) on fp32 xBC cols of P, + bias + SiLU -> fp32 XC (group-local)
__global__ __launch_bounds__(256) void conv_silu(
    const float* __restrict__ P, const float* __restrict__ cw,
    const float* __restrict__ cb, float* __restrict__ XC)
{
    int c4 = threadIdx.x * 4;
    if (c4 >= CDIM) return;
    int l = blockIdx.x, bl = blockIdx.y;
    int h = l / WWD, w = l % WWD;
    float acc[4] = {cb[c4], cb[c4 + 1], cb[c4 + 2], cb[c4 + 3]};
    float wv[9][4];
#pragma unroll
    for (int tap = 0; tap < 9; ++tap)
#pragma unroll
        for (int j = 0; j < 4; ++j) wv[tap][j] = cw[(c4 + j) * 9 + tap];
    const float* base = P + (size_t)bl * LL * DPROJ + DINNER + c4;
#pragma unroll
    for (int kh = -1; kh <= 1; ++kh) {
        int h2 = h + kh;
        if ((unsigned)h2 >= HH) continue;
#pragma unroll
        for (int kw = -1; kw <= 1; ++kw) {
            int w2 = w + kw;
            if ((unsigned)w2 >= WWD) continue;
            float4 v = *(const float4*)&base[(size_t)(h2 * WWD + w2) * DPROJ];
            int tap = (kh + 1) * 3 + (kw + 1);
            acc[0] += wv[tap][0] * v.x;
            acc[1] += wv[tap][1] * v.y;
            acc[2] += wv[tap][2] * v.z;
            acc[3] += wv[tap][3] * v.w;
        }
    }
    float4 o;
    o.x = acc[0] / (1.f + __expf(-acc[0]));
    o.y = acc[1] / (1.f + __expf(-acc[1]));
    o.z = acc[2] / (1.f + __expf(-acc[2]));
    o.w = acc[3] / (1.f + __expf(-acc[3]));
    *(float4*)&XC[((size_t)bl * LL + l) * CDIM + c4] = o;
}

// coefg[bl][h][l] = softplus(dt_raw + dt_bias[h]) * (-exp(A_log[h]))   (group-local)
__global__ __launch_bounds__(256) void coef_kernel(
    const float* __restrict__ P, const float* __restrict__ dt_bias,
    const float* __restrict__ A_log, float* __restrict__ coefg)
{
    int idx = blockIdx.x * 256 + threadIdx.x;
    int l = idx % LL;
    int h = (idx / LL) % NH;
    int bl = idx / (LL * NH);
    float x = P[((size_t)bl * LL + l) * DPROJ + DINNER + CDIM + h] + dt_bias[h];
    float sp = (x > 20.f) ? x : log1pf(__expf(x));
    coefg[idx] = -__expf(A_log[h]) * sp;
}

// KVT[bl,h,p,s] += sum_{l in chunk} B[l,s] * x[l,h*64+p] * coefg[bl,h,l]
__global__ __launch_bounds__(256) void kv_kernel(
    const float* __restrict__ XC, const float* __restrict__ coefg,
    float* __restrict__ KVT)
{
    int h  = blockIdx.x;
    int bl = blockIdx.y;
    int lbase = blockIdx.z * 448;
    __shared__ float Bsh[32][DSTATE];
    __shared__ float Xsh[32][HD];
    __shared__ float cf[32];
    const int t = threadIdx.x;
    const int ss = t & 63;          // lane owns state index s
    const int p0 = (t >> 6) * 16;   // wave owns p block
    const int lq = t >> 4;
    const int sq = (t & 15) * 4;
    float acc[16] = {};
    const float* xbase = XC + (size_t)bl * LL * CDIM;
    const float* crow = coefg + ((size_t)bl * NH + h) * LL + lbase;

    for (int l0 = 0; l0 < 448; l0 += 32) {
#pragma unroll
        for (int rr = 0; rr < 32; rr += 16) {
            const float* r = xbase + (size_t)(lbase + l0 + lq + rr) * CDIM;
            *(float4*)&Bsh[lq + rr][sq] = *(const float4*)&r[DINNER + sq];
            *(float4*)&Xsh[lq + rr][sq] = *(const float4*)&r[h * HD + sq];
        }
        if (t < 32) cf[t] = crow[l0 + t];
        __syncthreads();
#pragma unroll
        for (int li = 0; li < 32; ++li) {
            float bb = Bsh[li][ss] * cf[li];
            float4 x0 = *(const float4*)&Xsh[li][p0 + 0];
            float4 x1 = *(const float4*)&Xsh[li][p0 + 4];
            float4 x2 = *(const float4*)&Xsh[li][p0 + 8];
            float4 x3 = *(const float4*)&Xsh[li][p0 + 12];
            acc[0]  += x0.x * bb; acc[1]  += x0.y * bb; acc[2]  += x0.z * bb; acc[3]  += x0.w * bb;
            acc[4]  += x1.x * bb; acc[5]  += x1.y * bb; acc[6]  += x1.z * bb; acc[7]  += x1.w * bb;
            acc[8]  += x2.x * bb; acc[9]  += x2.y * bb; acc[10] += x2.z * bb; acc[11] += x2.w * bb;
            acc[12] += x3.x * bb; acc[13] += x3.y * bb; acc[14] += x3.z * bb; acc[15] += x3.w * bb;
        }
        __syncthreads();
    }
    float* outp = KVT + ((size_t)bl * NH + h) * HD * DSTATE;
#pragma unroll
    for (int j = 0; j < 16; ++j)
        atomicAdd(&outp[(size_t)(p0 + j) * DSTATE + ss], acc[j]);
}

// Yg = Cmat @ KVcat + x*D, gated by silu(z); fp32 yg written in-place over z cols of P.
// MFMA, no LDS: A = C cols of XC (K-contig), B = KVT rows (K-contig), 3-term split.
// Tile: M=64 (49 per bl), N=128 (2 heads), K=64. 4 waves, each 64 rows x 32 cols.
__global__ __launch_bounds__(256) void ckv_gate(
    float* __restrict__ P, const float* __restrict__ XC,
    const float* __restrict__ KVT, const float* __restrict__ Dp)
{
    const int t = threadIdx.x;
    const int lane = t & 63;
    const int w = t >> 6;
    const int bn = blockIdx.x * 128;
    const int mt = blockIdx.y;       // 0..48
    const int bl = blockIdx.z;
    const int wc = w * 32;
    const int l15 = lane & 15;
    const int kq = (lane >> 4) * 8;

    f32x4 acc[4][2];
#pragma unroll
    for (int m = 0; m < 4; ++m)
#pragma unroll
        for (int n = 0; n < 2; ++n) acc[m][n] = (f32x4){0.f, 0.f, 0.f, 0.f};

    const size_t rbase = (size_t)bl * LL + mt * 64;
    const float* Cbase = XC + rbase * CDIM + (DINNER + DSTATE);

    const float* Bptr[2];
    float dcoef[2];
    int dglob[2];
#pragma unroll
    for (int n = 0; n < 2; ++n) {
        int d = bn + wc + n * 16 + l15;
        dglob[n] = d;
        int h = d >> 6, p = d & 63;
        Bptr[n] = KVT + (((size_t)bl * NH + h) * HD + p) * DSTATE;
        dcoef[n] = Dp[h];
    }

#pragma unroll
    for (int ks = 0; ks < 2; ++ks) {
        const int koff = ks * 32 + kq;
        short8 ah[4], al[4];
#pragma unroll
        for (int m = 0; m < 4; ++m) {
            float tmp[8];
            const float* src = Cbase + (size_t)(l15 + m * 16) * CDIM + koff;
            *(float4*)&tmp[0] = *(const float4*)src;
            *(float4*)&tmp[4] = *(const float4*)(src + 4);
            split8(tmp, ah[m], al[m]);
        }
        short8 bh[2], bl8[2];
#pragma unroll
        for (int n = 0; n < 2; ++n) {
            float tmp[8];
            *(float4*)&tmp[0] = *(const float4*)&Bptr[n][koff];
            *(float4*)&tmp[4] = *(const float4*)&Bptr[n][koff + 4];
            split8(tmp, bh[n], bl8[n]);
        }
#pragma unroll
        for (int m = 0; m < 4; ++m)
#pragma unroll
            for (int n = 0; n < 2; ++n) {
                acc[m][n] = mfma16(ah[m], bh[n], acc[m][n]);
                acc[m][n] = mfma16(ah[m], bl8[n], acc[m][n]);
                acc[m][n] = mfma16(al[m], bh[n], acc[m][n]);
            }
    }

    const int r0 = (lane >> 4) << 2;
#pragma unroll
    for (int m = 0; m < 4; ++m)
#pragma unroll
        for (int ri = 0; ri < 4; ++ri) {
            size_t grow = rbase + m * 16 + r0 + ri;
#pragma unroll
            for (int n = 0; n < 2; ++n) {
                int d = dglob[n];
                float x = XC[grow * CDIM + d];
                float* zp = P + grow * DPROJ + d;
                float z = *zp;
                float sz = z / (1.f + __expf(-z));
                *zp = (acc[m][n][ri] + x * dcoef[n]) * sz;
            }
        }
}

// LayerNorm(768) over yg rows in P z-region; write bf16 hi|lo pair in-place
__global__ __launch_bounds__(256, 4) void ln_kernel(
    float* __restrict__ P, const float* __restrict__ ln_g, const float* __restrict__ ln_b)
{
    int lrow0 = blockIdx.x * 4;
    const int t = threadIdx.x;
    __shared__ float rs1[4][4], rs2[4][4];

    float yv[3][4];
#pragma unroll
    for (int i = 0; i < 3; ++i) {
        int d = t + 256 * i;
#pragma unroll
        for (int r = 0; r < 4; ++r)
            yv[i][r] = P[(size_t)(lrow0 + r) * DPROJ + d];
    }

#pragma unroll
    for (int r = 0; r < 4; ++r) {
        float s1 = yv[0][r] + yv[1][r] + yv[2][r];
        float s2 = yv[0][r]*yv[0][r] + yv[1][r]*yv[1][r] + yv[2][r]*yv[2][r];
        for (int off = 32; off; off >>= 1) {
            s1 += __shfl_down(s1, off);
            s2 += __shfl_down(s2, off);
        }
        if ((t & 63) == 0) { rs1[r][t >> 6] = s1; rs2[r][t >> 6] = s2; }
    }
    __syncthreads();

    float mu[4], rstd[4];
#pragma unroll
    for (int r = 0; r < 4; ++r) {
        float S1 = rs1[r][0] + rs1[r][1] + rs1[r][2] + rs1[r][3];
        float S2 = rs2[r][0] + rs2[r][1] + rs2[r][2] + rs2[r][3];
        mu[r] = S1 * (1.f / 768.f);
        float var = S2 * (1.f / 768.f) - mu[r] * mu[r];
        rstd[r] = rsqrtf(var + LNEPS);
    }

#pragma unroll
    for (int i = 0; i < 3; ++i) {
        int d = t + 256 * i;
        float g = ln_g[d], bb = ln_b[d];
#pragma unroll
        for (int r = 0; r < 4; ++r) {
            float y = (yv[i][r] - mu[r]) * rstd[r] * g + bb;
            unsigned short hi = f2b(y);
            unsigned short lo = f2b(y - b2f(hi));
            unsigned short* prow = (unsigned short*)(P + (size_t)(lrow0 + r) * DPROJ);
            prow[d] = hi;
            prow[DINNER + d] = lo;
        }
    }
}

extern "C" void kernel_launch(void* const* d_in, const int* in_sizes, int n_in,
                              void* d_out, int out_size, void* d_ws, size_t ws_size,
                              hipStream_t stream)
{
    const float* u       = (const float*)d_in[0];
    const float* W_in    = (const float*)d_in[1];
    const float* conv_w  = (const float*)d_in[2];
    const float* conv_b  = (const float*)d_in[3];
    const float* dt_bias = (const float*)d_in[4];
    const float* A_log   = (const float*)d_in[5];
    const float* Dp      = (const float*)d_in[6];
    const float* ln_g    = (const float*)d_in[7];
    const float* ln_b    = (const float*)d_in[8];
    const float* W_out   = (const float*)d_in[9];
    float* out = (float*)d_out;
    (void)ws_size;

    const int B = in_sizes[0] / (LL * DMODEL);   // 16

    // workspace (~152 MiB)
    float* P     = (float*)d_ws;                        // GM*1676 f32
    float* XC    = P + (size_t)GM * DPROJ;              // GM*896 f32
    float* coefg = XC + (size_t)GM * CDIM;              // GRP*NH*LL f32
    float* KVT   = coefg + (size_t)GRP * NH * LL;       // GRP*NH*64*64 f32
    unsigned short* uh  = (unsigned short*)(KVT + (size_t)GRP * NH * HD * DSTATE);
    unsigned short* ul  = uh + (size_t)GM * DMODEL;     // GM*384 each
    unsigned short* Wih = ul + (size_t)GM * DMODEL;     // 1676*384
    unsigned short* Wil = Wih + (size_t)DPROJ * DMODEL;
    unsigned short* Woh = Wil + (size_t)DPROJ * DMODEL; // 384*768
    unsigned short* Wol = Woh + (size_t)DMODEL * DINNER;

    // one-time weight pre-splits
    {
        int n4 = DPROJ * DMODEL / 4;
        split_f32<<<(n4 + 255) / 256, 256, 0, stream>>>(W_in, Wih, Wil, n4);
        n4 = DMODEL * DINNER / 4;
        split_f32<<<(n4 + 255) / 256, 256, 0, stream>>>(W_out, Woh, Wol, n4);
    }

    for (int b0 = 0; b0 < B; b0 += GRP) {
        // 0) pre-split u group
        {
            int n4 = GM * DMODEL / 4;
            split_f32<<<(n4 + 255) / 256, 256, 0, stream>>>(
                u + (size_t)b0 * LL * DMODEL, uh, ul, n4);
        }

        // 1) P = u_grp @ W_in^T
        gemm_ps<<<dim3(14, GM / 128), 256, 0, stream>>>(
            uh, ul, DMODEL, Wih, Wil, DMODEL, P, DPROJ, DPROJ, DMODEL);

        // 2) dt coefficients
        coef_kernel<<<(GRP * NH * LL) / 256, 256, 0, stream>>>(P, dt_bias, A_log, coefg);

        // 3) depthwise conv + SiLU
        conv_silu<<<dim3(LL, GRP), 256, 0, stream>>>(P, conv_w, conv_b, XC);

        // 4) KV einsum (transposed KVT[p][s])
        hipMemsetAsync(KVT, 0, (size_t)GRP * NH * DSTATE * HD * sizeof(float), stream);
        kv_kernel<<<dim3(NH, GRP, 7), 256, 0, stream>>>(XC, coefg, KVT);

        // 5a) yg = (C@KVcat + x*D) * silu(z)  (MFMA, in-place over z cols of P)
        ckv_gate<<<dim3(6, 49, GRP), 256, 0, stream>>>(P, XC, KVT, Dp);

        // 5b) LayerNorm -> y bf16 hi|lo into P z cols
        ln_kernel<<<GM / 4, 256, 0, stream>>>(P, ln_g, ln_b);

        // 6) out_grp = y @ W_out^T  (A = packed hi/lo in P, lda = 3352 ushorts)
        gemm_ps<<<dim3(DMODEL / 128, GM / 128), 256, 0, stream>>>(
            (const unsigned short*)P, (const unsigned short*)P + DINNER, DPROJ * 2,
            Woh, Wol, DINNER,
            out + (size_t)b0 * LL * DMODEL, DMODEL, DMODEL, DINNER);
    }
}

// Round 7
// 1012.045 us; speedup vs baseline: 2.2703x; 1.0666x over previous
//
#include <hip/hip_runtime.h>
#include <hip/hip_bf16.h>

#define LL 3136
#define HH 56
#define WWD 56
#define DMODEL 384
#define DINNER 768
#define NH 12
#define HD 64
#define DSTATE 64
#define CDIM 896
#define DPROJ 1676
#define LNEPS 1e-5f
#define GRP 4
#define GM (GRP * LL)          // 12544 rows per group

typedef __attribute__((ext_vector_type(8))) short short8;
typedef __attribute__((ext_vector_type(4))) float f32x4;

__device__ __forceinline__ float b2f(unsigned short u) {
    return __uint_as_float(((unsigned int)u) << 16);
}
__device__ __forceinline__ unsigned short f2b(float f) {
    __hip_bfloat16 h = __float2bfloat16(f);   // RNE
    return *reinterpret_cast<unsigned short*>(&h);
}

// RNE split: a = hi + lo + r, |r| <= 2^-16 |a|
__device__ __forceinline__ void split8(const float* __restrict__ f, short8& hv, short8& lv) {
#pragma unroll
    for (int i = 0; i < 8; ++i) {
        float a = f[i];
        unsigned short h = f2b(a);
        hv[i] = (short)h;
        float r = a - b2f(h);
        lv[i] = (short)f2b(r);
    }
}

__device__ __forceinline__ f32x4 mfma16(short8 a, short8 b, f32x4 c) {
    return __builtin_amdgcn_mfma_f32_16x16x32_bf16(a, b, c, 0, 0, 0);
}

// async global->LDS, 16B per lane; dest = lds base (wave-uniform) + lane*16
__device__ __forceinline__ void gload16(const unsigned short* g, unsigned short* l) {
    __builtin_amdgcn_global_load_lds(
        (const __attribute__((address_space(1))) unsigned int*)g,
        (__attribute__((address_space(3))) unsigned int*)l, 16, 0, 0);
}

// elementwise RNE split: in -> hi bf16, lo bf16 (residual)
__global__ __launch_bounds__(256) void split_f32(
    const float* __restrict__ in, unsigned short* __restrict__ hi,
    unsigned short* __restrict__ lo, int n4)
{
    int i = blockIdx.x * 256 + threadIdx.x;
    if (i >= n4) return;
    float4 v = ((const float4*)in)[i];
    ushort4 h, l;
    h.x = f2b(v.x); l.x = f2b(v.x - b2f(h.x));
    h.y = f2b(v.y); l.y = f2b(v.y - b2f(h.y));
    h.z = f2b(v.z); l.z = f2b(v.z - b2f(h.z));
    h.w = f2b(v.w); l.w = f2b(v.w - b2f(h.w));
    ((ushort4*)hi)[i] = h;
    ((ushort4*)lo)[i] = l;
}

// C[m,n] = sum_k (Ah+Al)[m,k]*(Bh+Bl)[n,k] (3-term), pre-split bf16 operands, fp32 out.
// m97 structure: global_load_lds dwordx4 staging, linear LDS + XOR granule swizzle.
// Tile: BM = MT*32 rows x 128 cols, BK=64. 4 waves, each (MT*16) x 64 output.
template<int MT>
__global__ __launch_bounds__(256) void gemm_ps(
    const unsigned short* __restrict__ Ah, const unsigned short* __restrict__ Al, int lda,
    const unsigned short* __restrict__ Bh, const unsigned short* __restrict__ Bl, int ldb,
    float* __restrict__ C, int ldc, int N, int K)
{
    constexpr int BM = MT * 32;
    __shared__ __align__(16) unsigned short Ahs[BM * 64], Als[BM * 64];
    __shared__ __align__(16) unsigned short Bhs[128 * 64], Bls[128 * 64];
    const int t = threadIdx.x;
    const int lane = t & 63;
    const int w = t >> 6;
    const int bn = blockIdx.x * 128;
    const int bm = blockIdx.y * BM;
    const int wr = (w >> 1) * (MT * 16);
    const int wc = (w & 1) * 64;
    const int l15 = lane & 15;
    const int g   = lane >> 4;        // fragment granule col 0..3
    const int srow = lane >> 3;       // staging row within 8-row issue
    const int slot = lane & 7;        // staging granule slot 0..7

    f32x4 acc[MT][4];
#pragma unroll
    for (int m = 0; m < MT; ++m)
#pragma unroll
        for (int n = 0; n < 4; ++n) acc[m][n] = (f32x4){0.f, 0.f, 0.f, 0.f};

    for (int k0 = 0; k0 < K; k0 += 64) {
        // ---- stage tiles: each issue covers 8 rows x 64 cols (1KB) per array ----
#pragma unroll
        for (int it = 0; it < MT; ++it) {            // A: BM rows, 4 waves
            int rowblk = w * (8 * MT) + it * 8;
            int row = rowblk + srow;
            int sl = (slot ^ (row & 7)) * 8;         // pre-swizzled source granule
            size_t goff = (size_t)(bm + row) * lda + k0 + sl;
            gload16(Ah + goff, Ahs + rowblk * 64);
            gload16(Al + goff, Als + rowblk * 64);
        }
#pragma unroll
        for (int it = 0; it < 4; ++it) {             // B: 128 rows
            int rowblk = w * 32 + it * 8;
            int row = rowblk + srow;
            int n = bn + row; if (n > N - 1) n = N - 1;   // clamp (garbage cols unwritten)
            int sl = (slot ^ (row & 7)) * 8;
            size_t goff = (size_t)n * ldb + k0 + sl;
            gload16(Bh + goff, Bhs + rowblk * 64);
            gload16(Bl + goff, Bls + rowblk * 64);
        }
        __syncthreads();   // compiler drains vmcnt before barrier

        // ---- compute ----
#pragma unroll
        for (int ks = 0; ks < 2; ++ks) {
            short8 ah[MT], al[MT], bh[4], blv[4];
#pragma unroll
            for (int m = 0; m < MT; ++m) {
                int arow = wr + m * 16 + l15;
                int off = arow * 64 + (((ks * 4 + g) ^ (arow & 7)) << 3);
                ah[m] = *(const short8*)&Ahs[off];
                al[m] = *(const short8*)&Als[off];
            }
#pragma unroll
            for (int n = 0; n < 4; ++n) {
                int brow = wc + n * 16 + l15;
                int off = brow * 64 + (((ks * 4 + g) ^ (brow & 7)) << 3);
                bh[n]  = *(const short8*)&Bhs[off];
                blv[n] = *(const short8*)&Bls[off];
            }
#pragma unroll
            for (int m = 0; m < MT; ++m)
#pragma unroll
                for (int n = 0; n < 4; ++n) {
                    acc[m][n] = mfma16(ah[m], bh[n], acc[m][n]);
                    acc[m][n] = mfma16(ah[m], blv[n], acc[m][n]);
                    acc[m][n] = mfma16(al[m], bh[n], acc[m][n]);
                }
        }
        __syncthreads();
    }

    const int col0 = bn + wc + l15;
    const int row0 = bm + wr + (g << 2);
#pragma unroll
    for (int n = 0; n < 4; ++n) {
        int col = col0 + n * 16;
        if (col < N) {
#pragma unroll
            for (int m = 0; m < MT; ++m)
#pragma unroll
                for (int ri = 0; ri < 4; ++ri)
                    C[(size_t)(row0 + m * 16 + ri) * ldc + col] = acc[m][n][ri];
        }
    }
}

// depthwise 3x3 conv (pad 1) on fp32 xBC cols of P, + bias + SiLU -> fp32 XC (group-local)
__global__ __launch_bounds__(256) void conv_silu(
    const float* __restrict__ P, const float* __restrict__ cw,
    const float* __restrict__ cb, float* __restrict__ XC)
{
    int c4 = threadIdx.x * 4;
    if (c4 >= CDIM) return;
    int l = blockIdx.x, bl = blockIdx.y;
    int h = l / WWD, w = l % WWD;
    float acc[4] = {cb[c4], cb[c4 + 1], cb[c4 + 2], cb[c4 + 3]};
    float wv[9][4];
#pragma unroll
    for (int tap = 0; tap < 9; ++tap)
#pragma unroll
        for (int j = 0; j < 4; ++j) wv[tap][j] = cw[(c4 + j) * 9 + tap];
    const float* base = P + (size_t)bl * LL * DPROJ + DINNER + c4;
#pragma unroll
    for (int kh = -1; kh <= 1; ++kh) {
        int h2 = h + kh;
        if ((unsigned)h2 >= HH) continue;
#pragma unroll
        for (int kw = -1; kw <= 1; ++kw) {
            int w2 = w + kw;
            if ((unsigned)w2 >= WWD) continue;
            float4 v = *(const float4*)&base[(size_t)(h2 * WWD + w2) * DPROJ];
            int tap = (kh + 1) * 3 + (kw + 1);
            acc[0] += wv[tap][0] * v.x;
            acc[1] += wv[tap][1] * v.y;
            acc[2] += wv[tap][2] * v.z;
            acc[3] += wv[tap][3] * v.w;
        }
    }
    float4 o;
    o.x = acc[0] / (1.f + __expf(-acc[0]));
    o.y = acc[1] / (1.f + __expf(-acc[1]));
    o.z = acc[2] / (1.f + __expf(-acc[2]));
    o.w = acc[3] / (1.f + __expf(-acc[3]));
    *(float4*)&XC[((size_t)bl * LL + l) * CDIM + c4] = o;
}

// coefg[bl][h][l] = softplus(dt_raw + dt_bias[h]) * (-exp(A_log[h]))   (group-local)
__global__ __launch_bounds__(256) void coef_kernel(
    const float* __restrict__ P, const float* __restrict__ dt_bias,
    const float* __restrict__ A_log, float* __restrict__ coefg)
{
    int idx = blockIdx.x * 256 + threadIdx.x;
    int l = idx % LL;
    int h = (idx / LL) % NH;
    int bl = idx / (LL * NH);
    float x = P[((size_t)bl * LL + l) * DPROJ + DINNER + CDIM + h] + dt_bias[h];
    float sp = (x > 20.f) ? x : log1pf(__expf(x));
    coefg[idx] = -__expf(A_log[h]) * sp;
}

// KVT[bl,h,p,s] += sum_{l in chunk} B[l,s] * x[l,h*64+p] * coefg[bl,h,l]
__global__ __launch_bounds__(256) void kv_kernel(
    const float* __restrict__ XC, const float* __restrict__ coefg,
    float* __restrict__ KVT)
{
    int h  = blockIdx.x;
    int bl = blockIdx.y;
    int lbase = blockIdx.z * 448;
    __shared__ float Bsh[32][DSTATE];
    __shared__ float Xsh[32][HD];
    __shared__ float cf[32];
    const int t = threadIdx.x;
    const int ss = t & 63;          // lane owns state index s
    const int p0 = (t >> 6) * 16;   // wave owns p block
    const int lq = t >> 4;
    const int sq = (t & 15) * 4;
    float acc[16] = {};
    const float* xbase = XC + (size_t)bl * LL * CDIM;
    const float* crow = coefg + ((size_t)bl * NH + h) * LL + lbase;

    for (int l0 = 0; l0 < 448; l0 += 32) {
#pragma unroll
        for (int rr = 0; rr < 32; rr += 16) {
            const float* r = xbase + (size_t)(lbase + l0 + lq + rr) * CDIM;
            *(float4*)&Bsh[lq + rr][sq] = *(const float4*)&r[DINNER + sq];
            *(float4*)&Xsh[lq + rr][sq] = *(const float4*)&r[h * HD + sq];
        }
        if (t < 32) cf[t] = crow[l0 + t];
        __syncthreads();
#pragma unroll
        for (int li = 0; li < 32; ++li) {
            float bb = Bsh[li][ss] * cf[li];
            float4 x0 = *(const float4*)&Xsh[li][p0 + 0];
            float4 x1 = *(const float4*)&Xsh[li][p0 + 4];
            float4 x2 = *(const float4*)&Xsh[li][p0 + 8];
            float4 x3 = *(const float4*)&Xsh[li][p0 + 12];
            acc[0]  += x0.x * bb; acc[1]  += x0.y * bb; acc[2]  += x0.z * bb; acc[3]  += x0.w * bb;
            acc[4]  += x1.x * bb; acc[5]  += x1.y * bb; acc[6]  += x1.z * bb; acc[7]  += x1.w * bb;
            acc[8]  += x2.x * bb; acc[9]  += x2.y * bb; acc[10] += x2.z * bb; acc[11] += x2.w * bb;
            acc[12] += x3.x * bb; acc[13] += x3.y * bb; acc[14] += x3.z * bb; acc[15] += x3.w * bb;
        }
        __syncthreads();
    }
    float* outp = KVT + ((size_t)bl * NH + h) * HD * DSTATE;
#pragma unroll
    for (int j = 0; j < 16; ++j)
        atomicAdd(&outp[(size_t)(p0 + j) * DSTATE + ss], acc[j]);
}

// Yg = Cmat @ KVcat + x*D, gated by silu(z); fp32 yg written in-place over z cols of P.
__global__ __launch_bounds__(256) void ckv_gate(
    float* __restrict__ P, const float* __restrict__ XC,
    const float* __restrict__ KVT, const float* __restrict__ Dp)
{
    const int t = threadIdx.x;
    const int lane = t & 63;
    const int w = t >> 6;
    const int bn = blockIdx.x * 128;
    const int mt = blockIdx.y;       // 0..48
    const int bl = blockIdx.z;
    const int wc = w * 32;
    const int l15 = lane & 15;
    const int kq = (lane >> 4) * 8;

    f32x4 acc[4][2];
#pragma unroll
    for (int m = 0; m < 4; ++m)
#pragma unroll
        for (int n = 0; n < 2; ++n) acc[m][n] = (f32x4){0.f, 0.f, 0.f, 0.f};

    const size_t rbase = (size_t)bl * LL + mt * 64;
    const float* Cbase = XC + rbase * CDIM + (DINNER + DSTATE);

    const float* Bptr[2];
    float dcoef[2];
    int dglob[2];
#pragma unroll
    for (int n = 0; n < 2; ++n) {
        int d = bn + wc + n * 16 + l15;
        dglob[n] = d;
        int h = d >> 6, p = d & 63;
        Bptr[n] = KVT + (((size_t)bl * NH + h) * HD + p) * DSTATE;
        dcoef[n] = Dp[h];
    }

#pragma unroll
    for (int ks = 0; ks < 2; ++ks) {
        const int koff = ks * 32 + kq;
        short8 ah[4], al[4];
#pragma unroll
        for (int m = 0; m < 4; ++m) {
            float tmp[8];
            const float* src = Cbase + (size_t)(l15 + m * 16) * CDIM + koff;
            *(float4*)&tmp[0] = *(const float4*)src;
            *(float4*)&tmp[4] = *(const float4*)(src + 4);
            split8(tmp, ah[m], al[m]);
        }
        short8 bh[2], bl8[2];
#pragma unroll
        for (int n = 0; n < 2; ++n) {
            float tmp[8];
            *(float4*)&tmp[0] = *(const float4*)&Bptr[n][koff];
            *(float4*)&tmp[4] = *(const float4*)&Bptr[n][koff + 4];
            split8(tmp, bh[n], bl8[n]);
        }
#pragma unroll
        for (int m = 0; m < 4; ++m)
#pragma unroll
            for (int n = 0; n < 2; ++n) {
                acc[m][n] = mfma16(ah[m], bh[n], acc[m][n]);
                acc[m][n] = mfma16(ah[m], bl8[n], acc[m][n]);
                acc[m][n] = mfma16(al[m], bh[n], acc[m][n]);
            }
    }

    const int r0 = (lane >> 4) << 2;
#pragma unroll
    for (int m = 0; m < 4; ++m)
#pragma unroll
        for (int ri = 0; ri < 4; ++ri) {
            size_t grow = rbase + m * 16 + r0 + ri;
#pragma unroll
            for (int n = 0; n < 2; ++n) {
                int d = dglob[n];
                float x = XC[grow * CDIM + d];
                float* zp = P + grow * DPROJ + d;
                float z = *zp;
                float sz = z / (1.f + __expf(-z));
                *zp = (acc[m][n][ri] + x * dcoef[n]) * sz;
            }
        }
}

// LayerNorm(768) over yg rows in P z-region; write bf16 hi|lo pair in-place
__global__ __launch_bounds__(256, 4) void ln_kernel(
    float* __restrict__ P, const float* __restrict__ ln_g, const float* __restrict__ ln_b)
{
    int lrow0 = blockIdx.x * 4;
    const int t = threadIdx.x;
    __shared__ float rs1[4][4], rs2[4][4];

    float yv[3][4];
#pragma unroll
    for (int i = 0; i < 3; ++i) {
        int d = t + 256 * i;
#pragma unroll
        for (int r = 0; r < 4; ++r)
            yv[i][r] = P[(size_t)(lrow0 + r) * DPROJ + d];
    }

#pragma unroll
    for (int r = 0; r < 4; ++r) {
        float s1 = yv[0][r] + yv[1][r] + yv[2][r];
        float s2 = yv[0][r]*yv[0][r] + yv[1][r]*yv[1][r] + yv[2][r]*yv[2][r];
        for (int off = 32; off; off >>= 1) {
            s1 += __shfl_down(s1, off);
            s2 += __shfl_down(s2, off);
        }
        if ((t & 63) == 0) { rs1[r][t >> 6] = s1; rs2[r][t >> 6] = s2; }
    }
    __syncthreads();

    float mu[4], rstd[4];
#pragma unroll
    for (int r = 0; r < 4; ++r) {
        float S1 = rs1[r][0] + rs1[r][1] + rs1[r][2] + rs1[r][3];
        float S2 = rs2[r][0] + rs2[r][1] + rs2[r][2] + rs2[r][3];
        mu[r] = S1 * (1.f / 768.f);
        float var = S2 * (1.f / 768.f) - mu[r] * mu[r];
        rstd[r] = rsqrtf(var + LNEPS);
    }

#pragma unroll
    for (int i = 0; i < 3; ++i) {
        int d = t + 256 * i;
        float g = ln_g[d], bb = ln_b[d];
#pragma unroll
        for (int r = 0; r < 4; ++r) {
            float y = (yv[i][r] - mu[r]) * rstd[r] * g + bb;
            unsigned short hi = f2b(y);
            unsigned short lo = f2b(y - b2f(hi));
            unsigned short* prow = (unsigned short*)(P + (size_t)(lrow0 + r) * DPROJ);
            prow[d] = hi;
            prow[DINNER + d] = lo;
        }
    }
}

extern "C" void kernel_launch(void* const* d_in, const int* in_sizes, int n_in,
                              void* d_out, int out_size, void* d_ws, size_t ws_size,
                              hipStream_t stream)
{
    const float* u       = (const float*)d_in[0];
    const float* W_in    = (const float*)d_in[1];
    const float* conv_w  = (const float*)d_in[2];
    const float* conv_b  = (const float*)d_in[3];
    const float* dt_bias = (const float*)d_in[4];
    const float* A_log   = (const float*)d_in[5];
    const float* Dp      = (const float*)d_in[6];
    const float* ln_g    = (const float*)d_in[7];
    const float* ln_b    = (const float*)d_in[8];
    const float* W_out   = (const float*)d_in[9];
    float* out = (float*)d_out;
    (void)ws_size;

    const int B = in_sizes[0] / (LL * DMODEL);   // 16

    // workspace (~152 MiB)
    float* P     = (float*)d_ws;                        // GM*1676 f32
    float* XC    = P + (size_t)GM * DPROJ;              // GM*896 f32
    float* coefg = XC + (size_t)GM * CDIM;              // GRP*NH*LL f32
    float* KVT   = coefg + (size_t)GRP * NH * LL;       // GRP*NH*64*64 f32
    unsigned short* uh  = (unsigned short*)(KVT + (size_t)GRP * NH * HD * DSTATE);
    unsigned short* ul  = uh + (size_t)GM * DMODEL;     // GM*384 each
    unsigned short* Wih = ul + (size_t)GM * DMODEL;     // 1676*384
    unsigned short* Wil = Wih + (size_t)DPROJ * DMODEL;
    unsigned short* Woh = Wil + (size_t)DPROJ * DMODEL; // 384*768
    unsigned short* Wol = Woh + (size_t)DMODEL * DINNER;

    // one-time weight pre-splits
    {
        int n4 = DPROJ * DMODEL / 4;
        split_f32<<<(n4 + 255) / 256, 256, 0, stream>>>(W_in, Wih, Wil, n4);
        n4 = DMODEL * DINNER / 4;
        split_f32<<<(n4 + 255) / 256, 256, 0, stream>>>(W_out, Woh, Wol, n4);
    }

    for (int b0 = 0; b0 < B; b0 += GRP) {
        // 0) pre-split u group
        {
            int n4 = GM * DMODEL / 4;
            split_f32<<<(n4 + 255) / 256, 256, 0, stream>>>(
                u + (size_t)b0 * LL * DMODEL, uh, ul, n4);
        }

        // 1) P = u_grp @ W_in^T  (128x128 tiles)
        gemm_ps<4><<<dim3(14, GM / 128), 256, 0, stream>>>(
            uh, ul, DMODEL, Wih, Wil, DMODEL, P, DPROJ, DPROJ, DMODEL);

        // 2) dt coefficients
        coef_kernel<<<(GRP * NH * LL) / 256, 256, 0, stream>>>(P, dt_bias, A_log, coefg);

        // 3) depthwise conv + SiLU
        conv_silu<<<dim3(LL, GRP), 256, 0, stream>>>(P, conv_w, conv_b, XC);

        // 4) KV einsum (transposed KVT[p][s])
        hipMemsetAsync(KVT, 0, (size_t)GRP * NH * DSTATE * HD * sizeof(float), stream);
        kv_kernel<<<dim3(NH, GRP, 7), 256, 0, stream>>>(XC, coefg, KVT);

        // 5a) yg = (C@KVcat + x*D) * silu(z)  (MFMA, in-place over z cols of P)
        ckv_gate<<<dim3(6, 49, GRP), 256, 0, stream>>>(P, XC, KVT, Dp);

        // 5b) LayerNorm -> y bf16 hi|lo into P z cols
        ln_kernel<<<GM / 4, 256, 0, stream>>>(P, ln_g, ln_b);

        // 6) out_grp = y @ W_out^T  (64x128 tiles, A = packed hi/lo in P, lda = 3352 ushorts)
        gemm_ps<2><<<dim3(3, GM / 64), 256, 0, stream>>>(
            (const unsigned short*)P, (const unsigned short*)P + DINNER, DPROJ * 2,
            Woh, Wol, DINNER,
            out + (size_t)b0 * LL * DMODEL, DMODEL, DMODEL, DINNER);
    }
}

// Round 8
// 835.076 us; speedup vs baseline: 2.7515x; 1.2119x over previous
//
#include <hip/hip_runtime.h>
#include <hip/hip_bf16.h>

#define LL 3136
#define HH 56
#define WWD 56
#define DMODEL 384
#define DINNER 768
#define NH 12
#define HD 64
#define DSTATE 64
#define CDIM 896
#define DPROJ 1676
#define LNEPS 1e-5f
#define GRP 4
#define GM (GRP * LL)          // 12544 rows per group

typedef __attribute__((ext_vector_type(8))) _Float16 half8;
typedef __attribute__((ext_vector_type(4))) float f32x4;

__device__ __forceinline__ unsigned short f2h_bits(float f) {
    _Float16 h = (_Float16)f;   // RNE
    return *reinterpret_cast<unsigned short*>(&h);
}

__device__ __forceinline__ f32x4 mfma16h(half8 a, half8 b, f32x4 c) {
    return __builtin_amdgcn_mfma_f32_16x16x32_f16(a, b, c, 0, 0, 0);
}

// async global->LDS, 16B per lane; dest = lds base (wave-uniform) + lane*16
__device__ __forceinline__ void gload16(const unsigned short* g, unsigned short* l) {
    __builtin_amdgcn_global_load_lds(
        (const __attribute__((address_space(1))) unsigned int*)g,
        (__attribute__((address_space(3))) unsigned int*)l, 16, 0, 0);
}

// elementwise convert fp32 -> fp16 (RNE)
__global__ __launch_bounds__(256) void cvt_f16(
    const float* __restrict__ in, unsigned short* __restrict__ out, int n4)
{
    int i = blockIdx.x * 256 + threadIdx.x;
    if (i >= n4) return;
    float4 v = ((const float4*)in)[i];
    ushort4 o;
    o.x = f2h_bits(v.x); o.y = f2h_bits(v.y);
    o.z = f2h_bits(v.z); o.w = f2h_bits(v.w);
    ((ushort4*)out)[i] = o;
}

// C[m,n] = sum_k A[m,k]*B[n,k], fp16 operands (1-term), fp32 out.
// m97 structure: global_load_lds dwordx4 staging, linear LDS + XOR granule swizzle.
// Tile: BM = MT*32 rows x 128 cols, BK=64. 4 waves, each (MT*16) x 64 output.
template<int MT>
__global__ __launch_bounds__(256) void gemm_h(
    const unsigned short* __restrict__ Ah, int lda,
    const unsigned short* __restrict__ Bh, int ldb,
    float* __restrict__ C, int ldc, int N, int K)
{
    constexpr int BM = MT * 32;
    __shared__ __align__(16) unsigned short Ahs[BM * 64];
    __shared__ __align__(16) unsigned short Bhs[128 * 64];
    const int t = threadIdx.x;
    const int lane = t & 63;
    const int w = t >> 6;
    const int bn = blockIdx.x * 128;
    const int bm = blockIdx.y * BM;
    const int wr = (w >> 1) * (MT * 16);
    const int wc = (w & 1) * 64;
    const int l15 = lane & 15;
    const int g   = lane >> 4;        // fragment granule col 0..3
    const int srow = lane >> 3;       // staging row within 8-row issue
    const int slot = lane & 7;        // staging granule slot 0..7

    f32x4 acc[MT][4];
#pragma unroll
    for (int m = 0; m < MT; ++m)
#pragma unroll
        for (int n = 0; n < 4; ++n) acc[m][n] = (f32x4){0.f, 0.f, 0.f, 0.f};

    for (int k0 = 0; k0 < K; k0 += 64) {
        // ---- stage tiles: each issue covers 8 rows x 64 cols (1KB) ----
#pragma unroll
        for (int it = 0; it < MT; ++it) {            // A: BM rows, 4 waves
            int rowblk = w * (8 * MT) + it * 8;
            int row = rowblk + srow;
            int sl = (slot ^ (row & 7)) * 8;         // pre-swizzled source granule
            size_t goff = (size_t)(bm + row) * lda + k0 + sl;
            gload16(Ah + goff, Ahs + rowblk * 64);
        }
#pragma unroll
        for (int it = 0; it < 4; ++it) {             // B: 128 rows
            int rowblk = w * 32 + it * 8;
            int row = rowblk + srow;
            int n = bn + row; if (n > N - 1) n = N - 1;   // clamp (garbage cols unwritten)
            int sl = (slot ^ (row & 7)) * 8;
            size_t goff = (size_t)n * ldb + k0 + sl;
            gload16(Bh + goff, Bhs + rowblk * 64);
        }
        __syncthreads();

        // ---- compute ----
#pragma unroll
        for (int ks = 0; ks < 2; ++ks) {
            half8 av[MT], bv[4];
#pragma unroll
            for (int m = 0; m < MT; ++m) {
                int arow = wr + m * 16 + l15;
                int off = arow * 64 + (((ks * 4 + g) ^ (arow & 7)) << 3);
                av[m] = *(const half8*)&Ahs[off];
            }
#pragma unroll
            for (int n = 0; n < 4; ++n) {
                int brow = wc + n * 16 + l15;
                int off = brow * 64 + (((ks * 4 + g) ^ (brow & 7)) << 3);
                bv[n] = *(const half8*)&Bhs[off];
            }
#pragma unroll
            for (int m = 0; m < MT; ++m)
#pragma unroll
                for (int n = 0; n < 4; ++n)
                    acc[m][n] = mfma16h(av[m], bv[n], acc[m][n]);
        }
        __syncthreads();
    }

    const int col0 = bn + wc + l15;
    const int row0 = bm + wr + (g << 2);
#pragma unroll
    for (int n = 0; n < 4; ++n) {
        int col = col0 + n * 16;
        if (col < N) {
#pragma unroll
            for (int m = 0; m < MT; ++m)
#pragma unroll
                for (int ri = 0; ri < 4; ++ri)
                    C[(size_t)(row0 + m * 16 + ri) * ldc + col] = acc[m][n][ri];
        }
    }
}

// depthwise 3x3 conv (pad 1) on fp32 xBC cols of P, + bias + SiLU -> fp32 XC (group-local)
__global__ __launch_bounds__(256) void conv_silu(
    const float* __restrict__ P, const float* __restrict__ cw,
    const float* __restrict__ cb, float* __restrict__ XC)
{
    int c4 = threadIdx.x * 4;
    if (c4 >= CDIM) return;
    int l = blockIdx.x, bl = blockIdx.y;
    int h = l / WWD, w = l % WWD;
    float acc[4] = {cb[c4], cb[c4 + 1], cb[c4 + 2], cb[c4 + 3]};
    float wv[9][4];
#pragma unroll
    for (int tap = 0; tap < 9; ++tap)
#pragma unroll
        for (int j = 0; j < 4; ++j) wv[tap][j] = cw[(c4 + j) * 9 + tap];
    const float* base = P + (size_t)bl * LL * DPROJ + DINNER + c4;
#pragma unroll
    for (int kh = -1; kh <= 1; ++kh) {
        int h2 = h + kh;
        if ((unsigned)h2 >= HH) continue;
#pragma unroll
        for (int kw = -1; kw <= 1; ++kw) {
            int w2 = w + kw;
            if ((unsigned)w2 >= WWD) continue;
            float4 v = *(const float4*)&base[(size_t)(h2 * WWD + w2) * DPROJ];
            int tap = (kh + 1) * 3 + (kw + 1);
            acc[0] += wv[tap][0] * v.x;
            acc[1] += wv[tap][1] * v.y;
            acc[2] += wv[tap][2] * v.z;
            acc[3] += wv[tap][3] * v.w;
        }
    }
    float4 o;
    o.x = acc[0] / (1.f + __expf(-acc[0]));
    o.y = acc[1] / (1.f + __expf(-acc[1]));
    o.z = acc[2] / (1.f + __expf(-acc[2]));
    o.w = acc[3] / (1.f + __expf(-acc[3]));
    *(float4*)&XC[((size_t)bl * LL + l) * CDIM + c4] = o;
}

// coefg[bl][h][l] = softplus(dt_raw + dt_bias[h]) * (-exp(A_log[h]))   (group-local)
__global__ __launch_bounds__(256) void coef_kernel(
    const float* __restrict__ P, const float* __restrict__ dt_bias,
    const float* __restrict__ A_log, float* __restrict__ coefg)
{
    int idx = blockIdx.x * 256 + threadIdx.x;
    int l = idx % LL;
    int h = (idx / LL) % NH;
    int bl = idx / (LL * NH);
    float x = P[((size_t)bl * LL + l) * DPROJ + DINNER + CDIM + h] + dt_bias[h];
    float sp = (x > 20.f) ? x : log1pf(__expf(x));
    coefg[idx] = -__expf(A_log[h]) * sp;
}

// KVT[bl,h,p,s] += sum_{l in chunk} B[l,s] * x[l,h*64+p] * coefg[bl,h,l]
__global__ __launch_bounds__(256) void kv_kernel(
    const float* __restrict__ XC, const float* __restrict__ coefg,
    float* __restrict__ KVT)
{
    int h  = blockIdx.x;
    int bl = blockIdx.y;
    int lbase = blockIdx.z * 448;
    __shared__ float Bsh[32][DSTATE];
    __shared__ float Xsh[32][HD];
    __shared__ float cf[32];
    const int t = threadIdx.x;
    const int ss = t & 63;          // lane owns state index s
    const int p0 = (t >> 6) * 16;   // wave owns p block
    const int lq = t >> 4;
    const int sq = (t & 15) * 4;
    float acc[16] = {};
    const float* xbase = XC + (size_t)bl * LL * CDIM;
    const float* crow = coefg + ((size_t)bl * NH + h) * LL + lbase;

    for (int l0 = 0; l0 < 448; l0 += 32) {
#pragma unroll
        for (int rr = 0; rr < 32; rr += 16) {
            const float* r = xbase + (size_t)(lbase + l0 + lq + rr) * CDIM;
            *(float4*)&Bsh[lq + rr][sq] = *(const float4*)&r[DINNER + sq];
            *(float4*)&Xsh[lq + rr][sq] = *(const float4*)&r[h * HD + sq];
        }
        if (t < 32) cf[t] = crow[l0 + t];
        __syncthreads();
#pragma unroll
        for (int li = 0; li < 32; ++li) {
            float bb = Bsh[li][ss] * cf[li];
            float4 x0 = *(const float4*)&Xsh[li][p0 + 0];
            float4 x1 = *(const float4*)&Xsh[li][p0 + 4];
            float4 x2 = *(const float4*)&Xsh[li][p0 + 8];
            float4 x3 = *(const float4*)&Xsh[li][p0 + 12];
            acc[0]  += x0.x * bb; acc[1]  += x0.y * bb; acc[2]  += x0.z * bb; acc[3]  += x0.w * bb;
            acc[4]  += x1.x * bb; acc[5]  += x1.y * bb; acc[6]  += x1.z * bb; acc[7]  += x1.w * bb;
            acc[8]  += x2.x * bb; acc[9]  += x2.y * bb; acc[10] += x2.z * bb; acc[11] += x2.w * bb;
            acc[12] += x3.x * bb; acc[13] += x3.y * bb; acc[14] += x3.z * bb; acc[15] += x3.w * bb;
        }
        __syncthreads();
    }
    float* outp = KVT + ((size_t)bl * NH + h) * HD * DSTATE;
#pragma unroll
    for (int j = 0; j < 16; ++j)
        atomicAdd(&outp[(size_t)(p0 + j) * DSTATE + ss], acc[j]);
}

// Yg = Cmat @ KVcat + x*D, gated by silu(z); fp32 yg written in-place over z cols of P.
// MFMA fp16 (1-term), no LDS. Tile: M=64, N=128 (2 heads), K=64.
__global__ __launch_bounds__(256) void ckv_gate(
    float* __restrict__ P, const float* __restrict__ XC,
    const float* __restrict__ KVT, const float* __restrict__ Dp)
{
    const int t = threadIdx.x;
    const int lane = t & 63;
    const int w = t >> 6;
    const int bn = blockIdx.x * 128;
    const int mt = blockIdx.y;       // 0..48
    const int bl = blockIdx.z;
    const int wc = w * 32;
    const int l15 = lane & 15;
    const int kq = (lane >> 4) * 8;

    f32x4 acc[4][2];
#pragma unroll
    for (int m = 0; m < 4; ++m)
#pragma unroll
        for (int n = 0; n < 2; ++n) acc[m][n] = (f32x4){0.f, 0.f, 0.f, 0.f};

    const size_t rbase = (size_t)bl * LL + mt * 64;
    const float* Cbase = XC + rbase * CDIM + (DINNER + DSTATE);

    const float* Bptr[2];
    float dcoef[2];
    int dglob[2];
#pragma unroll
    for (int n = 0; n < 2; ++n) {
        int d = bn + wc + n * 16 + l15;
        dglob[n] = d;
        int h = d >> 6, p = d & 63;
        Bptr[n] = KVT + (((size_t)bl * NH + h) * HD + p) * DSTATE;
        dcoef[n] = Dp[h];
    }

#pragma unroll
    for (int ks = 0; ks < 2; ++ks) {
        const int koff = ks * 32 + kq;
        half8 av[4], bv[2];
#pragma unroll
        for (int m = 0; m < 4; ++m) {
            float tmp[8];
            const float* src = Cbase + (size_t)(l15 + m * 16) * CDIM + koff;
            *(float4*)&tmp[0] = *(const float4*)src;
            *(float4*)&tmp[4] = *(const float4*)(src + 4);
#pragma unroll
            for (int i = 0; i < 8; ++i) av[m][i] = (_Float16)tmp[i];
        }
#pragma unroll
        for (int n = 0; n < 2; ++n) {
            float tmp[8];
            *(float4*)&tmp[0] = *(const float4*)&Bptr[n][koff];
            *(float4*)&tmp[4] = *(const float4*)&Bptr[n][koff + 4];
#pragma unroll
            for (int i = 0; i < 8; ++i) bv[n][i] = (_Float16)tmp[i];
        }
#pragma unroll
        for (int m = 0; m < 4; ++m)
#pragma unroll
            for (int n = 0; n < 2; ++n)
                acc[m][n] = mfma16h(av[m], bv[n], acc[m][n]);
    }

    const int r0 = (lane >> 4) << 2;
#pragma unroll
    for (int m = 0; m < 4; ++m)
#pragma unroll
        for (int ri = 0; ri < 4; ++ri) {
            size_t grow = rbase + m * 16 + r0 + ri;
#pragma unroll
            for (int n = 0; n < 2; ++n) {
                int d = dglob[n];
                float x = XC[grow * CDIM + d];
                float* zp = P + grow * DPROJ + d;
                float z = *zp;
                float sz = z / (1.f + __expf(-z));
                *zp = (acc[m][n][ri] + x * dcoef[n]) * sz;
            }
        }
}

// LayerNorm(768) over yg rows in P z-region; write y as fp16 in-place (low half of z cols)
__global__ __launch_bounds__(256, 4) void ln_kernel(
    float* __restrict__ P, const float* __restrict__ ln_g, const float* __restrict__ ln_b)
{
    int lrow0 = blockIdx.x * 4;
    const int t = threadIdx.x;
    __shared__ float rs1[4][4], rs2[4][4];

    float yv[3][4];
#pragma unroll
    for (int i = 0; i < 3; ++i) {
        int d = t + 256 * i;
#pragma unroll
        for (int r = 0; r < 4; ++r)
            yv[i][r] = P[(size_t)(lrow0 + r) * DPROJ + d];
    }

#pragma unroll
    for (int r = 0; r < 4; ++r) {
        float s1 = yv[0][r] + yv[1][r] + yv[2][r];
        float s2 = yv[0][r]*yv[0][r] + yv[1][r]*yv[1][r] + yv[2][r]*yv[2][r];
        for (int off = 32; off; off >>= 1) {
            s1 += __shfl_down(s1, off);
            s2 += __shfl_down(s2, off);
        }
        if ((t & 63) == 0) { rs1[r][t >> 6] = s1; rs2[r][t >> 6] = s2; }
    }
    __syncthreads();

    float mu[4], rstd[4];
#pragma unroll
    for (int r = 0; r < 4; ++r) {
        float S1 = rs1[r][0] + rs1[r][1] + rs1[r][2] + rs1[r][3];
        float S2 = rs2[r][0] + rs2[r][1] + rs2[r][2] + rs2[r][3];
        mu[r] = S1 * (1.f / 768.f);
        float var = S2 * (1.f / 768.f) - mu[r] * mu[r];
        rstd[r] = rsqrtf(var + LNEPS);
    }

#pragma unroll
    for (int i = 0; i < 3; ++i) {
        int d = t + 256 * i;
        float g = ln_g[d], bb = ln_b[d];
#pragma unroll
        for (int r = 0; r < 4; ++r) {
            float y = (yv[i][r] - mu[r]) * rstd[r] * g + bb;
            unsigned short* prow = (unsigned short*)(P + (size_t)(lrow0 + r) * DPROJ);
            prow[d] = f2h_bits(y);
        }
    }
}

extern "C" void kernel_launch(void* const* d_in, const int* in_sizes, int n_in,
                              void* d_out, int out_size, void* d_ws, size_t ws_size,
                              hipStream_t stream)
{
    const float* u       = (const float*)d_in[0];
    const float* W_in    = (const float*)d_in[1];
    const float* conv_w  = (const float*)d_in[2];
    const float* conv_b  = (const float*)d_in[3];
    const float* dt_bias = (const float*)d_in[4];
    const float* A_log   = (const float*)d_in[5];
    const float* Dp      = (const float*)d_in[6];
    const float* ln_g    = (const float*)d_in[7];
    const float* ln_b    = (const float*)d_in[8];
    const float* W_out   = (const float*)d_in[9];
    float* out = (float*)d_out;
    (void)ws_size;

    const int B = in_sizes[0] / (LL * DMODEL);   // 16
    const int M = B * LL;                        // 50176

    // workspace (~171 MiB)
    float* P     = (float*)d_ws;                        // GM*1676 f32
    float* XC    = P + (size_t)GM * DPROJ;              // GM*896 f32
    float* coefg = XC + (size_t)GM * CDIM;              // GRP*NH*LL f32
    float* KVT   = coefg + (size_t)GRP * NH * LL;       // GRP*NH*64*64 f32
    unsigned short* u16  = (unsigned short*)(KVT + (size_t)GRP * NH * HD * DSTATE); // M*384 fp16
    unsigned short* Wi16 = u16 + (size_t)M * DMODEL;    // 1676*384 fp16
    unsigned short* Wo16 = Wi16 + (size_t)DPROJ * DMODEL; // 384*768 fp16

    // one-time fp16 converts
    cvt_f16<<<((size_t)M * DMODEL / 4 + 255) / 256, 256, 0, stream>>>(u, u16, M * DMODEL / 4);
    cvt_f16<<<(DPROJ * DMODEL / 4 + 255) / 256, 256, 0, stream>>>(W_in, Wi16, DPROJ * DMODEL / 4);
    cvt_f16<<<(DMODEL * DINNER / 4 + 255) / 256, 256, 0, stream>>>(W_out, Wo16, DMODEL * DINNER / 4);

    for (int b0 = 0; b0 < B; b0 += GRP) {
        // 1) P = u_grp @ W_in^T  (128x128 tiles, fp16 MFMA)
        gemm_h<4><<<dim3(14, GM / 128), 256, 0, stream>>>(
            u16 + (size_t)b0 * LL * DMODEL, DMODEL, Wi16, DMODEL, P, DPROJ, DPROJ, DMODEL);

        // 2) dt coefficients
        coef_kernel<<<(GRP * NH * LL) / 256, 256, 0, stream>>>(P, dt_bias, A_log, coefg);

        // 3) depthwise conv + SiLU
        conv_silu<<<dim3(LL, GRP), 256, 0, stream>>>(P, conv_w, conv_b, XC);

        // 4) KV einsum (transposed KVT[p][s])
        hipMemsetAsync(KVT, 0, (size_t)GRP * NH * DSTATE * HD * sizeof(float), stream);
        kv_kernel<<<dim3(NH, GRP, 7), 256, 0, stream>>>(XC, coefg, KVT);

        // 5a) yg = (C@KVcat + x*D) * silu(z)  (fp16 MFMA, in-place over z cols of P)
        ckv_gate<<<dim3(6, 49, GRP), 256, 0, stream>>>(P, XC, KVT, Dp);

        // 5b) LayerNorm -> y fp16 into P z cols
        ln_kernel<<<GM / 4, 256, 0, stream>>>(P, ln_g, ln_b);

        // 6) out_grp = y @ W_out^T  (64x128 tiles; A = fp16 y in P, lda = 3352 ushorts)
        gemm_h<2><<<dim3(3, GM / 64), 256, 0, stream>>>(
            (const unsigned short*)P, DPROJ * 2, Wo16, DINNER,
            out + (size_t)b0 * LL * DMODEL, DMODEL, DMODEL, DINNER);
    }
}

// Round 9
// 757.673 us; speedup vs baseline: 3.0325x; 1.1022x over previous
//
#include <hip/hip_runtime.h>
#include <hip/hip_bf16.h>

#define LL 3136
#define HH 56
#define WWD 56
#define DMODEL 384
#define DINNER 768
#define NH 12
#define HD 64
#define DSTATE 64
#define CDIM 896
#define DPROJ 1676
#define PSTRIDE 1680           // padded P row stride in ushorts (3360 B, 16B-aligned rows)
#define LNEPS 1e-5f
#define GRP 4
#define GM (GRP * LL)          // 12544 rows per group

typedef __attribute__((ext_vector_type(8))) _Float16 half8;
typedef __attribute__((ext_vector_type(4))) float f32x4;

__device__ __forceinline__ unsigned short f2h_bits(float f) {
    _Float16 h = (_Float16)f;   // RNE
    return *reinterpret_cast<unsigned short*>(&h);
}
__device__ __forceinline__ float h2f(unsigned short u) {
    _Float16 h = *reinterpret_cast<_Float16*>(&u);
    return (float)h;
}

__device__ __forceinline__ f32x4 mfma16h(half8 a, half8 b, f32x4 c) {
    return __builtin_amdgcn_mfma_f32_16x16x32_f16(a, b, c, 0, 0, 0);
}

// async global->LDS, 16B per lane; dest = lds base (wave-uniform) + lane*16
__device__ __forceinline__ void gload16(const unsigned short* g, unsigned short* l) {
    __builtin_amdgcn_global_load_lds(
        (const __attribute__((address_space(1))) unsigned int*)g,
        (__attribute__((address_space(3))) unsigned int*)l, 16, 0, 0);
}

// elementwise convert fp32 -> fp16 (RNE)
__global__ __launch_bounds__(256) void cvt_f16(
    const float* __restrict__ in, unsigned short* __restrict__ out, int n4)
{
    int i = blockIdx.x * 256 + threadIdx.x;
    if (i >= n4) return;
    float4 v = ((const float4*)in)[i];
    ushort4 o;
    o.x = f2h_bits(v.x); o.y = f2h_bits(v.y);
    o.z = f2h_bits(v.z); o.w = f2h_bits(v.w);
    ((ushort4*)out)[i] = o;
}

// C[m,n] = sum_k A[m,k]*B[n,k], fp16 operands, fp32 acc; OUT16 selects fp16/fp32 store.
// m97 structure: global_load_lds dwordx4 staging, linear LDS + XOR granule swizzle.
template<int MT, int OUT16>
__global__ __launch_bounds__(256) void gemm_h(
    const unsigned short* __restrict__ Ah, int lda,
    const unsigned short* __restrict__ Bh, int ldb,
    void* __restrict__ Cp, int ldc, int N, int K)
{
    constexpr int BM = MT * 32;
    __shared__ __align__(16) unsigned short Ahs[BM * 64];
    __shared__ __align__(16) unsigned short Bhs[128 * 64];
    const int t = threadIdx.x;
    const int lane = t & 63;
    const int w = t >> 6;
    const int bn = blockIdx.x * 128;
    const int bm = blockIdx.y * BM;
    const int wr = (w >> 1) * (MT * 16);
    const int wc = (w & 1) * 64;
    const int l15 = lane & 15;
    const int g   = lane >> 4;
    const int srow = lane >> 3;
    const int slot = lane & 7;

    f32x4 acc[MT][4];
#pragma unroll
    for (int m = 0; m < MT; ++m)
#pragma unroll
        for (int n = 0; n < 4; ++n) acc[m][n] = (f32x4){0.f, 0.f, 0.f, 0.f};

    for (int k0 = 0; k0 < K; k0 += 64) {
#pragma unroll
        for (int it = 0; it < MT; ++it) {            // A: BM rows
            int rowblk = w * (8 * MT) + it * 8;
            int row = rowblk + srow;
            int sl = (slot ^ (row & 7)) * 8;
            size_t goff = (size_t)(bm + row) * lda + k0 + sl;
            gload16(Ah + goff, Ahs + rowblk * 64);
        }
#pragma unroll
        for (int it = 0; it < 4; ++it) {             // B: 128 rows
            int rowblk = w * 32 + it * 8;
            int row = rowblk + srow;
            int n = bn + row; if (n > N - 1) n = N - 1;
            int sl = (slot ^ (row & 7)) * 8;
            size_t goff = (size_t)n * ldb + k0 + sl;
            gload16(Bh + goff, Bhs + rowblk * 64);
        }
        __syncthreads();

#pragma unroll
        for (int ks = 0; ks < 2; ++ks) {
            half8 av[MT], bv[4];
#pragma unroll
            for (int m = 0; m < MT; ++m) {
                int arow = wr + m * 16 + l15;
                int off = arow * 64 + (((ks * 4 + g) ^ (arow & 7)) << 3);
                av[m] = *(const half8*)&Ahs[off];
            }
#pragma unroll
            for (int n = 0; n < 4; ++n) {
                int brow = wc + n * 16 + l15;
                int off = brow * 64 + (((ks * 4 + g) ^ (brow & 7)) << 3);
                bv[n] = *(const half8*)&Bhs[off];
            }
#pragma unroll
            for (int m = 0; m < MT; ++m)
#pragma unroll
                for (int n = 0; n < 4; ++n)
                    acc[m][n] = mfma16h(av[m], bv[n], acc[m][n]);
        }
        __syncthreads();
    }

    const int col0 = bn + wc + l15;
    const int row0 = bm + wr + (g << 2);
#pragma unroll
    for (int n = 0; n < 4; ++n) {
        int col = col0 + n * 16;
        if (col < N) {
#pragma unroll
            for (int m = 0; m < MT; ++m)
#pragma unroll
                for (int ri = 0; ri < 4; ++ri) {
                    if (OUT16) {
                        ((unsigned short*)Cp)[(size_t)(row0 + m * 16 + ri) * ldc + col] =
                            f2h_bits(acc[m][n][ri]);
                    } else {
                        ((float*)Cp)[(size_t)(row0 + m * 16 + ri) * ldc + col] = acc[m][n][ri];
                    }
                }
        }
    }
}

// depthwise 3x3 conv (pad 1) on fp16 xBC cols of P, + bias + SiLU -> fp16 XC (group-local)
__global__ __launch_bounds__(256) void conv_silu(
    const unsigned short* __restrict__ P, const float* __restrict__ cw,
    const float* __restrict__ cb, unsigned short* __restrict__ XC)
{
    int c4 = threadIdx.x * 4;
    if (c4 >= CDIM) return;
    int l = blockIdx.x, bl = blockIdx.y;
    int h = l / WWD, w = l % WWD;
    float acc[4] = {cb[c4], cb[c4 + 1], cb[c4 + 2], cb[c4 + 3]};
    float wv[9][4];
#pragma unroll
    for (int tap = 0; tap < 9; ++tap)
#pragma unroll
        for (int j = 0; j < 4; ++j) wv[tap][j] = cw[(c4 + j) * 9 + tap];
    const unsigned short* base = P + (size_t)bl * LL * PSTRIDE + DINNER + c4;
#pragma unroll
    for (int kh = -1; kh <= 1; ++kh) {
        int h2 = h + kh;
        if ((unsigned)h2 >= HH) continue;
#pragma unroll
        for (int kw = -1; kw <= 1; ++kw) {
            int w2 = w + kw;
            if ((unsigned)w2 >= WWD) continue;
            ushort4 v = *(const ushort4*)&base[(size_t)(h2 * WWD + w2) * PSTRIDE];
            int tap = (kh + 1) * 3 + (kw + 1);
            acc[0] += wv[tap][0] * h2f(v.x);
            acc[1] += wv[tap][1] * h2f(v.y);
            acc[2] += wv[tap][2] * h2f(v.z);
            acc[3] += wv[tap][3] * h2f(v.w);
        }
    }
    ushort4 o;
    o.x = f2h_bits(acc[0] / (1.f + __expf(-acc[0])));
    o.y = f2h_bits(acc[1] / (1.f + __expf(-acc[1])));
    o.z = f2h_bits(acc[2] / (1.f + __expf(-acc[2])));
    o.w = f2h_bits(acc[3] / (1.f + __expf(-acc[3])));
    *(ushort4*)&XC[((size_t)bl * LL + l) * CDIM + c4] = o;
}

// coefg[bl][h][l] = softplus(dt_raw + dt_bias[h]) * (-exp(A_log[h]))   (group-local)
__global__ __launch_bounds__(256) void coef_kernel(
    const unsigned short* __restrict__ P, const float* __restrict__ dt_bias,
    const float* __restrict__ A_log, float* __restrict__ coefg)
{
    int idx = blockIdx.x * 256 + threadIdx.x;
    int l = idx % LL;
    int h = (idx / LL) % NH;
    int bl = idx / (LL * NH);
    float x = h2f(P[((size_t)bl * LL + l) * PSTRIDE + DINNER + CDIM + h]) + dt_bias[h];
    float sp = (x > 20.f) ? x : log1pf(__expf(x));
    coefg[idx] = -__expf(A_log[h]) * sp;
}

// KVT[bl,h,p,s] += sum_{l in chunk} B[l,s] * x[l,h*64+p] * coefg[bl,h,l]
__global__ __launch_bounds__(256) void kv_kernel(
    const unsigned short* __restrict__ XC, const float* __restrict__ coefg,
    float* __restrict__ KVT)
{
    int h  = blockIdx.x;
    int bl = blockIdx.y;
    int lbase = blockIdx.z * 448;
    __shared__ float Bsh[32][DSTATE];
    __shared__ float Xsh[32][HD];
    __shared__ float cf[32];
    const int t = threadIdx.x;
    const int ss = t & 63;
    const int p0 = (t >> 6) * 16;
    const int lq = t >> 4;
    const int sq = (t & 15) * 4;
    float acc[16] = {};
    const unsigned short* xbase = XC + (size_t)bl * LL * CDIM;
    const float* crow = coefg + ((size_t)bl * NH + h) * LL + lbase;

    for (int l0 = 0; l0 < 448; l0 += 32) {
#pragma unroll
        for (int rr = 0; rr < 32; rr += 16) {
            const unsigned short* r = xbase + (size_t)(lbase + l0 + lq + rr) * CDIM;
            ushort4 bv = *(const ushort4*)&r[DINNER + sq];
            Bsh[lq + rr][sq + 0] = h2f(bv.x); Bsh[lq + rr][sq + 1] = h2f(bv.y);
            Bsh[lq + rr][sq + 2] = h2f(bv.z); Bsh[lq + rr][sq + 3] = h2f(bv.w);
            ushort4 xv = *(const ushort4*)&r[h * HD + sq];
            Xsh[lq + rr][sq + 0] = h2f(xv.x); Xsh[lq + rr][sq + 1] = h2f(xv.y);
            Xsh[lq + rr][sq + 2] = h2f(xv.z); Xsh[lq + rr][sq + 3] = h2f(xv.w);
        }
        if (t < 32) cf[t] = crow[l0 + t];
        __syncthreads();
#pragma unroll
        for (int li = 0; li < 32; ++li) {
            float bb = Bsh[li][ss] * cf[li];
            float4 x0 = *(const float4*)&Xsh[li][p0 + 0];
            float4 x1 = *(const float4*)&Xsh[li][p0 + 4];
            float4 x2 = *(const float4*)&Xsh[li][p0 + 8];
            float4 x3 = *(const float4*)&Xsh[li][p0 + 12];
            acc[0]  += x0.x * bb; acc[1]  += x0.y * bb; acc[2]  += x0.z * bb; acc[3]  += x0.w * bb;
            acc[4]  += x1.x * bb; acc[5]  += x1.y * bb; acc[6]  += x1.z * bb; acc[7]  += x1.w * bb;
            acc[8]  += x2.x * bb; acc[9]  += x2.y * bb; acc[10] += x2.z * bb; acc[11] += x2.w * bb;
            acc[12] += x3.x * bb; acc[13] += x3.y * bb; acc[14] += x3.z * bb; acc[15] += x3.w * bb;
        }
        __syncthreads();
    }
    float* outp = KVT + ((size_t)bl * NH + h) * HD * DSTATE;
#pragma unroll
    for (int j = 0; j < 16; ++j)
        atomicAdd(&outp[(size_t)(p0 + j) * DSTATE + ss], acc[j]);
}

// Yg = Cmat @ KVcat + x*D, gated by silu(z); fp16 yg written in-place over z cols of P.
// MFMA fp16, no LDS. A = C cols of XC (fp16, direct half8), B = KVT rows (fp32->fp16).
__global__ __launch_bounds__(256) void ckv_gate(
    unsigned short* __restrict__ P, const unsigned short* __restrict__ XC,
    const float* __restrict__ KVT, const float* __restrict__ Dp)
{
    const int t = threadIdx.x;
    const int lane = t & 63;
    const int w = t >> 6;
    const int bn = blockIdx.x * 128;
    const int mt = blockIdx.y;       // 0..48
    const int bl = blockIdx.z;
    const int wc = w * 32;
    const int l15 = lane & 15;
    const int kq = (lane >> 4) * 8;

    f32x4 acc[4][2];
#pragma unroll
    for (int m = 0; m < 4; ++m)
#pragma unroll
        for (int n = 0; n < 2; ++n) acc[m][n] = (f32x4){0.f, 0.f, 0.f, 0.f};

    const size_t rbase = (size_t)bl * LL + mt * 64;
    const unsigned short* Cb = XC + rbase * CDIM + (DINNER + DSTATE);

    const float* Bptr[2];
    float dcoef[2];
    int dglob[2];
#pragma unroll
    for (int n = 0; n < 2; ++n) {
        int d = bn + wc + n * 16 + l15;
        dglob[n] = d;
        int h = d >> 6, p = d & 63;
        Bptr[n] = KVT + (((size_t)bl * NH + h) * HD + p) * DSTATE;
        dcoef[n] = Dp[h];
    }

#pragma unroll
    for (int ks = 0; ks < 2; ++ks) {
        const int koff = ks * 32 + kq;
        half8 av[4], bv[2];
#pragma unroll
        for (int m = 0; m < 4; ++m)
            av[m] = *(const half8*)&Cb[(size_t)(l15 + m * 16) * CDIM + koff];
#pragma unroll
        for (int n = 0; n < 2; ++n) {
            float tmp[8];
            *(float4*)&tmp[0] = *(const float4*)&Bptr[n][koff];
            *(float4*)&tmp[4] = *(const float4*)&Bptr[n][koff + 4];
#pragma unroll
            for (int i = 0; i < 8; ++i) bv[n][i] = (_Float16)tmp[i];
        }
#pragma unroll
        for (int m = 0; m < 4; ++m)
#pragma unroll
            for (int n = 0; n < 2; ++n)
                acc[m][n] = mfma16h(av[m], bv[n], acc[m][n]);
    }

    const int r0 = (lane >> 4) << 2;
#pragma unroll
    for (int m = 0; m < 4; ++m)
#pragma unroll
        for (int ri = 0; ri < 4; ++ri) {
            size_t grow = rbase + m * 16 + r0 + ri;
#pragma unroll
            for (int n = 0; n < 2; ++n) {
                int d = dglob[n];
                float x = h2f(XC[grow * CDIM + d]);
                unsigned short* zp = P + grow * PSTRIDE + d;
                float z = h2f(*zp);
                float sz = z / (1.f + __expf(-z));
                *zp = f2h_bits((acc[m][n][ri] + x * dcoef[n]) * sz);
            }
        }
}

// LayerNorm(768) over fp16 yg rows in P z-region; write fp16 y in-place
__global__ __launch_bounds__(256, 4) void ln_kernel(
    unsigned short* __restrict__ P, const float* __restrict__ ln_g, const float* __restrict__ ln_b)
{
    int lrow0 = blockIdx.x * 4;
    const int t = threadIdx.x;
    __shared__ float rs1[4][4], rs2[4][4];

    float yv[3][4];
#pragma unroll
    for (int i = 0; i < 3; ++i) {
        int d = t + 256 * i;
#pragma unroll
        for (int r = 0; r < 4; ++r)
            yv[i][r] = h2f(P[(size_t)(lrow0 + r) * PSTRIDE + d]);
    }

#pragma unroll
    for (int r = 0; r < 4; ++r) {
        float s1 = yv[0][r] + yv[1][r] + yv[2][r];
        float s2 = yv[0][r]*yv[0][r] + yv[1][r]*yv[1][r] + yv[2][r]*yv[2][r];
        for (int off = 32; off; off >>= 1) {
            s1 += __shfl_down(s1, off);
            s2 += __shfl_down(s2, off);
        }
        if ((t & 63) == 0) { rs1[r][t >> 6] = s1; rs2[r][t >> 6] = s2; }
    }
    __syncthreads();

    float mu[4], rstd[4];
#pragma unroll
    for (int r = 0; r < 4; ++r) {
        float S1 = rs1[r][0] + rs1[r][1] + rs1[r][2] + rs1[r][3];
        float S2 = rs2[r][0] + rs2[r][1] + rs2[r][2] + rs2[r][3];
        mu[r] = S1 * (1.f / 768.f);
        float var = S2 * (1.f / 768.f) - mu[r] * mu[r];
        rstd[r] = rsqrtf(var + LNEPS);
    }

#pragma unroll
    for (int i = 0; i < 3; ++i) {
        int d = t + 256 * i;
        float g = ln_g[d], bb = ln_b[d];
#pragma unroll
        for (int r = 0; r < 4; ++r) {
            float y = (yv[i][r] - mu[r]) * rstd[r] * g + bb;
            P[(size_t)(lrow0 + r) * PSTRIDE + d] = f2h_bits(y);
        }
    }
}

extern "C" void kernel_launch(void* const* d_in, const int* in_sizes, int n_in,
                              void* d_out, int out_size, void* d_ws, size_t ws_size,
                              hipStream_t stream)
{
    const float* u       = (const float*)d_in[0];
    const float* W_in    = (const float*)d_in[1];
    const float* conv_w  = (const float*)d_in[2];
    const float* conv_b  = (const float*)d_in[3];
    const float* dt_bias = (const float*)d_in[4];
    const float* A_log   = (const float*)d_in[5];
    const float* Dp      = (const float*)d_in[6];
    const float* ln_g    = (const float*)d_in[7];
    const float* ln_b    = (const float*)d_in[8];
    const float* W_out   = (const float*)d_in[9];
    float* out = (float*)d_out;
    (void)ws_size;

    const int B = in_sizes[0] / (LL * DMODEL);   // 16
    const int M = B * LL;                        // 50176

    // workspace (~108 MiB), all fp16 intermediates
    unsigned short* P  = (unsigned short*)d_ws;             // GM*PSTRIDE fp16
    unsigned short* XC = P + (size_t)GM * PSTRIDE;          // GM*896 fp16
    float* coefg = (float*)(XC + (size_t)GM * CDIM);        // GRP*NH*LL f32
    float* KVT   = coefg + (size_t)GRP * NH * LL;           // GRP*NH*64*64 f32
    unsigned short* u16  = (unsigned short*)(KVT + (size_t)GRP * NH * HD * DSTATE); // M*384
    unsigned short* Wi16 = u16 + (size_t)M * DMODEL;        // 1676*384
    unsigned short* Wo16 = Wi16 + (size_t)DPROJ * DMODEL;   // 384*768

    // one-time fp16 converts
    cvt_f16<<<((size_t)M * DMODEL / 4 + 255) / 256, 256, 0, stream>>>(u, u16, M * DMODEL / 4);
    cvt_f16<<<(DPROJ * DMODEL / 4 + 255) / 256, 256, 0, stream>>>(W_in, Wi16, DPROJ * DMODEL / 4);
    cvt_f16<<<(DMODEL * DINNER / 4 + 255) / 256, 256, 0, stream>>>(W_out, Wo16, DMODEL * DINNER / 4);

    for (int b0 = 0; b0 < B; b0 += GRP) {
        // 1) P = u_grp @ W_in^T  (fp16 MFMA, fp16 store)
        gemm_h<4, 1><<<dim3(14, GM / 128), 256, 0, stream>>>(
            u16 + (size_t)b0 * LL * DMODEL, DMODEL, Wi16, DMODEL, P, PSTRIDE, DPROJ, DMODEL);

        // 2) dt coefficients
        coef_kernel<<<(GRP * NH * LL) / 256, 256, 0, stream>>>(P, dt_bias, A_log, coefg);

        // 3) depthwise conv + SiLU (fp16 in/out)
        conv_silu<<<dim3(LL, GRP), 256, 0, stream>>>(P, conv_w, conv_b, XC);

        // 4) KV einsum (fp16 reads, fp32 acc, transposed KVT[p][s])
        hipMemsetAsync(KVT, 0, (size_t)GRP * NH * DSTATE * HD * sizeof(float), stream);
        kv_kernel<<<dim3(NH, GRP, 7), 256, 0, stream>>>(XC, coefg, KVT);

        // 5a) yg = (C@KVcat + x*D) * silu(z)  (fp16 MFMA, fp16 in-place over z cols of P)
        ckv_gate<<<dim3(6, 49, GRP), 256, 0, stream>>>(P, XC, KVT, Dp);

        // 5b) LayerNorm -> y fp16 into P z cols
        ln_kernel<<<GM / 4, 256, 0, stream>>>(P, ln_g, ln_b);

        // 6) out_grp = y @ W_out^T  (fp16 A in P, fp32 out)
        gemm_h<2, 0><<<dim3(3, GM / 64), 256, 0, stream>>>(
            P, PSTRIDE, Wo16, DINNER,
            out + (size_t)b0 * LL * DMODEL, DMODEL, DMODEL, DINNER);
    }
}

// Round 10
// 708.583 us; speedup vs baseline: 3.2426x; 1.0693x over previous
//
#include <hip/hip_runtime.h>
#include <hip/hip_bf16.h>

#define LL 3136
#define HH 56
#define WWD 56
#define DMODEL 384
#define DINNER 768
#define NH 12
#define HD 64
#define DSTATE 64
#define CDIM 896
#define DPROJ 1676
#define PSTRIDE 1680           // padded P row stride in ushorts (3360 B, 16B-aligned rows)
#define LNEPS 1e-5f
#define GRP 4
#define GM (GRP * LL)          // 12544 rows per group

typedef __attribute__((ext_vector_type(8))) _Float16 half8;
typedef __attribute__((ext_vector_type(4))) float f32x4;

__device__ __forceinline__ unsigned short f2h_bits(float f) {
    _Float16 h = (_Float16)f;   // RNE
    return *reinterpret_cast<unsigned short*>(&h);
}
__device__ __forceinline__ float h2f(unsigned short u) {
    _Float16 h = *reinterpret_cast<_Float16*>(&u);
    return (float)h;
}

__device__ __forceinline__ f32x4 mfma16h(half8 a, half8 b, f32x4 c) {
    return __builtin_amdgcn_mfma_f32_16x16x32_f16(a, b, c, 0, 0, 0);
}

// async global->LDS, 16B per lane; dest = lds base (wave-uniform) + lane*16
__device__ __forceinline__ void gload16(const unsigned short* g, unsigned short* l) {
    __builtin_amdgcn_global_load_lds(
        (const __attribute__((address_space(1))) unsigned int*)g,
        (__attribute__((address_space(3))) unsigned int*)l, 16, 0, 0);
}

// elementwise convert fp32 -> fp16 (RNE)
__global__ __launch_bounds__(256) void cvt_f16(
    const float* __restrict__ in, unsigned short* __restrict__ out, int n4)
{
    int i = blockIdx.x * 256 + threadIdx.x;
    if (i >= n4) return;
    float4 v = ((const float4*)in)[i];
    ushort4 o;
    o.x = f2h_bits(v.x); o.y = f2h_bits(v.y);
    o.z = f2h_bits(v.z); o.w = f2h_bits(v.w);
    ((ushort4*)out)[i] = o;
}

// pack conv weights f32 [c][tap] -> fp16 [tap][c]
__global__ __launch_bounds__(256) void pack_w16(
    const float* __restrict__ cw, unsigned short* __restrict__ wt)
{
    int c = blockIdx.x * 256 + threadIdx.x;
    if (c >= CDIM) return;
#pragma unroll
    for (int tap = 0; tap < 9; ++tap)
        wt[tap * CDIM + c] = f2h_bits(cw[c * 9 + tap]);
}

// C[m,n] = sum_k A[m,k]*B[n,k], fp16 operands, fp32 acc; OUT16 selects fp16/fp32 store.
// m97 structure: global_load_lds dwordx4 staging, linear LDS + XOR granule swizzle.
template<int MT, int OUT16>
__global__ __launch_bounds__(256) void gemm_h(
    const unsigned short* __restrict__ Ah, int lda,
    const unsigned short* __restrict__ Bh, int ldb,
    void* __restrict__ Cp, int ldc, int N, int K)
{
    constexpr int BM = MT * 32;
    __shared__ __align__(16) unsigned short Ahs[BM * 64];
    __shared__ __align__(16) unsigned short Bhs[128 * 64];
    const int t = threadIdx.x;
    const int lane = t & 63;
    const int w = t >> 6;
    const int bn = blockIdx.x * 128;
    const int bm = blockIdx.y * BM;
    const int wr = (w >> 1) * (MT * 16);
    const int wc = (w & 1) * 64;
    const int l15 = lane & 15;
    const int g   = lane >> 4;
    const int srow = lane >> 3;
    const int slot = lane & 7;

    f32x4 acc[MT][4];
#pragma unroll
    for (int m = 0; m < MT; ++m)
#pragma unroll
        for (int n = 0; n < 4; ++n) acc[m][n] = (f32x4){0.f, 0.f, 0.f, 0.f};

    for (int k0 = 0; k0 < K; k0 += 64) {
#pragma unroll
        for (int it = 0; it < MT; ++it) {            // A: BM rows
            int rowblk = w * (8 * MT) + it * 8;
            int row = rowblk + srow;
            int sl = (slot ^ (row & 7)) * 8;
            size_t goff = (size_t)(bm + row) * lda + k0 + sl;
            gload16(Ah + goff, Ahs + rowblk * 64);
        }
#pragma unroll
        for (int it = 0; it < 4; ++it) {             // B: 128 rows
            int rowblk = w * 32 + it * 8;
            int row = rowblk + srow;
            int n = bn + row; if (n > N - 1) n = N - 1;
            int sl = (slot ^ (row & 7)) * 8;
            size_t goff = (size_t)n * ldb + k0 + sl;
            gload16(Bh + goff, Bhs + rowblk * 64);
        }
        __syncthreads();

#pragma unroll
        for (int ks = 0; ks < 2; ++ks) {
            half8 av[MT], bv[4];
#pragma unroll
            for (int m = 0; m < MT; ++m) {
                int arow = wr + m * 16 + l15;
                int off = arow * 64 + (((ks * 4 + g) ^ (arow & 7)) << 3);
                av[m] = *(const half8*)&Ahs[off];
            }
#pragma unroll
            for (int n = 0; n < 4; ++n) {
                int brow = wc + n * 16 + l15;
                int off = brow * 64 + (((ks * 4 + g) ^ (brow & 7)) << 3);
                bv[n] = *(const half8*)&Bhs[off];
            }
#pragma unroll
            for (int m = 0; m < MT; ++m)
#pragma unroll
                for (int n = 0; n < 4; ++n)
                    acc[m][n] = mfma16h(av[m], bv[n], acc[m][n]);
        }
        __syncthreads();
    }

    const int col0 = bn + wc + l15;
    const int row0 = bm + wr + (g << 2);
#pragma unroll
    for (int n = 0; n < 4; ++n) {
        int col = col0 + n * 16;
        if (col < N) {
#pragma unroll
            for (int m = 0; m < MT; ++m)
#pragma unroll
                for (int ri = 0; ri < 4; ++ri) {
                    if (OUT16) {
                        ((unsigned short*)Cp)[(size_t)(row0 + m * 16 + ri) * ldc + col] =
                            f2h_bits(acc[m][n][ri]);
                    } else {
                        ((float*)Cp)[(size_t)(row0 + m * 16 + ri) * ldc + col] = acc[m][n][ri];
                    }
                }
        }
    }
}

// depthwise 3x3 conv (pad 1) + bias + SiLU. 8 channels x 4 w-positions per thread.
// fp16 in (P xBC cols) / fp16 out (XC). Tap loads shared across the 4 outputs.
__global__ __launch_bounds__(128) void conv_silu(
    const unsigned short* __restrict__ P, const unsigned short* __restrict__ wt,
    const float* __restrict__ cb, unsigned short* __restrict__ XC)
{
    const int t = threadIdx.x;
    if (t >= 112) return;
    const int c8 = t * 8;
    const int l0 = blockIdx.x * 4;           // 4 outputs in one spatial row (56 % 4 == 0)
    const int bl = blockIdx.y;
    const int h = l0 / WWD, w0 = l0 % WWD;

    float acc[4][8];
    float4 b0 = *(const float4*)&cb[c8];
    float4 b1 = *(const float4*)&cb[c8 + 4];
#pragma unroll
    for (int o = 0; o < 4; ++o) {
        acc[o][0] = b0.x; acc[o][1] = b0.y; acc[o][2] = b0.z; acc[o][3] = b0.w;
        acc[o][4] = b1.x; acc[o][5] = b1.y; acc[o][6] = b1.z; acc[o][7] = b1.w;
    }

    const unsigned short* pb = P + (size_t)bl * LL * PSTRIDE + DINNER + c8;

#pragma unroll
    for (int kh = 0; kh < 3; ++kh) {
        int h2 = h + kh - 1;
        bool hok = (unsigned)h2 < HH;
        float xf[6][8];
#pragma unroll
        for (int j = 0; j < 6; ++j) {
            int wj = w0 - 1 + j;
            if (hok && (unsigned)wj < WWD) {
                half8 v = *(const half8*)&pb[(size_t)(h2 * WWD + wj) * PSTRIDE];
#pragma unroll
                for (int q = 0; q < 8; ++q) xf[j][q] = (float)v[q];
            } else {
#pragma unroll
                for (int q = 0; q < 8; ++q) xf[j][q] = 0.f;
            }
        }
#pragma unroll
        for (int kw = 0; kw < 3; ++kw) {
            half8 wv = *(const half8*)&wt[(kh * 3 + kw) * CDIM + c8];
            float wf[8];
#pragma unroll
            for (int q = 0; q < 8; ++q) wf[q] = (float)wv[q];
#pragma unroll
            for (int o = 0; o < 4; ++o)
#pragma unroll
                for (int q = 0; q < 8; ++q)
                    acc[o][q] += wf[q] * xf[o + kw][q];
        }
    }

#pragma unroll
    for (int o = 0; o < 4; ++o) {
        half8 ov;
#pragma unroll
        for (int q = 0; q < 8; ++q) {
            float a = acc[o][q];
            ov[q] = (_Float16)(a / (1.f + __expf(-a)));
        }
        *(half8*)&XC[((size_t)bl * LL + l0 + o) * CDIM + c8] = ov;
    }
}

// coefg[bl][h][l] = softplus(dt_raw + dt_bias[h]) * (-exp(A_log[h]))   (group-local)
__global__ __launch_bounds__(256) void coef_kernel(
    const unsigned short* __restrict__ P, const float* __restrict__ dt_bias,
    const float* __restrict__ A_log, float* __restrict__ coefg)
{
    int idx = blockIdx.x * 256 + threadIdx.x;
    int l = idx % LL;
    int h = (idx / LL) % NH;
    int bl = idx / (LL * NH);
    float x = h2f(P[((size_t)bl * LL + l) * PSTRIDE + DINNER + CDIM + h]) + dt_bias[h];
    float sp = (x > 20.f) ? x : log1pf(__expf(x));
    coefg[idx] = -__expf(A_log[h]) * sp;
}

// KVT[bl,h,p,s] += sum_{l in chunk} B[l,s] * x[l,h*64+p] * coefg[bl,h,l]
__global__ __launch_bounds__(256) void kv_kernel(
    const unsigned short* __restrict__ XC, const float* __restrict__ coefg,
    float* __restrict__ KVT)
{
    int h  = blockIdx.x;
    int bl = blockIdx.y;
    int lbase = blockIdx.z * 448;
    __shared__ float Bsh[32][DSTATE];
    __shared__ float Xsh[32][HD];
    __shared__ float cf[32];
    const int t = threadIdx.x;
    const int ss = t & 63;
    const int p0 = (t >> 6) * 16;
    const int lq = t >> 4;
    const int sq = (t & 15) * 4;
    float acc[16] = {};
    const unsigned short* xbase = XC + (size_t)bl * LL * CDIM;
    const float* crow = coefg + ((size_t)bl * NH + h) * LL + lbase;

    for (int l0 = 0; l0 < 448; l0 += 32) {
#pragma unroll
        for (int rr = 0; rr < 32; rr += 16) {
            const unsigned short* r = xbase + (size_t)(lbase + l0 + lq + rr) * CDIM;
            ushort4 bv = *(const ushort4*)&r[DINNER + sq];
            Bsh[lq + rr][sq + 0] = h2f(bv.x); Bsh[lq + rr][sq + 1] = h2f(bv.y);
            Bsh[lq + rr][sq + 2] = h2f(bv.z); Bsh[lq + rr][sq + 3] = h2f(bv.w);
            ushort4 xv = *(const ushort4*)&r[h * HD + sq];
            Xsh[lq + rr][sq + 0] = h2f(xv.x); Xsh[lq + rr][sq + 1] = h2f(xv.y);
            Xsh[lq + rr][sq + 2] = h2f(xv.z); Xsh[lq + rr][sq + 3] = h2f(xv.w);
        }
        if (t < 32) cf[t] = crow[l0 + t];
        __syncthreads();
#pragma unroll
        for (int li = 0; li < 32; ++li) {
            float bb = Bsh[li][ss] * cf[li];
            float4 x0 = *(const float4*)&Xsh[li][p0 + 0];
            float4 x1 = *(const float4*)&Xsh[li][p0 + 4];
            float4 x2 = *(const float4*)&Xsh[li][p0 + 8];
            float4 x3 = *(const float4*)&Xsh[li][p0 + 12];
            acc[0]  += x0.x * bb; acc[1]  += x0.y * bb; acc[2]  += x0.z * bb; acc[3]  += x0.w * bb;
            acc[4]  += x1.x * bb; acc[5]  += x1.y * bb; acc[6]  += x1.z * bb; acc[7]  += x1.w * bb;
            acc[8]  += x2.x * bb; acc[9]  += x2.y * bb; acc[10] += x2.z * bb; acc[11] += x2.w * bb;
            acc[12] += x3.x * bb; acc[13] += x3.y * bb; acc[14] += x3.z * bb; acc[15] += x3.w * bb;
        }
        __syncthreads();
    }
    float* outp = KVT + ((size_t)bl * NH + h) * HD * DSTATE;
#pragma unroll
    for (int j = 0; j < 16; ++j)
        atomicAdd(&outp[(size_t)(p0 + j) * DSTATE + ss], acc[j]);
}

// Yg = Cmat @ KVcat + x*D, gated by silu(z); fp16 yg written in-place over z cols of P.
__global__ __launch_bounds__(256) void ckv_gate(
    unsigned short* __restrict__ P, const unsigned short* __restrict__ XC,
    const float* __restrict__ KVT, const float* __restrict__ Dp)
{
    const int t = threadIdx.x;
    const int lane = t & 63;
    const int w = t >> 6;
    const int bn = blockIdx.x * 128;
    const int mt = blockIdx.y;       // 0..48
    const int bl = blockIdx.z;
    const int wc = w * 32;
    const int l15 = lane & 15;
    const int kq = (lane >> 4) * 8;

    f32x4 acc[4][2];
#pragma unroll
    for (int m = 0; m < 4; ++m)
#pragma unroll
        for (int n = 0; n < 2; ++n) acc[m][n] = (f32x4){0.f, 0.f, 0.f, 0.f};

    const size_t rbase = (size_t)bl * LL + mt * 64;
    const unsigned short* Cb = XC + rbase * CDIM + (DINNER + DSTATE);

    const float* Bptr[2];
    float dcoef[2];
    int dglob[2];
#pragma unroll
    for (int n = 0; n < 2; ++n) {
        int d = bn + wc + n * 16 + l15;
        dglob[n] = d;
        int h = d >> 6, p = d & 63;
        Bptr[n] = KVT + (((size_t)bl * NH + h) * HD + p) * DSTATE;
        dcoef[n] = Dp[h];
    }

#pragma unroll
    for (int ks = 0; ks < 2; ++ks) {
        const int koff = ks * 32 + kq;
        half8 av[4], bv[2];
#pragma unroll
        for (int m = 0; m < 4; ++m)
            av[m] = *(const half8*)&Cb[(size_t)(l15 + m * 16) * CDIM + koff];
#pragma unroll
        for (int n = 0; n < 2; ++n) {
            float tmp[8];
            *(float4*)&tmp[0] = *(const float4*)&Bptr[n][koff];
            *(float4*)&tmp[4] = *(const float4*)&Bptr[n][koff + 4];
#pragma unroll
            for (int i = 0; i < 8; ++i) bv[n][i] = (_Float16)tmp[i];
        }
#pragma unroll
        for (int m = 0; m < 4; ++m)
#pragma unroll
            for (int n = 0; n < 2; ++n)
                acc[m][n] = mfma16h(av[m], bv[n], acc[m][n]);
    }

    const int r0 = (lane >> 4) << 2;
#pragma unroll
    for (int m = 0; m < 4; ++m)
#pragma unroll
        for (int ri = 0; ri < 4; ++ri) {
            size_t grow = rbase + m * 16 + r0 + ri;
#pragma unroll
            for (int n = 0; n < 2; ++n) {
                int d = dglob[n];
                float x = h2f(XC[grow * CDIM + d]);
                unsigned short* zp = P + grow * PSTRIDE + d;
                float z = h2f(*zp);
                float sz = z / (1.f + __expf(-z));
                *zp = f2h_bits((acc[m][n][ri] + x * dcoef[n]) * sz);
            }
        }
}

// LayerNorm(768): one wave per row, no LDS. fp16 in/out over P z cols.
__global__ __launch_bounds__(256, 4) void ln_kernel(
    unsigned short* __restrict__ P, const float* __restrict__ ln_g, const float* __restrict__ ln_b)
{
    const int row = blockIdx.x * 4 + (threadIdx.x >> 6);
    const int lane = threadIdx.x & 63;
    unsigned short* pr = P + (size_t)row * PSTRIDE;
    const bool act = lane < 48;                 // 48 lanes x 16 elems = 768

    float v[16];
    float s1 = 0.f, s2 = 0.f;
    if (act) {
        half8 a = *(const half8*)&pr[lane * 16];
        half8 b = *(const half8*)&pr[lane * 16 + 8];
#pragma unroll
        for (int q = 0; q < 8; ++q) { v[q] = (float)a[q]; v[8 + q] = (float)b[q]; }
#pragma unroll
        for (int q = 0; q < 16; ++q) { s1 += v[q]; s2 += v[q] * v[q]; }
    } else {
#pragma unroll
        for (int q = 0; q < 16; ++q) v[q] = 0.f;
    }
#pragma unroll
    for (int off = 32; off; off >>= 1) {
        s1 += __shfl_xor(s1, off, 64);
        s2 += __shfl_xor(s2, off, 64);
    }
    float mu = s1 * (1.f / 768.f);
    float var = s2 * (1.f / 768.f) - mu * mu;
    float rstd = rsqrtf(var + LNEPS);

    if (act) {
        const float* gp = ln_g + lane * 16;
        const float* bp = ln_b + lane * 16;
        half8 o0, o1;
#pragma unroll
        for (int q = 0; q < 8; ++q) {
            o0[q] = (_Float16)((v[q] - mu) * rstd * gp[q] + bp[q]);
            o1[q] = (_Float16)((v[8 + q] - mu) * rstd * gp[8 + q] + bp[8 + q]);
        }
        *(half8*)&pr[lane * 16] = o0;
        *(half8*)&pr[lane * 16 + 8] = o1;
    }
}

extern "C" void kernel_launch(void* const* d_in, const int* in_sizes, int n_in,
                              void* d_out, int out_size, void* d_ws, size_t ws_size,
                              hipStream_t stream)
{
    const float* u       = (const float*)d_in[0];
    const float* W_in    = (const float*)d_in[1];
    const float* conv_w  = (const float*)d_in[2];
    const float* conv_b  = (const float*)d_in[3];
    const float* dt_bias = (const float*)d_in[4];
    const float* A_log   = (const float*)d_in[5];
    const float* Dp      = (const float*)d_in[6];
    const float* ln_g    = (const float*)d_in[7];
    const float* ln_b    = (const float*)d_in[8];
    const float* W_out   = (const float*)d_in[9];
    float* out = (float*)d_out;
    (void)ws_size;

    const int B = in_sizes[0] / (LL * DMODEL);   // 16
    const int M = B * LL;                        // 50176

    // workspace (~110 MiB), all fp16 intermediates
    unsigned short* P  = (unsigned short*)d_ws;             // GM*PSTRIDE fp16
    unsigned short* XC = P + (size_t)GM * PSTRIDE;          // GM*896 fp16
    float* coefg = (float*)(XC + (size_t)GM * CDIM);        // GRP*NH*LL f32
    float* KVT   = coefg + (size_t)GRP * NH * LL;           // GRP*NH*64*64 f32
    unsigned short* u16  = (unsigned short*)(KVT + (size_t)GRP * NH * HD * DSTATE); // M*384
    unsigned short* Wi16 = u16 + (size_t)M * DMODEL;        // 1676*384
    unsigned short* Wo16 = Wi16 + (size_t)DPROJ * DMODEL;   // 384*768
    unsigned short* wt16 = Wo16 + (size_t)DMODEL * DINNER;  // 9*896

    // one-time fp16 converts / packs
    cvt_f16<<<((size_t)M * DMODEL / 4 + 255) / 256, 256, 0, stream>>>(u, u16, M * DMODEL / 4);
    cvt_f16<<<(DPROJ * DMODEL / 4 + 255) / 256, 256, 0, stream>>>(W_in, Wi16, DPROJ * DMODEL / 4);
    cvt_f16<<<(DMODEL * DINNER / 4 + 255) / 256, 256, 0, stream>>>(W_out, Wo16, DMODEL * DINNER / 4);
    pack_w16<<<(CDIM + 255) / 256, 256, 0, stream>>>(conv_w, wt16);

    for (int b0 = 0; b0 < B; b0 += GRP) {
        // 1) P = u_grp @ W_in^T  (fp16 MFMA, fp16 store)
        gemm_h<4, 1><<<dim3(14, GM / 128), 256, 0, stream>>>(
            u16 + (size_t)b0 * LL * DMODEL, DMODEL, Wi16, DMODEL, P, PSTRIDE, DPROJ, DMODEL);

        // 2) dt coefficients
        coef_kernel<<<(GRP * NH * LL) / 256, 256, 0, stream>>>(P, dt_bias, A_log, coefg);

        // 3) depthwise conv + SiLU (8ch x 4w per thread)
        conv_silu<<<dim3(LL / 4, GRP), 128, 0, stream>>>(P, wt16, conv_b, XC);

        // 4) KV einsum (fp16 reads, fp32 acc, transposed KVT[p][s])
        hipMemsetAsync(KVT, 0, (size_t)GRP * NH * DSTATE * HD * sizeof(float), stream);
        kv_kernel<<<dim3(NH, GRP, 7), 256, 0, stream>>>(XC, coefg, KVT);

        // 5a) yg = (C@KVcat + x*D) * silu(z)  (fp16 MFMA, fp16 in-place over z cols of P)
        ckv_gate<<<dim3(6, 49, GRP), 256, 0, stream>>>(P, XC, KVT, Dp);

        // 5b) LayerNorm -> y fp16 into P z cols (1 wave/row)
        ln_kernel<<<GM / 4, 256, 0, stream>>>(P, ln_g, ln_b);

        // 6) out_grp = y @ W_out^T  (fp16 A in P, fp32 out)
        gemm_h<2, 0><<<dim3(3, GM / 64), 256, 0, stream>>>(
            P, PSTRIDE, Wo16, DINNER,
            out + (size_t)b0 * LL * DMODEL, DMODEL, DMODEL, DINNER);
    }
}

// Round 11
// 602.418 us; speedup vs baseline: 3.8141x; 1.1762x over previous
//
#include <hip/hip_runtime.h>
#include <hip/hip_bf16.h>

#define LL 3136
#define HH 56
#define WWD 56
#define DMODEL 384
#define DINNER 768
#define NH 12
#define HD 64
#define DSTATE 64
#define CDIM 896
#define DPROJ 1676
#define PSTRIDE 1680           // padded P row stride in ushorts (3360 B, 16B-aligned rows)
#define LNEPS 1e-5f
#define GRP 8
#define GM (GRP * LL)          // 25088 rows per group

typedef __attribute__((ext_vector_type(8))) _Float16 half8;
typedef __attribute__((ext_vector_type(4))) float f32x4;

__device__ __forceinline__ unsigned short f2h_bits(float f) {
    _Float16 h = (_Float16)f;   // RNE
    return *reinterpret_cast<unsigned short*>(&h);
}
__device__ __forceinline__ float h2f(unsigned short u) {
    _Float16 h = *reinterpret_cast<_Float16*>(&u);
    return (float)h;
}

__device__ __forceinline__ f32x4 mfma16h(half8 a, half8 b, f32x4 c) {
    return __builtin_amdgcn_mfma_f32_16x16x32_f16(a, b, c, 0, 0, 0);
}

// async global->LDS, 16B per lane; dest = lds base (wave-uniform) + lane*16
__device__ __forceinline__ void gload16(const unsigned short* g, unsigned short* l) {
    __builtin_amdgcn_global_load_lds(
        (const __attribute__((address_space(1))) unsigned int*)g,
        (__attribute__((address_space(3))) unsigned int*)l, 16, 0, 0);
}

// elementwise convert fp32 -> fp16 (RNE)
__global__ __launch_bounds__(256) void cvt_f16(
    const float* __restrict__ in, unsigned short* __restrict__ out, int n4)
{
    int i = blockIdx.x * 256 + threadIdx.x;
    if (i >= n4) return;
    float4 v = ((const float4*)in)[i];
    ushort4 o;
    o.x = f2h_bits(v.x); o.y = f2h_bits(v.y);
    o.z = f2h_bits(v.z); o.w = f2h_bits(v.w);
    ((ushort4*)out)[i] = o;
}

// pack conv weights f32 [c][tap] -> fp16 [tap][c]
__global__ __launch_bounds__(256) void pack_w16(
    const float* __restrict__ cw, unsigned short* __restrict__ wt)
{
    int c = blockIdx.x * 256 + threadIdx.x;
    if (c >= CDIM) return;
#pragma unroll
    for (int tap = 0; tap < 9; ++tap)
        wt[tap * CDIM + c] = f2h_bits(cw[c * 9 + tap]);
}

// C[m,n] = sum_k A[m,k]*B[n,k], fp16 operands, fp32 acc; OUT16 selects fp16/fp32 store.
// m97 structure: global_load_lds dwordx4 staging, linear LDS + XOR granule swizzle.
template<int MT, int OUT16>
__global__ __launch_bounds__(256) void gemm_h(
    const unsigned short* __restrict__ Ah, int lda,
    const unsigned short* __restrict__ Bh, int ldb,
    void* __restrict__ Cp, int ldc, int N, int K)
{
    constexpr int BM = MT * 32;
    __shared__ __align__(16) unsigned short Ahs[BM * 64];
    __shared__ __align__(16) unsigned short Bhs[128 * 64];
    const int t = threadIdx.x;
    const int lane = t & 63;
    const int w = t >> 6;
    const int bn = blockIdx.x * 128;
    const int bm = blockIdx.y * BM;
    const int wr = (w >> 1) * (MT * 16);
    const int wc = (w & 1) * 64;
    const int l15 = lane & 15;
    const int g   = lane >> 4;
    const int srow = lane >> 3;
    const int slot = lane & 7;

    f32x4 acc[MT][4];
#pragma unroll
    for (int m = 0; m < MT; ++m)
#pragma unroll
        for (int n = 0; n < 4; ++n) acc[m][n] = (f32x4){0.f, 0.f, 0.f, 0.f};

    for (int k0 = 0; k0 < K; k0 += 64) {
#pragma unroll
        for (int it = 0; it < MT; ++it) {            // A: BM rows
            int rowblk = w * (8 * MT) + it * 8;
            int row = rowblk + srow;
            int sl = (slot ^ (row & 7)) * 8;
            size_t goff = (size_t)(bm + row) * lda + k0 + sl;
            gload16(Ah + goff, Ahs + rowblk * 64);
        }
#pragma unroll
        for (int it = 0; it < 4; ++it) {             // B: 128 rows
            int rowblk = w * 32 + it * 8;
            int row = rowblk + srow;
            int n = bn + row; if (n > N - 1) n = N - 1;
            int sl = (slot ^ (row & 7)) * 8;
            size_t goff = (size_t)n * ldb + k0 + sl;
            gload16(Bh + goff, Bhs + rowblk * 64);
        }
        __syncthreads();

#pragma unroll
        for (int ks = 0; ks < 2; ++ks) {
            half8 av[MT], bv[4];
#pragma unroll
            for (int m = 0; m < MT; ++m) {
                int arow = wr + m * 16 + l15;
                int off = arow * 64 + (((ks * 4 + g) ^ (arow & 7)) << 3);
                av[m] = *(const half8*)&Ahs[off];
            }
#pragma unroll
            for (int n = 0; n < 4; ++n) {
                int brow = wc + n * 16 + l15;
                int off = brow * 64 + (((ks * 4 + g) ^ (brow & 7)) << 3);
                bv[n] = *(const half8*)&Bhs[off];
            }
#pragma unroll
            for (int m = 0; m < MT; ++m)
#pragma unroll
                for (int n = 0; n < 4; ++n)
                    acc[m][n] = mfma16h(av[m], bv[n], acc[m][n]);
        }
        __syncthreads();
    }

    const int col0 = bn + wc + l15;
    const int row0 = bm + wr + (g << 2);
#pragma unroll
    for (int n = 0; n < 4; ++n) {
        int col = col0 + n * 16;
        if (col < N) {
#pragma unroll
            for (int m = 0; m < MT; ++m)
#pragma unroll
                for (int ri = 0; ri < 4; ++ri) {
                    if (OUT16) {
                        ((unsigned short*)Cp)[(size_t)(row0 + m * 16 + ri) * ldc + col] =
                            f2h_bits(acc[m][n][ri]);
                    } else {
                        ((float*)Cp)[(size_t)(row0 + m * 16 + ri) * ldc + col] = acc[m][n][ri];
                    }
                }
        }
    }
}

// depthwise 3x3 conv (pad 1) + bias + SiLU. 8 channels x 4 w-positions per thread.
__global__ __launch_bounds__(128) void conv_silu(
    const unsigned short* __restrict__ P, const unsigned short* __restrict__ wt,
    const float* __restrict__ cb, unsigned short* __restrict__ XC)
{
    const int t = threadIdx.x;
    if (t >= 112) return;
    const int c8 = t * 8;
    const int l0 = blockIdx.x * 4;           // 4 outputs in one spatial row (56 % 4 == 0)
    const int bl = blockIdx.y;
    const int h = l0 / WWD, w0 = l0 % WWD;

    float acc[4][8];
    float4 b0 = *(const float4*)&cb[c8];
    float4 b1 = *(const float4*)&cb[c8 + 4];
#pragma unroll
    for (int o = 0; o < 4; ++o) {
        acc[o][0] = b0.x; acc[o][1] = b0.y; acc[o][2] = b0.z; acc[o][3] = b0.w;
        acc[o][4] = b1.x; acc[o][5] = b1.y; acc[o][6] = b1.z; acc[o][7] = b1.w;
    }

    const unsigned short* pb = P + (size_t)bl * LL * PSTRIDE + DINNER + c8;

#pragma unroll
    for (int kh = 0; kh < 3; ++kh) {
        int h2 = h + kh - 1;
        bool hok = (unsigned)h2 < HH;
        float xf[6][8];
#pragma unroll
        for (int j = 0; j < 6; ++j) {
            int wj = w0 - 1 + j;
            if (hok && (unsigned)wj < WWD) {
                half8 v = *(const half8*)&pb[(size_t)(h2 * WWD + wj) * PSTRIDE];
#pragma unroll
                for (int q = 0; q < 8; ++q) xf[j][q] = (float)v[q];
            } else {
#pragma unroll
                for (int q = 0; q < 8; ++q) xf[j][q] = 0.f;
            }
        }
#pragma unroll
        for (int kw = 0; kw < 3; ++kw) {
            half8 wv = *(const half8*)&wt[(kh * 3 + kw) * CDIM + c8];
            float wf[8];
#pragma unroll
            for (int q = 0; q < 8; ++q) wf[q] = (float)wv[q];
#pragma unroll
            for (int o = 0; o < 4; ++o)
#pragma unroll
                for (int q = 0; q < 8; ++q)
                    acc[o][q] += wf[q] * xf[o + kw][q];
        }
    }

#pragma unroll
    for (int o = 0; o < 4; ++o) {
        half8 ov;
#pragma unroll
        for (int q = 0; q < 8; ++q) {
            float a = acc[o][q];
            ov[q] = (_Float16)(a / (1.f + __expf(-a)));
        }
        *(half8*)&XC[((size_t)bl * LL + l0 + o) * CDIM + c8] = ov;
    }
}

// coefg[bl][h][l] = softplus(dt_raw + dt_bias[h]) * (-exp(A_log[h]))   (group-local)
__global__ __launch_bounds__(256) void coef_kernel(
    const unsigned short* __restrict__ P, const float* __restrict__ dt_bias,
    const float* __restrict__ A_log, float* __restrict__ coefg)
{
    int idx = blockIdx.x * 256 + threadIdx.x;
    int l = idx % LL;
    int h = (idx / LL) % NH;
    int bl = idx / (LL * NH);
    float x = h2f(P[((size_t)bl * LL + l) * PSTRIDE + DINNER + CDIM + h]) + dt_bias[h];
    float sp = (x > 20.f) ? x : log1pf(__expf(x));
    coefg[idx] = -__expf(A_log[h]) * sp;
}

// KVT[bl,h,p,s] += sum_{l in chunk of 224} B[l,s] * x[l,h*64+p] * coefg[bl,h,l]
__global__ __launch_bounds__(256) void kv_kernel(
    const unsigned short* __restrict__ XC, const float* __restrict__ coefg,
    float* __restrict__ KVT)
{
    int h  = blockIdx.x;
    int bl = blockIdx.y;
    int lbase = blockIdx.z * 224;
    __shared__ float Bsh[32][DSTATE];
    __shared__ float Xsh[32][HD];
    __shared__ float cf[32];
    const int t = threadIdx.x;
    const int ss = t & 63;
    const int p0 = (t >> 6) * 16;
    const int lq = t >> 4;
    const int sq = (t & 15) * 4;
    float acc[16] = {};
    const unsigned short* xbase = XC + (size_t)bl * LL * CDIM;
    const float* crow = coefg + ((size_t)bl * NH + h) * LL + lbase;

    for (int l0 = 0; l0 < 224; l0 += 32) {
#pragma unroll
        for (int rr = 0; rr < 32; rr += 16) {
            const unsigned short* r = xbase + (size_t)(lbase + l0 + lq + rr) * CDIM;
            ushort4 bv = *(const ushort4*)&r[DINNER + sq];
            Bsh[lq + rr][sq + 0] = h2f(bv.x); Bsh[lq + rr][sq + 1] = h2f(bv.y);
            Bsh[lq + rr][sq + 2] = h2f(bv.z); Bsh[lq + rr][sq + 3] = h2f(bv.w);
            ushort4 xv = *(const ushort4*)&r[h * HD + sq];
            Xsh[lq + rr][sq + 0] = h2f(xv.x); Xsh[lq + rr][sq + 1] = h2f(xv.y);
            Xsh[lq + rr][sq + 2] = h2f(xv.z); Xsh[lq + rr][sq + 3] = h2f(xv.w);
        }
        if (t < 32) cf[t] = crow[l0 + t];
        __syncthreads();
#pragma unroll
        for (int li = 0; li < 32; ++li) {
            float bb = Bsh[li][ss] * cf[li];
            float4 x0 = *(const float4*)&Xsh[li][p0 + 0];
            float4 x1 = *(const float4*)&Xsh[li][p0 + 4];
            float4 x2 = *(const float4*)&Xsh[li][p0 + 8];
            float4 x3 = *(const float4*)&Xsh[li][p0 + 12];
            acc[0]  += x0.x * bb; acc[1]  += x0.y * bb; acc[2]  += x0.z * bb; acc[3]  += x0.w * bb;
            acc[4]  += x1.x * bb; acc[5]  += x1.y * bb; acc[6]  += x1.z * bb; acc[7]  += x1.w * bb;
            acc[8]  += x2.x * bb; acc[9]  += x2.y * bb; acc[10] += x2.z * bb; acc[11] += x2.w * bb;
            acc[12] += x3.x * bb; acc[13] += x3.y * bb; acc[14] += x3.z * bb; acc[15] += x3.w * bb;
        }
        __syncthreads();
    }
    float* outp = KVT + ((size_t)bl * NH + h) * HD * DSTATE;
#pragma unroll
    for (int j = 0; j < 16; ++j)
        atomicAdd(&outp[(size_t)(p0 + j) * DSTATE + ss], acc[j]);
}

// Yg = Cmat @ KVcat + x*D, gated by silu(z); fp16 yg written in-place over z cols of P.
__global__ __launch_bounds__(256) void ckv_gate(
    unsigned short* __restrict__ P, const unsigned short* __restrict__ XC,
    const float* __restrict__ KVT, const float* __restrict__ Dp)
{
    const int t = threadIdx.x;
    const int lane = t & 63;
    const int w = t >> 6;
    const int bn = blockIdx.x * 128;
    const int mt = blockIdx.y;       // 0..48
    const int bl = blockIdx.z;
    const int wc = w * 32;
    const int l15 = lane & 15;
    const int kq = (lane >> 4) * 8;

    f32x4 acc[4][2];
#pragma unroll
    for (int m = 0; m < 4; ++m)
#pragma unroll
        for (int n = 0; n < 2; ++n) acc[m][n] = (f32x4){0.f, 0.f, 0.f, 0.f};

    const size_t rbase = (size_t)bl * LL + mt * 64;
    const unsigned short* Cb = XC + rbase * CDIM + (DINNER + DSTATE);

    const float* Bptr[2];
    float dcoef[2];
    int dglob[2];
#pragma unroll
    for (int n = 0; n < 2; ++n) {
        int d = bn + wc + n * 16 + l15;
        dglob[n] = d;
        int h = d >> 6, p = d & 63;
        Bptr[n] = KVT + (((size_t)bl * NH + h) * HD + p) * DSTATE;
        dcoef[n] = Dp[h];
    }

#pragma unroll
    for (int ks = 0; ks < 2; ++ks) {
        const int koff = ks * 32 + kq;
        half8 av[4], bv[2];
#pragma unroll
        for (int m = 0; m < 4; ++m)
            av[m] = *(const half8*)&Cb[(size_t)(l15 + m * 16) * CDIM + koff];
#pragma unroll
        for (int n = 0; n < 2; ++n) {
            float tmp[8];
            *(float4*)&tmp[0] = *(const float4*)&Bptr[n][koff];
            *(float4*)&tmp[4] = *(const float4*)&Bptr[n][koff + 4];
#pragma unroll
            for (int i = 0; i < 8; ++i) bv[n][i] = (_Float16)tmp[i];
        }
#pragma unroll
        for (int m = 0; m < 4; ++m)
#pragma unroll
            for (int n = 0; n < 2; ++n)
                acc[m][n] = mfma16h(av[m], bv[n], acc[m][n]);
    }

    const int r0 = (lane >> 4) << 2;
#pragma unroll
    for (int m = 0; m < 4; ++m)
#pragma unroll
        for (int ri = 0; ri < 4; ++ri) {
            size_t grow = rbase + m * 16 + r0 + ri;
#pragma unroll
            for (int n = 0; n < 2; ++n) {
                int d = dglob[n];
                float x = h2f(XC[grow * CDIM + d]);
                unsigned short* zp = P + grow * PSTRIDE + d;
                float z = h2f(*zp);
                float sz = z / (1.f + __expf(-z));
                *zp = f2h_bits((acc[m][n][ri] + x * dcoef[n]) * sz);
            }
        }
}

// LayerNorm(768): one wave per row, no LDS. fp16 in/out over P z cols.
__global__ __launch_bounds__(256, 4) void ln_kernel(
    unsigned short* __restrict__ P, const float* __restrict__ ln_g, const float* __restrict__ ln_b)
{
    const int row = blockIdx.x * 4 + (threadIdx.x >> 6);
    const int lane = threadIdx.x & 63;
    unsigned short* pr = P + (size_t)row * PSTRIDE;
    const bool act = lane < 48;                 // 48 lanes x 16 elems = 768

    float v[16];
    float s1 = 0.f, s2 = 0.f;
    if (act) {
        half8 a = *(const half8*)&pr[lane * 16];
        half8 b = *(const half8*)&pr[lane * 16 + 8];
#pragma unroll
        for (int q = 0; q < 8; ++q) { v[q] = (float)a[q]; v[8 + q] = (float)b[q]; }
#pragma unroll
        for (int q = 0; q < 16; ++q) { s1 += v[q]; s2 += v[q] * v[q]; }
    } else {
#pragma unroll
        for (int q = 0; q < 16; ++q) v[q] = 0.f;
    }
#pragma unroll
    for (int off = 32; off; off >>= 1) {
        s1 += __shfl_xor(s1, off, 64);
        s2 += __shfl_xor(s2, off, 64);
    }
    float mu = s1 * (1.f / 768.f);
    float var = s2 * (1.f / 768.f) - mu * mu;
    float rstd = rsqrtf(var + LNEPS);

    if (act) {
        const float* gp = ln_g + lane * 16;
        const float* bp = ln_b + lane * 16;
        half8 o0, o1;
#pragma unroll
        for (int q = 0; q < 8; ++q) {
            o0[q] = (_Float16)((v[q] - mu) * rstd * gp[q] + bp[q]);
            o1[q] = (_Float16)((v[8 + q] - mu) * rstd * gp[8 + q] + bp[8 + q]);
        }
        *(half8*)&pr[lane * 16] = o0;
        *(half8*)&pr[lane * 16 + 8] = o1;
    }
}

extern "C" void kernel_launch(void* const* d_in, const int* in_sizes, int n_in,
                              void* d_out, int out_size, void* d_ws, size_t ws_size,
                              hipStream_t stream)
{
    const float* u       = (const float*)d_in[0];
    const float* W_in    = (const float*)d_in[1];
    const float* conv_w  = (const float*)d_in[2];
    const float* conv_b  = (const float*)d_in[3];
    const float* dt_bias = (const float*)d_in[4];
    const float* A_log   = (const float*)d_in[5];
    const float* Dp      = (const float*)d_in[6];
    const float* ln_g    = (const float*)d_in[7];
    const float* ln_b    = (const float*)d_in[8];
    const float* W_out   = (const float*)d_in[9];
    float* out = (float*)d_out;
    (void)ws_size;

    const int B = in_sizes[0] / (LL * DMODEL);   // 16
    const int M = B * LL;                        // 50176

    // workspace (~173 MiB), all fp16 intermediates
    unsigned short* P  = (unsigned short*)d_ws;             // GM*PSTRIDE fp16
    unsigned short* XC = P + (size_t)GM * PSTRIDE;          // GM*896 fp16
    float* coefg = (float*)(XC + (size_t)GM * CDIM);        // GRP*NH*LL f32
    float* KVT   = coefg + (size_t)GRP * NH * LL;           // GRP*NH*64*64 f32
    unsigned short* u16  = (unsigned short*)(KVT + (size_t)GRP * NH * HD * DSTATE); // M*384
    unsigned short* Wi16 = u16 + (size_t)M * DMODEL;        // 1676*384
    unsigned short* Wo16 = Wi16 + (size_t)DPROJ * DMODEL;   // 384*768
    unsigned short* wt16 = Wo16 + (size_t)DMODEL * DINNER;  // 9*896

    // one-time fp16 converts / packs
    cvt_f16<<<((size_t)M * DMODEL / 4 + 255) / 256, 256, 0, stream>>>(u, u16, M * DMODEL / 4);
    cvt_f16<<<(DPROJ * DMODEL / 4 + 255) / 256, 256, 0, stream>>>(W_in, Wi16, DPROJ * DMODEL / 4);
    cvt_f16<<<(DMODEL * DINNER / 4 + 255) / 256, 256, 0, stream>>>(W_out, Wo16, DMODEL * DINNER / 4);
    pack_w16<<<(CDIM + 255) / 256, 256, 0, stream>>>(conv_w, wt16);

    for (int b0 = 0; b0 < B; b0 += GRP) {
        // 1) P = u_grp @ W_in^T  (fp16 MFMA, fp16 store)
        gemm_h<4, 1><<<dim3(14, GM / 128), 256, 0, stream>>>(
            u16 + (size_t)b0 * LL * DMODEL, DMODEL, Wi16, DMODEL, P, PSTRIDE, DPROJ, DMODEL);

        // 2) dt coefficients
        coef_kernel<<<(GRP * NH * LL) / 256, 256, 0, stream>>>(P, dt_bias, A_log, coefg);

        // 3) depthwise conv + SiLU (8ch x 4w per thread)
        conv_silu<<<dim3(LL / 4, GRP), 128, 0, stream>>>(P, wt16, conv_b, XC);

        // 4) KV einsum (fp16 reads, fp32 acc, transposed KVT[p][s]; 14 L-chunks of 224)
        hipMemsetAsync(KVT, 0, (size_t)GRP * NH * DSTATE * HD * sizeof(float), stream);
        kv_kernel<<<dim3(NH, GRP, 14), 256, 0, stream>>>(XC, coefg, KVT);

        // 5a) yg = (C@KVcat + x*D) * silu(z)  (fp16 MFMA, fp16 in-place over z cols of P)
        ckv_gate<<<dim3(6, 49, GRP), 256, 0, stream>>>(P, XC, KVT, Dp);

        // 5b) LayerNorm -> y fp16 into P z cols (1 wave/row)
        ln_kernel<<<GM / 4, 256, 0, stream>>>(P, ln_g, ln_b);

        // 6) out_grp = y @ W_out^T  (fp16 A in P, fp32 out)
        gemm_h<2, 0><<<dim3(3, GM / 64), 256, 0, stream>>>(
            P, PSTRIDE, Wo16, DINNER,
            out + (size_t)b0 * LL * DMODEL, DMODEL, DMODEL, DINNER);
    }
}

// Round 12
// 554.519 us; speedup vs baseline: 4.1435x; 1.0864x over previous
//
#include <hip/hip_runtime.h>
#include <hip/hip_bf16.h>

#define LL 3136
#define HH 56
#define WWD 56
#define DMODEL 384
#define DINNER 768
#define NH 12
#define HD 64
#define DSTATE 64
#define CDIM 896
#define DPROJ 1676
#define PSTRIDE 1680           // padded P row stride in ushorts (3360 B, 16B-aligned rows)
#define LNEPS 1e-5f
#define GRP 8
#define GM (GRP * LL)          // 25088 rows per group

typedef __attribute__((ext_vector_type(8))) _Float16 half8;
typedef __attribute__((ext_vector_type(4))) float f32x4;

__device__ __forceinline__ unsigned short f2h_bits(float f) {
    _Float16 h = (_Float16)f;   // RNE
    return *reinterpret_cast<unsigned short*>(&h);
}
__device__ __forceinline__ float h2f(unsigned short u) {
    _Float16 h = *reinterpret_cast<_Float16*>(&u);
    return (float)h;
}

__device__ __forceinline__ f32x4 mfma16h(half8 a, half8 b, f32x4 c) {
    return __builtin_amdgcn_mfma_f32_16x16x32_f16(a, b, c, 0, 0, 0);
}

// async global->LDS, 16B per lane; dest = lds base (wave-uniform) + lane*16
__device__ __forceinline__ void gload16(const unsigned short* g, unsigned short* l) {
    __builtin_amdgcn_global_load_lds(
        (const __attribute__((address_space(1))) unsigned int*)g,
        (__attribute__((address_space(3))) unsigned int*)l, 16, 0, 0);
}

// elementwise convert fp32 -> fp16 (RNE)
__global__ __launch_bounds__(256) void cvt_f16(
    const float* __restrict__ in, unsigned short* __restrict__ out, int n4)
{
    int i = blockIdx.x * 256 + threadIdx.x;
    if (i >= n4) return;
    float4 v = ((const float4*)in)[i];
    ushort4 o;
    o.x = f2h_bits(v.x); o.y = f2h_bits(v.y);
    o.z = f2h_bits(v.z); o.w = f2h_bits(v.w);
    ((ushort4*)out)[i] = o;
}

// pack conv weights f32 [c][tap] -> fp16 [tap][c]
__global__ __launch_bounds__(256) void pack_w16(
    const float* __restrict__ cw, unsigned short* __restrict__ wt)
{
    int c = blockIdx.x * 256 + threadIdx.x;
    if (c >= CDIM) return;
#pragma unroll
    for (int tap = 0; tap < 9; ++tap)
        wt[tap * CDIM + c] = f2h_bits(cw[c * 9 + tap]);
}

// C[m,n] = sum_k A[m,k]*B[n,k], fp16 operands, fp32 acc; OUT16 selects fp16/fp32 store.
// m97 structure: global_load_lds dwordx4 staging, linear LDS + XOR granule swizzle.
template<int MT, int OUT16>
__global__ __launch_bounds__(256) void gemm_h(
    const unsigned short* __restrict__ Ah, int lda,
    const unsigned short* __restrict__ Bh, int ldb,
    void* __restrict__ Cp, int ldc, int N, int K)
{
    constexpr int BM = MT * 32;
    __shared__ __align__(16) unsigned short Ahs[BM * 64];
    __shared__ __align__(16) unsigned short Bhs[128 * 64];
    const int t = threadIdx.x;
    const int lane = t & 63;
    const int w = t >> 6;
    const int bn = blockIdx.x * 128;
    const int bm = blockIdx.y * BM;
    const int wr = (w >> 1) * (MT * 16);
    const int wc = (w & 1) * 64;
    const int l15 = lane & 15;
    const int g   = lane >> 4;
    const int srow = lane >> 3;
    const int slot = lane & 7;

    f32x4 acc[MT][4];
#pragma unroll
    for (int m = 0; m < MT; ++m)
#pragma unroll
        for (int n = 0; n < 4; ++n) acc[m][n] = (f32x4){0.f, 0.f, 0.f, 0.f};

    for (int k0 = 0; k0 < K; k0 += 64) {
#pragma unroll
        for (int it = 0; it < MT; ++it) {            // A: BM rows
            int rowblk = w * (8 * MT) + it * 8;
            int row = rowblk + srow;
            int sl = (slot ^ (row & 7)) * 8;
            size_t goff = (size_t)(bm + row) * lda + k0 + sl;
            gload16(Ah + goff, Ahs + rowblk * 64);
        }
#pragma unroll
        for (int it = 0; it < 4; ++it) {             // B: 128 rows
            int rowblk = w * 32 + it * 8;
            int row = rowblk + srow;
            int n = bn + row; if (n > N - 1) n = N - 1;
            int sl = (slot ^ (row & 7)) * 8;
            size_t goff = (size_t)n * ldb + k0 + sl;
            gload16(Bh + goff, Bhs + rowblk * 64);
        }
        __syncthreads();

#pragma unroll
        for (int ks = 0; ks < 2; ++ks) {
            half8 av[MT], bv[4];
#pragma unroll
            for (int m = 0; m < MT; ++m) {
                int arow = wr + m * 16 + l15;
                int off = arow * 64 + (((ks * 4 + g) ^ (arow & 7)) << 3);
                av[m] = *(const half8*)&Ahs[off];
            }
#pragma unroll
            for (int n = 0; n < 4; ++n) {
                int brow = wc + n * 16 + l15;
                int off = brow * 64 + (((ks * 4 + g) ^ (brow & 7)) << 3);
                bv[n] = *(const half8*)&Bhs[off];
            }
#pragma unroll
            for (int m = 0; m < MT; ++m)
#pragma unroll
                for (int n = 0; n < 4; ++n)
                    acc[m][n] = mfma16h(av[m], bv[n], acc[m][n]);
        }
        __syncthreads();
    }

    const int col0 = bn + wc + l15;
    const int row0 = bm + wr + (g << 2);
#pragma unroll
    for (int n = 0; n < 4; ++n) {
        int col = col0 + n * 16;
        if (col < N) {
#pragma unroll
            for (int m = 0; m < MT; ++m)
#pragma unroll
                for (int ri = 0; ri < 4; ++ri) {
                    if (OUT16) {
                        ((unsigned short*)Cp)[(size_t)(row0 + m * 16 + ri) * ldc + col] =
                            f2h_bits(acc[m][n][ri]);
                    } else {
                        ((float*)Cp)[(size_t)(row0 + m * 16 + ri) * ldc + col] = acc[m][n][ri];
                    }
                }
        }
    }
}

// depthwise 3x3 conv (pad 1) + bias + SiLU. 8 channels x 4 w-positions per thread.
__global__ __launch_bounds__(128) void conv_silu(
    const unsigned short* __restrict__ P, const unsigned short* __restrict__ wt,
    const float* __restrict__ cb, unsigned short* __restrict__ XC)
{
    const int t = threadIdx.x;
    if (t >= 112) return;
    const int c8 = t * 8;
    const int l0 = blockIdx.x * 4;           // 4 outputs in one spatial row (56 % 4 == 0)
    const int bl = blockIdx.y;
    const int h = l0 / WWD, w0 = l0 % WWD;

    float acc[4][8];
    float4 b0 = *(const float4*)&cb[c8];
    float4 b1 = *(const float4*)&cb[c8 + 4];
#pragma unroll
    for (int o = 0; o < 4; ++o) {
        acc[o][0] = b0.x; acc[o][1] = b0.y; acc[o][2] = b0.z; acc[o][3] = b0.w;
        acc[o][4] = b1.x; acc[o][5] = b1.y; acc[o][6] = b1.z; acc[o][7] = b1.w;
    }

    const unsigned short* pb = P + (size_t)bl * LL * PSTRIDE + DINNER + c8;

#pragma unroll
    for (int kh = 0; kh < 3; ++kh) {
        int h2 = h + kh - 1;
        bool hok = (unsigned)h2 < HH;
        float xf[6][8];
#pragma unroll
        for (int j = 0; j < 6; ++j) {
            int wj = w0 - 1 + j;
            if (hok && (unsigned)wj < WWD) {
                half8 v = *(const half8*)&pb[(size_t)(h2 * WWD + wj) * PSTRIDE];
#pragma unroll
                for (int q = 0; q < 8; ++q) xf[j][q] = (float)v[q];
            } else {
#pragma unroll
                for (int q = 0; q < 8; ++q) xf[j][q] = 0.f;
            }
        }
#pragma unroll
        for (int kw = 0; kw < 3; ++kw) {
            half8 wv = *(const half8*)&wt[(kh * 3 + kw) * CDIM + c8];
            float wf[8];
#pragma unroll
            for (int q = 0; q < 8; ++q) wf[q] = (float)wv[q];
#pragma unroll
            for (int o = 0; o < 4; ++o)
#pragma unroll
                for (int q = 0; q < 8; ++q)
                    acc[o][q] += wf[q] * xf[o + kw][q];
        }
    }

#pragma unroll
    for (int o = 0; o < 4; ++o) {
        half8 ov;
#pragma unroll
        for (int q = 0; q < 8; ++q) {
            float a = acc[o][q];
            ov[q] = (_Float16)(a / (1.f + __expf(-a)));
        }
        *(half8*)&XC[((size_t)bl * LL + l0 + o) * CDIM + c8] = ov;
    }
}

// KVT[bl,h,p,s] += sum_{l in chunk of 224} B[l,s] * x[l,h*64+p] * cf[l]
// cf computed inline from P's dt column; async-stage split (loads issued before compute).
__global__ __launch_bounds__(256) void kv_kernel(
    const unsigned short* __restrict__ XC, const unsigned short* __restrict__ P,
    const float* __restrict__ dt_bias, const float* __restrict__ A_log,
    float* __restrict__ KVT)
{
    int h  = blockIdx.x;
    int bl = blockIdx.y;
    int lbase = blockIdx.z * 224;
    __shared__ float Bsh[32][DSTATE];
    __shared__ float Xsh[32][HD];
    __shared__ float cf[32];
    const int t = threadIdx.x;
    const int ss = t & 63;
    const int p0 = (t >> 6) * 16;
    const int lq = t >> 4;
    const int sq = (t & 15) * 4;
    float acc[16] = {};
    const unsigned short* xbase = XC + (size_t)bl * LL * CDIM;
    const unsigned short* pdt = P + (size_t)bl * LL * PSTRIDE + DINNER + CDIM + h;
    const float nA = -__expf(A_log[h]);
    const float db = dt_bias[h];

    // prefetch chunk 0 into registers
    ushort4 Bv[2], Xv[2];
    float dtv = 0.f;
#pragma unroll
    for (int rr = 0; rr < 2; ++rr) {
        const unsigned short* r = xbase + (size_t)(lbase + lq + rr * 16) * CDIM;
        Bv[rr] = *(const ushort4*)&r[DINNER + sq];
        Xv[rr] = *(const ushort4*)&r[h * HD + sq];
    }
    if (t < 32) dtv = h2f(pdt[(size_t)(lbase + t) * PSTRIDE]);

    for (int c = 0; c < 7; ++c) {
        __syncthreads();   // previous compute done; buffer free
#pragma unroll
        for (int rr = 0; rr < 2; ++rr) {
            Bsh[lq + rr * 16][sq + 0] = h2f(Bv[rr].x); Bsh[lq + rr * 16][sq + 1] = h2f(Bv[rr].y);
            Bsh[lq + rr * 16][sq + 2] = h2f(Bv[rr].z); Bsh[lq + rr * 16][sq + 3] = h2f(Bv[rr].w);
            Xsh[lq + rr * 16][sq + 0] = h2f(Xv[rr].x); Xsh[lq + rr * 16][sq + 1] = h2f(Xv[rr].y);
            Xsh[lq + rr * 16][sq + 2] = h2f(Xv[rr].z); Xsh[lq + rr * 16][sq + 3] = h2f(Xv[rr].w);
        }
        if (t < 32) {
            float x = dtv + db;
            float sp = (x > 20.f) ? x : log1pf(__expf(x));
            cf[t] = nA * sp;
        }
        __syncthreads();   // buffer ready

        if (c < 6) {       // issue next chunk's loads; they land during compute
            int l0 = lbase + (c + 1) * 32;
#pragma unroll
            for (int rr = 0; rr < 2; ++rr) {
                const unsigned short* r = xbase + (size_t)(l0 + lq + rr * 16) * CDIM;
                Bv[rr] = *(const ushort4*)&r[DINNER + sq];
                Xv[rr] = *(const ushort4*)&r[h * HD + sq];
            }
            if (t < 32) dtv = h2f(pdt[(size_t)(l0 + t) * PSTRIDE]);
        }

#pragma unroll
        for (int li = 0; li < 32; ++li) {
            float bb = Bsh[li][ss] * cf[li];
            float4 x0 = *(const float4*)&Xsh[li][p0 + 0];
            float4 x1 = *(const float4*)&Xsh[li][p0 + 4];
            float4 x2 = *(const float4*)&Xsh[li][p0 + 8];
            float4 x3 = *(const float4*)&Xsh[li][p0 + 12];
            acc[0]  += x0.x * bb; acc[1]  += x0.y * bb; acc[2]  += x0.z * bb; acc[3]  += x0.w * bb;
            acc[4]  += x1.x * bb; acc[5]  += x1.y * bb; acc[6]  += x1.z * bb; acc[7]  += x1.w * bb;
            acc[8]  += x2.x * bb; acc[9]  += x2.y * bb; acc[10] += x2.z * bb; acc[11] += x2.w * bb;
            acc[12] += x3.x * bb; acc[13] += x3.y * bb; acc[14] += x3.z * bb; acc[15] += x3.w * bb;
        }
    }
    float* outp = KVT + ((size_t)bl * NH + h) * HD * DSTATE;
#pragma unroll
    for (int j = 0; j < 16; ++j)
        atomicAdd(&outp[(size_t)(p0 + j) * DSTATE + ss], acc[j]);
}

// Fused: yg = (Cmat @ KVcat + x*D) * silu(z); LayerNorm(768); y fp16 -> P z cols.
// Block: 16 rows x 768 cols. Wave w owns cols [w*192, w*192+192) (12 n-tiles).
__global__ __launch_bounds__(256) void ckv_ln(
    unsigned short* __restrict__ P, const unsigned short* __restrict__ XC,
    const unsigned short* __restrict__ KV16, const float* __restrict__ Dp,
    const float* __restrict__ ln_g, const float* __restrict__ ln_b)
{
    const int t = threadIdx.x;
    const int lane = t & 63;
    const int w = t >> 6;
    const int r0 = blockIdx.x * 16;
    const int bl = blockIdx.y;
    const int l15 = lane & 15;
    const int q4 = lane >> 4;          // row-quarter
    const int dw = w * 192;

    __shared__ float ps1[4][16], ps2[4][16];

    f32x4 acc[12];
#pragma unroll
    for (int n = 0; n < 12; ++n) acc[n] = (f32x4){0.f, 0.f, 0.f, 0.f};

    const size_t gbase = (size_t)bl * LL + r0;
    const unsigned short* Cb = XC + gbase * CDIM + (DINNER + DSTATE);
    const unsigned short* kvb = KV16 + (size_t)bl * NH * HD * DSTATE;

    float dch[12];
#pragma unroll
    for (int n = 0; n < 12; ++n) dch[n] = Dp[(dw + n * 16) >> 6];

#pragma unroll
    for (int ks = 0; ks < 2; ++ks) {
        int koff = ks * 32 + q4 * 8;
        half8 av = *(const half8*)&Cb[(size_t)l15 * CDIM + koff];
#pragma unroll
        for (int n = 0; n < 12; ++n) {
            int d = dw + n * 16 + l15;
            int hh = d >> 6, p = d & 63;
            half8 bv = *(const half8*)&kvb[((size_t)hh * HD + p) * DSTATE + koff];
            acc[n] = mfma16h(av, bv, acc[n]);
        }
    }

    // gate in place + per-row partial sums
    float s1[4], s2[4];
#pragma unroll
    for (int ri = 0; ri < 4; ++ri) {
        int rloc = q4 * 4 + ri;
        size_t g = gbase + rloc;
        float a1 = 0.f, a2 = 0.f;
#pragma unroll
        for (int n = 0; n < 12; ++n) {
            int d = dw + n * 16 + l15;
            float x = h2f(XC[g * CDIM + d]);
            float z = h2f(P[g * PSTRIDE + d]);
            float sz = z / (1.f + __expf(-z));
            float yg = (acc[n][ri] + x * dch[n]) * sz;
            acc[n][ri] = yg;
            a1 += yg; a2 += yg * yg;
        }
#pragma unroll
        for (int off = 1; off < 16; off <<= 1) {
            a1 += __shfl_xor(a1, off);
            a2 += __shfl_xor(a2, off);
        }
        s1[ri] = a1; s2[ri] = a2;
    }
    if (l15 == 0) {
#pragma unroll
        for (int ri = 0; ri < 4; ++ri) {
            ps1[w][q4 * 4 + ri] = s1[ri];
            ps2[w][q4 * 4 + ri] = s2[ri];
        }
    }
    __syncthreads();

#pragma unroll
    for (int ri = 0; ri < 4; ++ri) {
        int rloc = q4 * 4 + ri;
        float S1 = ps1[0][rloc] + ps1[1][rloc] + ps1[2][rloc] + ps1[3][rloc];
        float S2 = ps2[0][rloc] + ps2[1][rloc] + ps2[2][rloc] + ps2[3][rloc];
        float mu = S1 * (1.f / 768.f);
        float var = S2 * (1.f / 768.f) - mu * mu;
        float rstd = rsqrtf(var + LNEPS);
        size_t g = gbase + rloc;
        unsigned short* prow = P + g * PSTRIDE;
#pragma unroll
        for (int n = 0; n < 12; ++n) {
            int d = dw + n * 16 + l15;
            float y = (acc[n][ri] - mu) * rstd * ln_g[d] + ln_b[d];
            prow[d] = f2h_bits(y);
        }
    }
}

extern "C" void kernel_launch(void* const* d_in, const int* in_sizes, int n_in,
                              void* d_out, int out_size, void* d_ws, size_t ws_size,
                              hipStream_t stream)
{
    const float* u       = (const float*)d_in[0];
    const float* W_in    = (const float*)d_in[1];
    const float* conv_w  = (const float*)d_in[2];
    const float* conv_b  = (const float*)d_in[3];
    const float* dt_bias = (const float*)d_in[4];
    const float* A_log   = (const float*)d_in[5];
    const float* Dp      = (const float*)d_in[6];
    const float* ln_g    = (const float*)d_in[7];
    const float* ln_b    = (const float*)d_in[8];
    const float* W_out   = (const float*)d_in[9];
    float* out = (float*)d_out;
    (void)ws_size;

    const int B = in_sizes[0] / (LL * DMODEL);   // 16
    const int M = B * LL;                        // 50176

    // workspace (~172 MiB)
    unsigned short* P  = (unsigned short*)d_ws;             // GM*PSTRIDE fp16
    unsigned short* XC = P + (size_t)GM * PSTRIDE;          // GM*896 fp16
    float* KVT = (float*)(XC + (size_t)GM * CDIM);          // GRP*NH*64*64 f32
    unsigned short* KV16 = (unsigned short*)(KVT + (size_t)GRP * NH * HD * DSTATE);
    unsigned short* u16  = KV16 + (size_t)GRP * NH * HD * DSTATE;  // M*384
    unsigned short* Wi16 = u16 + (size_t)M * DMODEL;        // 1676*384
    unsigned short* Wo16 = Wi16 + (size_t)DPROJ * DMODEL;   // 384*768
    unsigned short* wt16 = Wo16 + (size_t)DMODEL * DINNER;  // 9*896

    // one-time fp16 converts / packs
    cvt_f16<<<((size_t)M * DMODEL / 4 + 255) / 256, 256, 0, stream>>>(u, u16, M * DMODEL / 4);
    cvt_f16<<<(DPROJ * DMODEL / 4 + 255) / 256, 256, 0, stream>>>(W_in, Wi16, DPROJ * DMODEL / 4);
    cvt_f16<<<(DMODEL * DINNER / 4 + 255) / 256, 256, 0, stream>>>(W_out, Wo16, DMODEL * DINNER / 4);
    pack_w16<<<(CDIM + 255) / 256, 256, 0, stream>>>(conv_w, wt16);

    const int nkv4 = GRP * NH * HD * DSTATE / 4;

    for (int b0 = 0; b0 < B; b0 += GRP) {
        // 1) P = u_grp @ W_in^T  (fp16 MFMA, fp16 store)
        gemm_h<4, 1><<<dim3(14, GM / 128), 256, 0, stream>>>(
            u16 + (size_t)b0 * LL * DMODEL, DMODEL, Wi16, DMODEL, P, PSTRIDE, DPROJ, DMODEL);

        // 2) depthwise conv + SiLU (8ch x 4w per thread)
        conv_silu<<<dim3(LL / 4, GRP), 128, 0, stream>>>(P, wt16, conv_b, XC);

        // 3) KV einsum (inline coef, async-stage split; 14 L-chunks of 224)
        hipMemsetAsync(KVT, 0, (size_t)GRP * NH * DSTATE * HD * sizeof(float), stream);
        kv_kernel<<<dim3(NH, GRP, 14), 256, 0, stream>>>(XC, P, dt_bias, A_log, KVT);

        // 4) KVT fp32 -> fp16 (numerics identical to previous per-use convert)
        cvt_f16<<<(nkv4 + 255) / 256, 256, 0, stream>>>(KVT, KV16, nkv4);

        // 5) fused yg = (C@KV + x*D)*silu(z) + LayerNorm -> y fp16 into P z cols
        ckv_ln<<<dim3(LL / 16, GRP), 256, 0, stream>>>(P, XC, KV16, Dp, ln_g, ln_b);

        // 6) out_grp = y @ W_out^T  (fp16 A in P, fp32 out)
        gemm_h<2, 0><<<dim3(3, GM / 64), 256, 0, stream>>>(
            P, PSTRIDE, Wo16, DINNER,
            out + (size_t)b0 * LL * DMODEL, DMODEL, DMODEL, DINNER);
    }
}